// Round 11
// baseline (689.820 us; speedup 1.0000x reference)
//
#include <hip/hip_runtime.h>

typedef unsigned short u16;
using short8 = __attribute__((ext_vector_type(8))) short;
using f32x4  = __attribute__((ext_vector_type(4))) float;

#define TQ   2048
#define DM   1024
#define SLEN 1024
#define FDIM 3584
#define NEXP 8

static __device__ __forceinline__ u16 f2bf(float f) {
  union { float f; unsigned u; } a; a.f = f;
  unsigned r = a.u + 0x7fffu + ((a.u >> 16) & 1u);
  return (u16)(r >> 16);
}
static __device__ __forceinline__ float bf2f(u16 u) {
  union { unsigned u; float f; } a; a.u = ((unsigned)u) << 16;
  return a.f;
}
static __device__ __forceinline__ unsigned cvtpk(float lo, float hi) {
  unsigned r;
  asm volatile("v_cvt_pk_bf16_f32 %0, %1, %2" : "=v"(r) : "v"(lo), "v"(hi));
  return r;
}
// 8 f32 (2 float4) -> one MFMA B-fragment (8 bf16)
static __device__ __forceinline__ short8 pk8(float4 a, float4 b) {
  union { uint4 u; short8 s; } c;
  c.u.x = cvtpk(a.x, a.y); c.u.y = cvtpk(a.z, a.w);
  c.u.z = cvtpk(b.x, b.y); c.u.w = cvtpk(b.z, b.w);
  return c.s;
}

static __device__ __forceinline__ void gload16(const void* g, void* l) {
  __builtin_amdgcn_global_load_lds((const __attribute__((address_space(1))) void*)g,
                                   (__attribute__((address_space(3))) void*)l, 16, 0, 0);
}

// T1 chunked XCD swizzle
static __device__ __forceinline__ int xcd_lid(int bid, int cpx) {
  return (bid & 7) * cpx + (bid >> 3);
}

// convert 8 f32 (2 float4) -> 8 bf16 (16B) and ds_write_b128
static __device__ __forceinline__ void cvtwr8(float4 a, float4 b, u16* dst) {
  uint4 u;
  u.x = cvtpk(a.x, a.y); u.y = cvtpk(a.z, a.w);
  u.z = cvtpk(b.x, b.y); u.w = cvtpk(b.z, b.w);
  *(uint4*)dst = u;
}

// ---------------- RMSNorm: f32 in -> bf16 hi (+optional lo, +optional f32) ----
__global__ __launch_bounds__(256) void rmsnorm_kernel(
    const float* __restrict__ x, const float* __restrict__ w,
    u16* __restrict__ oh, u16* __restrict__ ol, float* __restrict__ of) {
  int t = blockIdx.x, tid = threadIdx.x;
  const float4* xr = (const float4*)(x + (size_t)t * DM);
  float4 v = xr[tid];
  float ss = v.x * v.x + v.y * v.y + v.z * v.z + v.w * v.w;
#pragma unroll
  for (int m = 1; m < 64; m <<= 1) ss += __shfl_xor(ss, m);
  __shared__ float red[4];
  if ((tid & 63) == 0) red[tid >> 6] = ss;
  __syncthreads();
  float tot = red[0] + red[1] + red[2] + red[3];
  float sc = rsqrtf(tot * (1.0f / DM) + 1e-5f);
  float4 wv = ((const float4*)w)[tid];
  float o0 = v.x * sc * wv.x, o1 = v.y * sc * wv.y, o2 = v.z * sc * wv.z, o3 = v.w * sc * wv.w;
  ushort4 hh;
  hh.x = f2bf(o0); hh.y = f2bf(o1); hh.z = f2bf(o2); hh.w = f2bf(o3);
  *(ushort4*)(oh + (size_t)t * DM + tid * 4) = hh;
  if (ol) {
    ushort4 ll;
    ll.x = f2bf(o0 - bf2f(hh.x)); ll.y = f2bf(o1 - bf2f(hh.y));
    ll.z = f2bf(o2 - bf2f(hh.z)); ll.w = f2bf(o3 - bf2f(hh.w));
    *(ushort4*)(ol + (size_t)t * DM + tid * 4) = ll;
  }
  if (of) {
    float4 o4; o4.x = o0; o4.y = o1; o4.z = o2; o4.w = o3;
    ((float4*)(of + (size_t)t * DM))[tid] = o4;
  }
}

// ---------------- split-weight conversion for wq/wk/wv (concat) + wo ---------
__global__ __launch_bounds__(256) void wconv_split_kernel(
    const float* __restrict__ wq, const float* __restrict__ wk,
    const float* __restrict__ wv, const float* __restrict__ wo,
    u16* __restrict__ qkvh, u16* __restrict__ qkvl,
    u16* __restrict__ woh, u16* __restrict__ wol) {
  for (int i = blockIdx.x * 256 + threadIdx.x; i < 655360; i += 640 * 256) {
    int el = i * 4;
    const float* src; u16 *dh, *dl;
    if (el < 1572864) {
      int r = el >> 10, c = el & 1023;
      if (r < 1024) src = wq + el;
      else if (r < 1280) src = wk + (r - 1024) * 1024 + c;
      else src = wv + (r - 1280) * 1024 + c;
      dh = qkvh + el; dl = qkvl + el;
    } else {
      int e2 = el - 1572864;
      src = wo + e2; dh = woh + e2; dl = wol + e2;
    }
    float4 v = *(const float4*)src;
    ushort4 h, l;
    h.x = f2bf(v.x); h.y = f2bf(v.y); h.z = f2bf(v.z); h.w = f2bf(v.w);
    l.x = f2bf(v.x - bf2f(h.x)); l.y = f2bf(v.y - bf2f(h.y));
    l.z = f2bf(v.z - bf2f(h.z)); l.w = f2bf(v.w - bf2f(h.w));
    *(ushort4*)dh = h; *(ushort4*)dl = l;
  }
}

// ---------------- split-bf16 GEMM, gload_lds + double-buffer ------------------
template <bool RESID>
__global__ __launch_bounds__(256) void gemm_split2_kernel(
    const u16* __restrict__ Ah, const u16* __restrict__ Al,
    const u16* __restrict__ Wh, const u16* __restrict__ Wl,
    float* __restrict__ C, const float* __restrict__ resid, int N, int cpx) {
  __shared__ u16 sAh[2][128][32], sAl[2][128][32], sWh[2][64][32], sWl[2][64][32];
  int lid = xcd_lid(blockIdx.x, cpx);
  int bm = lid & 15, bn = lid >> 4;
  int tid = threadIdx.x, lane = tid & 63, w = tid >> 6;
  int wm = w >> 1, wn = w & 1;
  int qi = lane & 15, g = lane >> 4;
  int lr = lane >> 2, lc = (lane & 3) * 8;
  const u16* pa0 = Ah + (size_t)(bm * 128 + w * 16 + lr) * DM + lc;
  const u16* pa1 = pa0 + 64 * DM;
  const u16* pl0 = Al + (size_t)(bm * 128 + w * 16 + lr) * DM + lc;
  const u16* pl1 = pl0 + 64 * DM;
  const u16* pw  = Wh + (size_t)(bn * 64 + w * 16 + lr) * DM + lc;
  const u16* pwl = Wl + (size_t)(bn * 64 + w * 16 + lr) * DM + lc;
  f32x4 acc[4][2] = {};
#define STG2(buf, kk) do { \
    gload16(pa0 + (kk), &sAh[buf][w * 16][0]); \
    gload16(pa1 + (kk), &sAh[buf][64 + w * 16][0]); \
    gload16(pl0 + (kk), &sAl[buf][w * 16][0]); \
    gload16(pl1 + (kk), &sAl[buf][64 + w * 16][0]); \
    gload16(pw  + (kk), &sWh[buf][w * 16][0]); \
    gload16(pwl + (kk), &sWl[buf][w * 16][0]); } while (0)
  STG2(0, 0);
  asm volatile("s_waitcnt vmcnt(0)" ::: "memory");
  __syncthreads();
  for (int ks = 0; ks < 32; ks++) {
    int cur = ks & 1;
    if (ks < 31) STG2(cur ^ 1, (ks + 1) * 32);
    short8 afh[4], afl[4], bfh[2], bfl[2];
#pragma unroll
    for (int i = 0; i < 4; i++) {
      afh[i] = *(short8*)&sAh[cur][wm * 64 + i * 16 + qi][g * 8];
      afl[i] = *(short8*)&sAl[cur][wm * 64 + i * 16 + qi][g * 8];
    }
#pragma unroll
    for (int i = 0; i < 2; i++) {
      bfh[i] = *(short8*)&sWh[cur][wn * 32 + i * 16 + qi][g * 8];
      bfl[i] = *(short8*)&sWl[cur][wn * 32 + i * 16 + qi][g * 8];
    }
#pragma unroll
    for (int mi = 0; mi < 4; mi++)
#pragma unroll
      for (int ni = 0; ni < 2; ni++) {
        f32x4 a = acc[mi][ni];
        a = __builtin_amdgcn_mfma_f32_16x16x32_bf16(afh[mi], bfh[ni], a, 0, 0, 0);
        a = __builtin_amdgcn_mfma_f32_16x16x32_bf16(afl[mi], bfh[ni], a, 0, 0, 0);
        a = __builtin_amdgcn_mfma_f32_16x16x32_bf16(afh[mi], bfl[ni], a, 0, 0, 0);
        acc[mi][ni] = a;
      }
    asm volatile("s_waitcnt vmcnt(0)" ::: "memory");
    __syncthreads();
  }
#undef STG2
#pragma unroll
  for (int mi = 0; mi < 4; mi++)
#pragma unroll
    for (int ni = 0; ni < 2; ni++) {
      int col = bn * 64 + wn * 32 + ni * 16 + qi;
#pragma unroll
      for (int r = 0; r < 4; r++) {
        int row = bm * 128 + wm * 64 + mi * 16 + g * 4 + r;
        float val = acc[mi][ni][r];
        if (RESID) val += resid[(size_t)row * N + col];
        C[(size_t)row * N + col] = val;
      }
    }
}

// ---------------- RoPE on fused qkv f32 [2048][1536] -------------------------
__global__ __launch_bounds__(256) void rope_split_kernel(
    const float* __restrict__ qkvf,
    const float* __restrict__ cosT, const float* __restrict__ sinT,
    u16* __restrict__ qh, u16* __restrict__ ql, u16* __restrict__ kh, u16* __restrict__ kl,
    u16* __restrict__ vh, u16* __restrict__ vl) {
  int t = blockIdx.x, tid = threadIdx.x;
  int s = t & (SLEN - 1);
  const float* rowp = qkvf + (size_t)t * 1536;
#pragma unroll
  for (int it = 0; it < 2; it++) {
    int i = it * 256 + tid;
    int hh = i >> 5, d = i & 31;
    float c = cosT[s * 64 + d], sn = sinT[s * 64 + d];
    size_t dst = (size_t)t * DM + hh * 64 + d;
    float x1 = rowp[hh * 64 + d], x2 = rowp[hh * 64 + d + 32];
    float o1 = x1 * c - x2 * sn;
    float o2 = x2 * c + x1 * sn;
    u16 h1 = f2bf(o1), h2 = f2bf(o2);
    qh[dst] = h1; qh[dst + 32] = h2;
    ql[dst] = f2bf(o1 - bf2f(h1)); ql[dst + 32] = f2bf(o2 - bf2f(h2));
  }
  if (tid < 128) {
    int hh = tid >> 5, d = tid & 31;
    float c = cosT[s * 64 + d], sn = sinT[s * 64 + d];
    size_t dst = (size_t)t * 256 + hh * 64 + d;
    float x1 = rowp[1024 + hh * 64 + d], x2 = rowp[1024 + hh * 64 + d + 32];
    float o1 = x1 * c - x2 * sn;
    float o2 = x2 * c + x1 * sn;
    u16 h1 = f2bf(o1), h2 = f2bf(o2);
    kh[dst] = h1; kh[dst + 32] = h2;
    kl[dst] = f2bf(o1 - bf2f(h1)); kl[dst + 32] = f2bf(o2 - bf2f(h2));
  }
  {
    size_t dst = (size_t)t * 256 + tid;
    float v = rowp[1280 + tid];
    u16 h = f2bf(v);
    vh[dst] = h; vl[dst] = f2bf(v - bf2f(h));
  }
}

// ---------------- flash attention, split-bf16, GQA 4:1, causal ---------------
// Balanced: block handles q-tiles {p, 15-p} -> uniform 17 K-tiles per block.
__global__ __launch_bounds__(256) void attn_kernel(
    const u16* __restrict__ qh, const u16* __restrict__ ql,
    const u16* __restrict__ kh, const u16* __restrict__ kl,
    const u16* __restrict__ vh, const u16* __restrict__ vl,
    u16* __restrict__ oh, u16* __restrict__ ol) {
  __shared__ u16 sKh[64][72], sKl[64][72];
  __shared__ u16 sVh[64][72], sVl[64][72];
  __shared__ u16 sPh[4][16][72], sPl[4][16][72];
  int p = blockIdx.x & 7;
  int bh = blockIdx.x >> 3;
  int b = bh >> 4, h = bh & 15, kvh = h >> 2;
  int tid = threadIdx.x, lane = tid & 63, w = tid >> 6;
  int qi = lane & 15, g = lane >> 4;
#pragma unroll
  for (int half = 0; half < 2; half++) {
    int qt = half ? (15 - p) : p;
    int qrow = qt * 64 + w * 16 + qi;
    size_t qbase = ((size_t)(b * SLEN + qrow)) * DM + h * 64;
    short8 qfh[2], qfl[2];
#pragma unroll
    for (int ds = 0; ds < 2; ds++) {
      qfh[ds] = *(const short8*)(qh + qbase + ds * 32 + g * 8);
      qfl[ds] = *(const short8*)(ql + qbase + ds * 32 + g * 8);
    }
    f32x4 oacc[4] = {};
    float mrun = -1e30f, lrun = 0.f;
    int ktiles = qt + 1;
    for (int kt = 0; kt < ktiles; kt++) {
      __syncthreads();
      {
        int r = tid >> 3, cs = (tid & 7) * 8;
#pragma unroll
        for (int rr = 0; rr < 64; rr += 32) {
          int key = kt * 64 + rr + r;
          size_t src = ((size_t)(b * SLEN + key)) * 256 + kvh * 64 + cs;
          *(short8*)&sKh[rr + r][cs] = *(const short8*)(kh + src);
          *(short8*)&sKl[rr + r][cs] = *(const short8*)(kl + src);
          short8 vv = *(const short8*)(vh + src);
          short8 vv2 = *(const short8*)(vl + src);
#pragma unroll
          for (int j = 0; j < 8; j++) {
            sVh[cs + j][rr + r] = (u16)vv[j];
            sVl[cs + j][rr + r] = (u16)vv2[j];
          }
        }
      }
      __syncthreads();
      f32x4 sa[4];
#pragma unroll
      for (int kf = 0; kf < 4; kf++) {
        f32x4 a = {};
#pragma unroll
        for (int ds = 0; ds < 2; ds++) {
          short8 kfh = *(short8*)&sKh[kf * 16 + qi][ds * 32 + g * 8];
          short8 kfl = *(short8*)&sKl[kf * 16 + qi][ds * 32 + g * 8];
          a = __builtin_amdgcn_mfma_f32_16x16x32_bf16(kfh, qfh[ds], a, 0, 0, 0);
          a = __builtin_amdgcn_mfma_f32_16x16x32_bf16(kfl, qfh[ds], a, 0, 0, 0);
          a = __builtin_amdgcn_mfma_f32_16x16x32_bf16(kfh, qfl[ds], a, 0, 0, 0);
        }
        sa[kf] = a;
      }
      int qg = qt * 64 + w * 16 + qi;
      float sv[4][4];
      float tmax = -1e30f;
#pragma unroll
      for (int kf = 0; kf < 4; kf++)
#pragma unroll
        for (int r = 0; r < 4; r++) {
          int key = kt * 64 + kf * 16 + g * 4 + r;
          float s = sa[kf][r] * 0.125f;
          s = (key <= qg) ? s : -1e30f;
          sv[kf][r] = s;
          tmax = fmaxf(tmax, s);
        }
      tmax = fmaxf(tmax, __shfl_xor(tmax, 16));
      tmax = fmaxf(tmax, __shfl_xor(tmax, 32));
      float mn = fmaxf(mrun, tmax);
      float alpha = expf(mrun - mn);
      float psum = 0.f;
#pragma unroll
      for (int kf = 0; kf < 4; kf++) {
        float p0 = expf(sv[kf][0] - mn), p1 = expf(sv[kf][1] - mn);
        float p2 = expf(sv[kf][2] - mn), p3 = expf(sv[kf][3] - mn);
        psum += p0 + p1 + p2 + p3;
        ushort4 ph, pl;
        ph.x = f2bf(p0); ph.y = f2bf(p1); ph.z = f2bf(p2); ph.w = f2bf(p3);
        pl.x = f2bf(p0 - bf2f(ph.x)); pl.y = f2bf(p1 - bf2f(ph.y));
        pl.z = f2bf(p2 - bf2f(ph.z)); pl.w = f2bf(p3 - bf2f(ph.w));
        *(ushort4*)&sPh[w][qi][kf * 16 + g * 4] = ph;
        *(ushort4*)&sPl[w][qi][kf * 16 + g * 4] = pl;
      }
      psum += __shfl_xor(psum, 16);
      psum += __shfl_xor(psum, 32);
      lrun = lrun * alpha + psum;
      mrun = mn;
#pragma unroll
      for (int df = 0; df < 4; df++) {
        oacc[df][0] *= alpha; oacc[df][1] *= alpha;
        oacc[df][2] *= alpha; oacc[df][3] *= alpha;
      }
#pragma unroll
      for (int ks = 0; ks < 2; ks++) {
        short8 pfh = *(short8*)&sPh[w][qi][ks * 32 + g * 8];
        short8 pfl = *(short8*)&sPl[w][qi][ks * 32 + g * 8];
#pragma unroll
        for (int df = 0; df < 4; df++) {
          short8 vfh = *(short8*)&sVh[df * 16 + qi][ks * 32 + g * 8];
          short8 vfl = *(short8*)&sVl[df * 16 + qi][ks * 32 + g * 8];
          f32x4 a = oacc[df];
          a = __builtin_amdgcn_mfma_f32_16x16x32_bf16(vfh, pfh, a, 0, 0, 0);
          a = __builtin_amdgcn_mfma_f32_16x16x32_bf16(vfl, pfh, a, 0, 0, 0);
          a = __builtin_amdgcn_mfma_f32_16x16x32_bf16(vfh, pfl, a, 0, 0, 0);
          oacc[df] = a;
        }
      }
    }
    float inv = 1.0f / lrun;
    size_t obase = ((size_t)(b * SLEN + qt * 64 + w * 16 + qi)) * DM + h * 64;
#pragma unroll
    for (int df = 0; df < 4; df++) {
      float o0 = oacc[df][0] * inv, o1 = oacc[df][1] * inv;
      float o2 = oacc[df][2] * inv, o3 = oacc[df][3] * inv;
      ushort4 hh, ll;
      hh.x = f2bf(o0); hh.y = f2bf(o1); hh.z = f2bf(o2); hh.w = f2bf(o3);
      ll.x = f2bf(o0 - bf2f(hh.x)); ll.y = f2bf(o1 - bf2f(hh.y));
      ll.z = f2bf(o2 - bf2f(hh.z)); ll.w = f2bf(o3 - bf2f(hh.w));
      *(ushort4*)(oh + obase + df * 16 + g * 4) = hh;
      *(ushort4*)(ol + obase + df * 16 + g * 4) = ll;
    }
  }
}

// ---------------- routing -----------------------------------------------------
__global__ void zero8_kernel(int* p) { if (threadIdx.x < 8) p[threadIdx.x] = 0; }

__global__ __launch_bounds__(64) void gate_kernel(
    const float* __restrict__ hf, const float* __restrict__ gw,
    int* cnt, int* tok_e, int* tok_pos, float* tok_w) {
  int t = blockIdx.x, lane = threadIdx.x;
  float acc[8] = {0, 0, 0, 0, 0, 0, 0, 0};
  for (int i = lane; i < DM; i += 64) {
    float h = hf[(size_t)t * DM + i];
#pragma unroll
    for (int e = 0; e < 8; e++) acc[e] += h * gw[e * DM + i];
  }
#pragma unroll
  for (int e = 0; e < 8; e++)
#pragma unroll
    for (int m = 1; m < 64; m <<= 1) acc[e] += __shfl_xor(acc[e], m);
  if (lane == 0) {
    int i0 = 0;
#pragma unroll
    for (int e = 1; e < 8; e++) if (acc[e] > acc[i0]) i0 = e;
    int i1 = -1;
#pragma unroll
    for (int e = 0; e < 8; e++) if (e != i0 && (i1 < 0 || acc[e] > acc[i1])) i1 = e;
    float w0 = 1.0f;
    float w1 = expf(acc[i1] - acc[i0]);
    float rs = 1.0f / (w0 + w1);
    int p0 = atomicAdd(&cnt[i0], 1);
    int p1 = atomicAdd(&cnt[i1], 1);
    tok_e[t * 2] = i0; tok_e[t * 2 + 1] = i1;
    tok_pos[t * 2] = p0; tok_pos[t * 2 + 1] = p1;
    tok_w[t * 2] = w0 * rs; tok_w[t * 2 + 1] = w1 * rs;
  }
}

__global__ void schedule_kernel(const int* cnt, int* offs, int* mt,
                                int* row_e, int* row_bm) {
  if (threadIdx.x == 0) {
    int s = 0, m = 0;
    for (int e = 0; e < 8; e++) {
      offs[e] = s;
      int nb = (cnt[e] + 127) >> 7;
      for (int i = 0; i < nb; i++) { row_e[m] = e; row_bm[m] = i; m++; }
      s += cnt[e];
    }
    *mt = m;
  }
}

__global__ __launch_bounds__(256) void gather_kernel(
    const u16* __restrict__ hn2b, const int* __restrict__ tok_e,
    const int* __restrict__ tok_pos, const float* __restrict__ tok_w,
    const int* __restrict__ offs, u16* __restrict__ Xg,
    int* __restrict__ pair_tok, int* __restrict__ pair_slot, float* __restrict__ pair_w) {
  int t = blockIdx.x;
#pragma unroll
  for (int slot = 0; slot < 2; slot++) {
    int e = tok_e[t * 2 + slot];
    int p = offs[e] + tok_pos[t * 2 + slot];
    ((ushort4*)(Xg + (size_t)p * DM))[threadIdx.x] =
        ((const ushort4*)(hn2b + (size_t)t * DM))[threadIdx.x];
    if (threadIdx.x == 0) {
      pair_tok[p] = t; pair_slot[p] = slot; pair_w[p] = tok_w[t * 2 + slot];
    }
  }
}

// ---- grouped MoE GEMM 1&3: A via gload_lds depth-3; W DIRECT global->VGPR ----
// BM=128, BN=64, BK=32. LDS = A only (24KB). No W LDS round-trip: lane (qi,g)
// loads its own B-fragment f32 source (rows share full 128B lines). Per-iter
// VMEM issue order [W(j+1) 8, A(j+2) 2] pinned; steady queue at loop top =
// [A(j)2, W(j)8, A(j+1)2] -> top wait vmcnt(10) completes A(j); compiler's
// wait before cvtpk completes W(j). Last iter: vmcnt(8).
__global__ __launch_bounds__(256) void moe_gemm13_kernel(
    const u16* __restrict__ Xg, const float* __restrict__ w1,
    const float* __restrict__ w3, const int* __restrict__ cnt,
    const int* __restrict__ offs, const int* __restrict__ mt,
    const int* __restrict__ row_e, const int* __restrict__ row_bm,
    u16* __restrict__ inter) {
  __shared__ u16 sA[3][128][32];
  int MT = *mt;
  int active = MT * 56;
  int cpx = (active + 7) >> 3;
  int xg8 = blockIdx.x >> 3;
  if (xg8 >= cpx) return;
  int lid = (blockIdx.x & 7) * cpx + xg8;
  if (lid >= active) return;
  int mrow = lid % MT, bn = lid / MT;
  int e = row_e[mrow], bm = row_bm[mrow];
  int count = cnt[e], off = offs[e];
  const u16* A = Xg + (size_t)off * DM;
  const float* W1 = w1 + (size_t)e * FDIM * DM;
  const float* W3 = w3 + (size_t)e * FDIM * DM;
  int tid = threadIdx.x, lane = tid & 63, w = tid >> 6;
  int wm = w >> 1, wn = w & 1;
  int qi = lane & 15, g = lane >> 4;
  // A staging (linear, gload_lds): wave w rows w*32..+31, 2 chunks of 16 rows
  int lrA = lane >> 2, lcA = (lane & 3) * 8;
  int ga0 = bm * 128 + w * 32 + lrA;      if (ga0 >= count) ga0 = count - 1;
  int ga1 = bm * 128 + w * 32 + 16 + lrA; if (ga1 >= count) ga1 = count - 1;
  const u16* pa0 = A + (size_t)ga0 * DM + lcA;
  const u16* pa1 = A + (size_t)ga1 * DM + lcA;
  // W direct: lane needs rows rt0 = bn*64+wn*32+qi and rt1 = rt0+16, cols k+g*8
  int rt0 = bn * 64 + wn * 32 + qi;
  const float* w1p0 = W1 + (size_t)rt0 * DM + g * 8;
  const float* w1p1 = w1p0 + 16 * DM;
  const float* w3p0 = W3 + (size_t)rt0 * DM + g * 8;
  const float* w3p1 = w3p0 + 16 * DM;
  f32x4 acc1[4][2] = {}, acc3[4][2] = {};
  // prologue: A buf0, buf1 gloads; then W gen0 reg loads (order pinned)
  gload16(pa0, &sA[0][w * 32][0]);
  gload16(pa1, &sA[0][w * 32 + 16][0]);
  gload16(pa0 + 32, &sA[1][w * 32][0]);
  gload16(pa1 + 32, &sA[1][w * 32 + 16][0]);
  __builtin_amdgcn_sched_barrier(0);
  float4 f10a = *(const float4*)w1p0, f10b = *(const float4*)(w1p0 + 4);
  float4 f11a = *(const float4*)w1p1, f11b = *(const float4*)(w1p1 + 4);
  float4 f30a = *(const float4*)w3p0, f30b = *(const float4*)(w3p0 + 4);
  float4 f31a = *(const float4*)w3p1, f31b = *(const float4*)(w3p1 + 4);
  for (int ks = 0; ks < 32; ks++) {
    int cur = ks % 3;
    if (ks == 31) asm volatile("s_waitcnt vmcnt(8)" ::: "memory");
    else          asm volatile("s_waitcnt vmcnt(10)" ::: "memory");
    __builtin_amdgcn_s_barrier();
    // build B fragments from prefetched regs (compiler waits for W(ks) here)
    short8 b1[2], b3[2];
    b1[0] = pk8(f10a, f10b); b1[1] = pk8(f11a, f11b);
    b3[0] = pk8(f30a, f30b); b3[1] = pk8(f31a, f31b);
    short8 af[4];
#pragma unroll
    for (int i = 0; i < 4; i++)
      af[i] = *(short8*)&sA[cur][wm * 64 + i * 16 + qi][g * 8];
    __builtin_amdgcn_s_setprio(1);
#pragma unroll
    for (int mi = 0; mi < 4; mi++)
#pragma unroll
      for (int ni = 0; ni < 2; ni++) {
        acc1[mi][ni] = __builtin_amdgcn_mfma_f32_16x16x32_bf16(af[mi], b1[ni], acc1[mi][ni], 0, 0, 0);
        acc3[mi][ni] = __builtin_amdgcn_mfma_f32_16x16x32_bf16(af[mi], b3[ni], acc3[mi][ni], 0, 0, 0);
      }
    __builtin_amdgcn_s_setprio(0);
    if (ks < 31) {
      int kk = (ks + 1) * 32;
      f10a = *(const float4*)(w1p0 + kk); f10b = *(const float4*)(w1p0 + kk + 4);
      f11a = *(const float4*)(w1p1 + kk); f11b = *(const float4*)(w1p1 + kk + 4);
      f30a = *(const float4*)(w3p0 + kk); f30b = *(const float4*)(w3p0 + kk + 4);
      f31a = *(const float4*)(w3p1 + kk); f31b = *(const float4*)(w3p1 + kk + 4);
      __builtin_amdgcn_sched_barrier(0);
      if (ks < 30) {
        int k2 = (ks + 2) * 32;
        int ab = (ks + 2) % 3;
        gload16(pa0 + k2, &sA[ab][w * 32][0]);
        gload16(pa1 + k2, &sA[ab][w * 32 + 16][0]);
      }
    }
  }
#pragma unroll
  for (int mi = 0; mi < 4; mi++)
#pragma unroll
    for (int r = 0; r < 4; r++) {
      int row = bm * 128 + wm * 64 + mi * 16 + g * 4 + r;
      if (row < count) {
        size_t obase = (size_t)(off + row) * FDIM + bn * 64 + wn * 32;
#pragma unroll
        for (int ni = 0; ni < 2; ni++) {
          float c1 = acc1[mi][ni][r], c3 = acc3[mi][ni][r];
          float sv = c1 / (1.0f + expf(-c1)) * c3;
          inter[obase + ni * 16 + qi] = f2bf(sv);
        }
      }
    }
}

// ---- grouped MoE GEMM 2: same W-direct structure. BM=128, BN=64 -------------
// Per-iter issue [W(j+1) 4, A(j+2) 2]; steady top wait vmcnt(6); last vmcnt(4).
__global__ __launch_bounds__(256) void moe_gemm2_kernel(
    const u16* __restrict__ inter, const float* __restrict__ w2,
    const int* __restrict__ cnt, const int* __restrict__ offs,
    const int* __restrict__ mt, const int* __restrict__ row_e,
    const int* __restrict__ row_bm,
    const int* __restrict__ pair_tok, const int* __restrict__ pair_slot,
    const float* __restrict__ pair_w, float* __restrict__ pout) {
  __shared__ u16 sA[3][128][32];
  int MT = *mt;
  int active = MT * 16;
  int cpx = (active + 7) >> 3;
  int xg8 = blockIdx.x >> 3;
  if (xg8 >= cpx) return;
  int lid = (blockIdx.x & 7) * cpx + xg8;
  if (lid >= active) return;
  int mrow = lid % MT, bn = lid / MT;
  int e = row_e[mrow], bm = row_bm[mrow];
  int count = cnt[e], off = offs[e];
  const u16* A = inter + (size_t)off * FDIM;
  const float* W = w2 + (size_t)e * DM * FDIM;
  int tid = threadIdx.x, lane = tid & 63, w = tid >> 6;
  int wm = w >> 1, wn = w & 1;
  int qi = lane & 15, g = lane >> 4;
  int lrA = lane >> 2, lcA = (lane & 3) * 8;
  int ga0 = bm * 128 + w * 32 + lrA;      if (ga0 >= count) ga0 = count - 1;
  int ga1 = bm * 128 + w * 32 + 16 + lrA; if (ga1 >= count) ga1 = count - 1;
  const u16* pa0 = A + (size_t)ga0 * FDIM + lcA;
  const u16* pa1 = A + (size_t)ga1 * FDIM + lcA;
  int rt0 = bn * 64 + wn * 32 + qi;
  const float* wp0 = W + (size_t)rt0 * FDIM + g * 8;
  const float* wp1 = wp0 + 16 * FDIM;
  f32x4 acc[4][2] = {};
  const int NK = FDIM / 32;   // 112
  gload16(pa0, &sA[0][w * 32][0]);
  gload16(pa1, &sA[0][w * 32 + 16][0]);
  gload16(pa0 + 32, &sA[1][w * 32][0]);
  gload16(pa1 + 32, &sA[1][w * 32 + 16][0]);
  __builtin_amdgcn_sched_barrier(0);
  float4 f0a = *(const float4*)wp0, f0b = *(const float4*)(wp0 + 4);
  float4 f1a = *(const float4*)wp1, f1b = *(const float4*)(wp1 + 4);
  for (int ks = 0; ks < NK; ks++) {
    int cur = ks % 3;
    if (ks == NK - 1) asm volatile("s_waitcnt vmcnt(4)" ::: "memory");
    else              asm volatile("s_waitcnt vmcnt(6)" ::: "memory");
    __builtin_amdgcn_s_barrier();
    short8 bfr[2];
    bfr[0] = pk8(f0a, f0b); bfr[1] = pk8(f1a, f1b);
    short8 af[4];
#pragma unroll
    for (int i = 0; i < 4; i++)
      af[i] = *(short8*)&sA[cur][wm * 64 + i * 16 + qi][g * 8];
    __builtin_amdgcn_s_setprio(1);
#pragma unroll
    for (int mi = 0; mi < 4; mi++)
#pragma unroll
      for (int ni = 0; ni < 2; ni++)
        acc[mi][ni] = __builtin_amdgcn_mfma_f32_16x16x32_bf16(af[mi], bfr[ni], acc[mi][ni], 0, 0, 0);
    __builtin_amdgcn_s_setprio(0);
    if (ks < NK - 1) {
      int kk = (ks + 1) * 32;
      f0a = *(const float4*)(wp0 + kk); f0b = *(const float4*)(wp0 + kk + 4);
      f1a = *(const float4*)(wp1 + kk); f1b = *(const float4*)(wp1 + kk + 4);
      __builtin_amdgcn_sched_barrier(0);
      if (ks < NK - 2) {
        int k2 = (ks + 2) * 32;
        int ab = (ks + 2) % 3;
        gload16(pa0 + k2, &sA[ab][w * 32][0]);
        gload16(pa1 + k2, &sA[ab][w * 32 + 16][0]);
      }
    }
  }
#pragma unroll
  for (int mi = 0; mi < 4; mi++)
#pragma unroll
    for (int r = 0; r < 4; r++) {
      int row = bm * 128 + wm * 64 + mi * 16 + g * 4 + r;
      if (row < count) {
        int p = off + row;
        int t = pair_tok[p];
        float wgt = pair_w[p];
        size_t obase = ((size_t)pair_slot[p] * TQ + t) * DM + bn * 64 + wn * 32;
#pragma unroll
        for (int ni = 0; ni < 2; ni++)
          pout[obase + ni * 16 + qi] = acc[mi][ni][r] * wgt;
      }
    }
}

// ---------------- final combine -----------------------------------------------
__global__ __launch_bounds__(256) void combine_kernel(
    const float* __restrict__ h, const float* __restrict__ pout, float* __restrict__ out) {
  size_t i = (size_t)blockIdx.x * 256 + threadIdx.x;
  float4 a = ((const float4*)h)[i];
  float4 b0 = ((const float4*)pout)[i];
  float4 b1 = ((const float4*)pout)[i + (size_t)TQ * DM / 4];
  float4 r;
  r.x = a.x + b0.x + b1.x; r.y = a.y + b0.y + b1.y;
  r.z = a.z + b0.z + b1.z; r.w = a.w + b0.w + b1.w;
  ((float4*)out)[i] = r;
}

// ================================================================================
extern "C" void kernel_launch(void* const* d_in, const int* in_sizes, int n_in,
                              void* d_out, int out_size, void* d_ws, size_t ws_size,
                              hipStream_t stream) {
  (void)in_sizes; (void)n_in; (void)out_size; (void)ws_size;
  const float* x    = (const float*)d_in[0];
  const float* ln1  = (const float*)d_in[1];
  const float* ln2  = (const float*)d_in[2];
  const float* wq   = (const float*)d_in[3];
  const float* wk   = (const float*)d_in[4];
  const float* wv   = (const float*)d_in[5];
  const float* wo   = (const float*)d_in[6];
  const float* gw   = (const float*)d_in[7];
  const float* w1   = (const float*)d_in[8];
  const float* w2   = (const float*)d_in[9];
  const float* w3   = (const float*)d_in[10];
  const float* cosT = (const float*)d_in[11];
  const float* sinT = (const float*)d_in[12];

  char* mb = (char*)d_ws;
  const size_t MB = 1024 * 1024;
  u16*   qhb  = (u16*)(mb + 0 * MB);        // rope->attn
  u16*   qlb  = (u16*)(mb + 4 * MB);
  u16*   khb  = (u16*)(mb + 8 * MB);
  u16*   klb  = (u16*)(mb + 9 * MB);
  u16*   vhb  = (u16*)(mb + 10 * MB);
  u16*   vlb  = (u16*)(mb + 11 * MB);
  u16*   hn2b = (u16*)(mb + 0 * MB);        // rmsnorm2->gather (after attn)
  float* hn2f = (float*)(mb + 4 * MB);      // rmsnorm2->gate
  u16*   ahb  = (u16*)(mb + 12 * MB);       // attn->gemm_o
  u16*   alb  = (u16*)(mb + 16 * MB);
  u16*   Xg   = (u16*)(mb + 12 * MB);       // gather->gemm13 (after gemm_o)
  u16*   hn1h = (u16*)(mb + 20 * MB);       // rmsnorm1->qkv
  u16*   hn1l = (u16*)(mb + 24 * MB);
  u16*   inter= (u16*)(mb + 20 * MB);       // gemm13->gemm2 (28 MiB)
  float* qkvf = (float*)(mb + 28 * MB);     // qkv->rope (12 MiB)
  float* h_res= (float*)(mb + 48 * MB);     // gemm_o->end (8 MiB)
  u16*   woh  = (u16*)(mb + 56 * MB);       // wconv->gemm_o (2 MiB)
  u16*   wol  = (u16*)(mb + 58 * MB);
  float* pout = (float*)(mb + 56 * MB);     // gemm2->combine (16 MiB)
  u16*   wqkvh= (u16*)(mb + 60 * MB);       // wconv->qkv (3 MiB)
  u16*   wqkvl= (u16*)(mb + 63 * MB);
  int*   cnt  = (int*)(mb + 72 * MB);
  int*   offs = cnt + 8;
  int*   mtp  = cnt + 16;
  int*   row_e  = cnt + 17;                 // 40
  int*   row_bm = cnt + 57;                 // 40
  int*   tok_e  = cnt + 128;
  int*   tok_pos = tok_e + 4096;
  float* tok_w   = (float*)(tok_pos + 4096);
  int*   pair_tok  = (int*)(tok_w + 4096);
  int*   pair_slot = pair_tok + 4096;
  float* pair_w    = (float*)(pair_slot + 4096);

  wconv_split_kernel<<<640, 256, 0, stream>>>(wq, wk, wv, wo, wqkvh, wqkvl, woh, wol);
  rmsnorm_kernel<<<TQ, 256, 0, stream>>>(x, ln1, hn1h, hn1l, nullptr);
  gemm_split2_kernel<false><<<384, 256, 0, stream>>>(hn1h, hn1l, wqkvh, wqkvl, qkvf, nullptr, 1536, 48);
  rope_split_kernel<<<TQ, 256, 0, stream>>>(qkvf, cosT, sinT, qhb, qlb, khb, klb, vhb, vlb);
  attn_kernel<<<256, 256, 0, stream>>>(qhb, qlb, khb, klb, vhb, vlb, ahb, alb);
  gemm_split2_kernel<true><<<256, 256, 0, stream>>>(ahb, alb, woh, wol, h_res, x, 1024, 32);
  rmsnorm_kernel<<<TQ, 256, 0, stream>>>(h_res, ln2, hn2b, nullptr, hn2f);
  zero8_kernel<<<1, 64, 0, stream>>>(cnt);
  gate_kernel<<<TQ, 64, 0, stream>>>(hn2f, gw, cnt, tok_e, tok_pos, tok_w);
  schedule_kernel<<<1, 64, 0, stream>>>(cnt, offs, mtp, row_e, row_bm);
  gather_kernel<<<TQ, 256, 0, stream>>>(hn2b, tok_e, tok_pos, tok_w, offs, Xg,
                                        pair_tok, pair_slot, pair_w);
  moe_gemm13_kernel<<<2240, 256, 0, stream>>>(Xg, w1, w3, cnt, offs, mtp,
                                              row_e, row_bm, inter);
  moe_gemm2_kernel<<<640, 256, 0, stream>>>(inter, w2, cnt, offs, mtp,
                                            row_e, row_bm,
                                            pair_tok, pair_slot, pair_w, pout);
  combine_kernel<<<TQ, 256, 0, stream>>>(h_res, pout, (float*)d_out);
}

// Round 12
// 472.177 us; speedup vs baseline: 1.4609x; 1.4609x over previous
//
#include <hip/hip_runtime.h>

typedef unsigned short u16;
using short8 = __attribute__((ext_vector_type(8))) short;
using f32x4  = __attribute__((ext_vector_type(4))) float;

#define TQ   2048
#define DM   1024
#define SLEN 1024
#define FDIM 3584
#define NEXP 8

static __device__ __forceinline__ u16 f2bf(float f) {
  union { float f; unsigned u; } a; a.f = f;
  unsigned r = a.u + 0x7fffu + ((a.u >> 16) & 1u);
  return (u16)(r >> 16);
}
static __device__ __forceinline__ float bf2f(u16 u) {
  union { unsigned u; float f; } a; a.u = ((unsigned)u) << 16;
  return a.f;
}
static __device__ __forceinline__ unsigned cvtpk(float lo, float hi) {
  unsigned r;
  asm volatile("v_cvt_pk_bf16_f32 %0, %1, %2" : "=v"(r) : "v"(lo), "v"(hi));
  return r;
}

static __device__ __forceinline__ void gload16(const void* g, void* l) {
  __builtin_amdgcn_global_load_lds((const __attribute__((address_space(1))) void*)g,
                                   (__attribute__((address_space(3))) void*)l, 16, 0, 0);
}

// T1 chunked XCD swizzle
static __device__ __forceinline__ int xcd_lid(int bid, int cpx) {
  return (bid & 7) * cpx + (bid >> 3);
}

// convert 8 f32 (2 float4) -> 8 bf16 (16B) and ds_write_b128
static __device__ __forceinline__ void cvtwr8(float4 a, float4 b, u16* dst) {
  uint4 u;
  u.x = cvtpk(a.x, a.y); u.y = cvtpk(a.z, a.w);
  u.z = cvtpk(b.x, b.y); u.w = cvtpk(b.z, b.w);
  *(uint4*)dst = u;
}

// ---------------- RMSNorm: f32 in -> bf16 hi (+optional lo, +optional f32) ----
__global__ __launch_bounds__(256) void rmsnorm_kernel(
    const float* __restrict__ x, const float* __restrict__ w,
    u16* __restrict__ oh, u16* __restrict__ ol, float* __restrict__ of) {
  int t = blockIdx.x, tid = threadIdx.x;
  const float4* xr = (const float4*)(x + (size_t)t * DM);
  float4 v = xr[tid];
  float ss = v.x * v.x + v.y * v.y + v.z * v.z + v.w * v.w;
#pragma unroll
  for (int m = 1; m < 64; m <<= 1) ss += __shfl_xor(ss, m);
  __shared__ float red[4];
  if ((tid & 63) == 0) red[tid >> 6] = ss;
  __syncthreads();
  float tot = red[0] + red[1] + red[2] + red[3];
  float sc = rsqrtf(tot * (1.0f / DM) + 1e-5f);
  float4 wv = ((const float4*)w)[tid];
  float o0 = v.x * sc * wv.x, o1 = v.y * sc * wv.y, o2 = v.z * sc * wv.z, o3 = v.w * sc * wv.w;
  ushort4 hh;
  hh.x = f2bf(o0); hh.y = f2bf(o1); hh.z = f2bf(o2); hh.w = f2bf(o3);
  *(ushort4*)(oh + (size_t)t * DM + tid * 4) = hh;
  if (ol) {
    ushort4 ll;
    ll.x = f2bf(o0 - bf2f(hh.x)); ll.y = f2bf(o1 - bf2f(hh.y));
    ll.z = f2bf(o2 - bf2f(hh.z)); ll.w = f2bf(o3 - bf2f(hh.w));
    *(ushort4*)(ol + (size_t)t * DM + tid * 4) = ll;
  }
  if (of) {
    float4 o4; o4.x = o0; o4.y = o1; o4.z = o2; o4.w = o3;
    ((float4*)(of + (size_t)t * DM))[tid] = o4;
  }
}

// ---------------- split-weight conversion for wq/wk/wv (concat) + wo ---------
__global__ __launch_bounds__(256) void wconv_split_kernel(
    const float* __restrict__ wq, const float* __restrict__ wk,
    const float* __restrict__ wv, const float* __restrict__ wo,
    u16* __restrict__ qkvh, u16* __restrict__ qkvl,
    u16* __restrict__ woh, u16* __restrict__ wol) {
  for (int i = blockIdx.x * 256 + threadIdx.x; i < 655360; i += 640 * 256) {
    int el = i * 4;
    const float* src; u16 *dh, *dl;
    if (el < 1572864) {
      int r = el >> 10, c = el & 1023;
      if (r < 1024) src = wq + el;
      else if (r < 1280) src = wk + (r - 1024) * 1024 + c;
      else src = wv + (r - 1280) * 1024 + c;
      dh = qkvh + el; dl = qkvl + el;
    } else {
      int e2 = el - 1572864;
      src = wo + e2; dh = woh + e2; dl = wol + e2;
    }
    float4 v = *(const float4*)src;
    ushort4 h, l;
    h.x = f2bf(v.x); h.y = f2bf(v.y); h.z = f2bf(v.z); h.w = f2bf(v.w);
    l.x = f2bf(v.x - bf2f(h.x)); l.y = f2bf(v.y - bf2f(h.y));
    l.z = f2bf(v.z - bf2f(h.z)); l.w = f2bf(v.w - bf2f(h.w));
    *(ushort4*)dh = h; *(ushort4*)dl = l;
  }
}

// ---------------- split-bf16 GEMM, gload_lds + double-buffer ------------------
template <bool RESID>
__global__ __launch_bounds__(256) void gemm_split2_kernel(
    const u16* __restrict__ Ah, const u16* __restrict__ Al,
    const u16* __restrict__ Wh, const u16* __restrict__ Wl,
    float* __restrict__ C, const float* __restrict__ resid, int N, int cpx) {
  __shared__ u16 sAh[2][128][32], sAl[2][128][32], sWh[2][64][32], sWl[2][64][32];
  int lid = xcd_lid(blockIdx.x, cpx);
  int bm = lid & 15, bn = lid >> 4;
  int tid = threadIdx.x, lane = tid & 63, w = tid >> 6;
  int wm = w >> 1, wn = w & 1;
  int qi = lane & 15, g = lane >> 4;
  int lr = lane >> 2, lc = (lane & 3) * 8;
  const u16* pa0 = Ah + (size_t)(bm * 128 + w * 16 + lr) * DM + lc;
  const u16* pa1 = pa0 + 64 * DM;
  const u16* pl0 = Al + (size_t)(bm * 128 + w * 16 + lr) * DM + lc;
  const u16* pl1 = pl0 + 64 * DM;
  const u16* pw  = Wh + (size_t)(bn * 64 + w * 16 + lr) * DM + lc;
  const u16* pwl = Wl + (size_t)(bn * 64 + w * 16 + lr) * DM + lc;
  f32x4 acc[4][2] = {};
#define STG2(buf, kk) do { \
    gload16(pa0 + (kk), &sAh[buf][w * 16][0]); \
    gload16(pa1 + (kk), &sAh[buf][64 + w * 16][0]); \
    gload16(pl0 + (kk), &sAl[buf][w * 16][0]); \
    gload16(pl1 + (kk), &sAl[buf][64 + w * 16][0]); \
    gload16(pw  + (kk), &sWh[buf][w * 16][0]); \
    gload16(pwl + (kk), &sWl[buf][w * 16][0]); } while (0)
  STG2(0, 0);
  asm volatile("s_waitcnt vmcnt(0)" ::: "memory");
  __syncthreads();
  for (int ks = 0; ks < 32; ks++) {
    int cur = ks & 1;
    if (ks < 31) STG2(cur ^ 1, (ks + 1) * 32);
    short8 afh[4], afl[4], bfh[2], bfl[2];
#pragma unroll
    for (int i = 0; i < 4; i++) {
      afh[i] = *(short8*)&sAh[cur][wm * 64 + i * 16 + qi][g * 8];
      afl[i] = *(short8*)&sAl[cur][wm * 64 + i * 16 + qi][g * 8];
    }
#pragma unroll
    for (int i = 0; i < 2; i++) {
      bfh[i] = *(short8*)&sWh[cur][wn * 32 + i * 16 + qi][g * 8];
      bfl[i] = *(short8*)&sWl[cur][wn * 32 + i * 16 + qi][g * 8];
    }
#pragma unroll
    for (int mi = 0; mi < 4; mi++)
#pragma unroll
      for (int ni = 0; ni < 2; ni++) {
        f32x4 a = acc[mi][ni];
        a = __builtin_amdgcn_mfma_f32_16x16x32_bf16(afh[mi], bfh[ni], a, 0, 0, 0);
        a = __builtin_amdgcn_mfma_f32_16x16x32_bf16(afl[mi], bfh[ni], a, 0, 0, 0);
        a = __builtin_amdgcn_mfma_f32_16x16x32_bf16(afh[mi], bfl[ni], a, 0, 0, 0);
        acc[mi][ni] = a;
      }
    asm volatile("s_waitcnt vmcnt(0)" ::: "memory");
    __syncthreads();
  }
#undef STG2
#pragma unroll
  for (int mi = 0; mi < 4; mi++)
#pragma unroll
    for (int ni = 0; ni < 2; ni++) {
      int col = bn * 64 + wn * 32 + ni * 16 + qi;
#pragma unroll
      for (int r = 0; r < 4; r++) {
        int row = bm * 128 + wm * 64 + mi * 16 + g * 4 + r;
        float val = acc[mi][ni][r];
        if (RESID) val += resid[(size_t)row * N + col];
        C[(size_t)row * N + col] = val;
      }
    }
}

// ---------------- RoPE on fused qkv f32 [2048][1536] -------------------------
__global__ __launch_bounds__(256) void rope_split_kernel(
    const float* __restrict__ qkvf,
    const float* __restrict__ cosT, const float* __restrict__ sinT,
    u16* __restrict__ qh, u16* __restrict__ ql, u16* __restrict__ kh, u16* __restrict__ kl,
    u16* __restrict__ vh, u16* __restrict__ vl) {
  int t = blockIdx.x, tid = threadIdx.x;
  int s = t & (SLEN - 1);
  const float* rowp = qkvf + (size_t)t * 1536;
#pragma unroll
  for (int it = 0; it < 2; it++) {
    int i = it * 256 + tid;
    int hh = i >> 5, d = i & 31;
    float c = cosT[s * 64 + d], sn = sinT[s * 64 + d];
    size_t dst = (size_t)t * DM + hh * 64 + d;
    float x1 = rowp[hh * 64 + d], x2 = rowp[hh * 64 + d + 32];
    float o1 = x1 * c - x2 * sn;
    float o2 = x2 * c + x1 * sn;
    u16 h1 = f2bf(o1), h2 = f2bf(o2);
    qh[dst] = h1; qh[dst + 32] = h2;
    ql[dst] = f2bf(o1 - bf2f(h1)); ql[dst + 32] = f2bf(o2 - bf2f(h2));
  }
  if (tid < 128) {
    int hh = tid >> 5, d = tid & 31;
    float c = cosT[s * 64 + d], sn = sinT[s * 64 + d];
    size_t dst = (size_t)t * 256 + hh * 64 + d;
    float x1 = rowp[1024 + hh * 64 + d], x2 = rowp[1024 + hh * 64 + d + 32];
    float o1 = x1 * c - x2 * sn;
    float o2 = x2 * c + x1 * sn;
    u16 h1 = f2bf(o1), h2 = f2bf(o2);
    kh[dst] = h1; kh[dst + 32] = h2;
    kl[dst] = f2bf(o1 - bf2f(h1)); kl[dst + 32] = f2bf(o2 - bf2f(h2));
  }
  {
    size_t dst = (size_t)t * 256 + tid;
    float v = rowp[1280 + tid];
    u16 h = f2bf(v);
    vh[dst] = h; vl[dst] = f2bf(v - bf2f(h));
  }
}

// ---------------- flash attention, split-bf16, GQA 4:1, causal ---------------
// 512 blocks, complement-balanced: bid<256 -> qt=p, bid>=256 -> qt=15-p.
// Round-robin dispatch pairs blocks c and c+256 on one CU: (p+1)+(16-p)=17
// tiles per CU, 2 blocks/CU (55KB LDS), 8 resident waves.
__global__ __launch_bounds__(256) void attn_kernel(
    const u16* __restrict__ qh, const u16* __restrict__ ql,
    const u16* __restrict__ kh, const u16* __restrict__ kl,
    const u16* __restrict__ vh, const u16* __restrict__ vl,
    u16* __restrict__ oh, u16* __restrict__ ol) {
  __shared__ u16 sKh[64][72], sKl[64][72];
  __shared__ u16 sVh[64][72], sVl[64][72];
  __shared__ u16 sPh[4][16][72], sPl[4][16][72];
  int idx = blockIdx.x & 255;
  int p = idx & 7;
  int bh = idx >> 3;
  int b = bh >> 4, h = bh & 15, kvh = h >> 2;
  int qt = (blockIdx.x < 256) ? p : (15 - p);
  int tid = threadIdx.x, lane = tid & 63, w = tid >> 6;
  int qi = lane & 15, g = lane >> 4;
  int qrow = qt * 64 + w * 16 + qi;
  size_t qbase = ((size_t)(b * SLEN + qrow)) * DM + h * 64;
  short8 qfh[2], qfl[2];
#pragma unroll
  for (int ds = 0; ds < 2; ds++) {
    qfh[ds] = *(const short8*)(qh + qbase + ds * 32 + g * 8);
    qfl[ds] = *(const short8*)(ql + qbase + ds * 32 + g * 8);
  }
  f32x4 oacc[4] = {};
  float mrun = -1e30f, lrun = 0.f;
  int ktiles = qt + 1;
  for (int kt = 0; kt < ktiles; kt++) {
    __syncthreads();
    {
      int r = tid >> 3, cs = (tid & 7) * 8;
#pragma unroll
      for (int rr = 0; rr < 64; rr += 32) {
        int key = kt * 64 + rr + r;
        size_t src = ((size_t)(b * SLEN + key)) * 256 + kvh * 64 + cs;
        *(short8*)&sKh[rr + r][cs] = *(const short8*)(kh + src);
        *(short8*)&sKl[rr + r][cs] = *(const short8*)(kl + src);
        short8 vv = *(const short8*)(vh + src);
        short8 vv2 = *(const short8*)(vl + src);
#pragma unroll
        for (int j = 0; j < 8; j++) {
          sVh[cs + j][rr + r] = (u16)vv[j];
          sVl[cs + j][rr + r] = (u16)vv2[j];
        }
      }
    }
    __syncthreads();
    f32x4 sa[4];
#pragma unroll
    for (int kf = 0; kf < 4; kf++) {
      f32x4 a = {};
#pragma unroll
      for (int ds = 0; ds < 2; ds++) {
        short8 kfh = *(short8*)&sKh[kf * 16 + qi][ds * 32 + g * 8];
        short8 kfl = *(short8*)&sKl[kf * 16 + qi][ds * 32 + g * 8];
        a = __builtin_amdgcn_mfma_f32_16x16x32_bf16(kfh, qfh[ds], a, 0, 0, 0);
        a = __builtin_amdgcn_mfma_f32_16x16x32_bf16(kfl, qfh[ds], a, 0, 0, 0);
        a = __builtin_amdgcn_mfma_f32_16x16x32_bf16(kfh, qfl[ds], a, 0, 0, 0);
      }
      sa[kf] = a;
    }
    int qg = qt * 64 + w * 16 + qi;
    float sv[4][4];
    float tmax = -1e30f;
#pragma unroll
    for (int kf = 0; kf < 4; kf++)
#pragma unroll
      for (int r = 0; r < 4; r++) {
        int key = kt * 64 + kf * 16 + g * 4 + r;
        float s = sa[kf][r] * 0.125f;
        s = (key <= qg) ? s : -1e30f;
        sv[kf][r] = s;
        tmax = fmaxf(tmax, s);
      }
    tmax = fmaxf(tmax, __shfl_xor(tmax, 16));
    tmax = fmaxf(tmax, __shfl_xor(tmax, 32));
    float mn = fmaxf(mrun, tmax);
    float alpha = expf(mrun - mn);
    float psum = 0.f;
#pragma unroll
    for (int kf = 0; kf < 4; kf++) {
      float p0 = expf(sv[kf][0] - mn), p1 = expf(sv[kf][1] - mn);
      float p2 = expf(sv[kf][2] - mn), p3 = expf(sv[kf][3] - mn);
      psum += p0 + p1 + p2 + p3;
      ushort4 ph, pl;
      ph.x = f2bf(p0); ph.y = f2bf(p1); ph.z = f2bf(p2); ph.w = f2bf(p3);
      pl.x = f2bf(p0 - bf2f(ph.x)); pl.y = f2bf(p1 - bf2f(ph.y));
      pl.z = f2bf(p2 - bf2f(ph.z)); pl.w = f2bf(p3 - bf2f(ph.w));
      *(ushort4*)&sPh[w][qi][kf * 16 + g * 4] = ph;
      *(ushort4*)&sPl[w][qi][kf * 16 + g * 4] = pl;
    }
    psum += __shfl_xor(psum, 16);
    psum += __shfl_xor(psum, 32);
    lrun = lrun * alpha + psum;
    mrun = mn;
#pragma unroll
    for (int df = 0; df < 4; df++) {
      oacc[df][0] *= alpha; oacc[df][1] *= alpha;
      oacc[df][2] *= alpha; oacc[df][3] *= alpha;
    }
#pragma unroll
    for (int ks = 0; ks < 2; ks++) {
      short8 pfh = *(short8*)&sPh[w][qi][ks * 32 + g * 8];
      short8 pfl = *(short8*)&sPl[w][qi][ks * 32 + g * 8];
#pragma unroll
      for (int df = 0; df < 4; df++) {
        short8 vfh = *(short8*)&sVh[df * 16 + qi][ks * 32 + g * 8];
        short8 vfl = *(short8*)&sVl[df * 16 + qi][ks * 32 + g * 8];
        f32x4 a = oacc[df];
        a = __builtin_amdgcn_mfma_f32_16x16x32_bf16(vfh, pfh, a, 0, 0, 0);
        a = __builtin_amdgcn_mfma_f32_16x16x32_bf16(vfl, pfh, a, 0, 0, 0);
        a = __builtin_amdgcn_mfma_f32_16x16x32_bf16(vfh, pfl, a, 0, 0, 0);
        oacc[df] = a;
      }
    }
  }
  float inv = 1.0f / lrun;
  size_t obase = ((size_t)(b * SLEN + qt * 64 + w * 16 + qi)) * DM + h * 64;
#pragma unroll
  for (int df = 0; df < 4; df++) {
    float o0 = oacc[df][0] * inv, o1 = oacc[df][1] * inv;
    float o2 = oacc[df][2] * inv, o3 = oacc[df][3] * inv;
    ushort4 hh, ll;
    hh.x = f2bf(o0); hh.y = f2bf(o1); hh.z = f2bf(o2); hh.w = f2bf(o3);
    ll.x = f2bf(o0 - bf2f(hh.x)); ll.y = f2bf(o1 - bf2f(hh.y));
    ll.z = f2bf(o2 - bf2f(hh.z)); ll.w = f2bf(o3 - bf2f(hh.w));
    *(ushort4*)(oh + obase + df * 16 + g * 4) = hh;
    *(ushort4*)(ol + obase + df * 16 + g * 4) = ll;
  }
}

// ---------------- routing -----------------------------------------------------
__global__ void zero8_kernel(int* p) { if (threadIdx.x < 8) p[threadIdx.x] = 0; }

__global__ __launch_bounds__(64) void gate_kernel(
    const float* __restrict__ hf, const float* __restrict__ gw,
    int* cnt, int* tok_e, int* tok_pos, float* tok_w) {
  int t = blockIdx.x, lane = threadIdx.x;
  float acc[8] = {0, 0, 0, 0, 0, 0, 0, 0};
  for (int i = lane; i < DM; i += 64) {
    float h = hf[(size_t)t * DM + i];
#pragma unroll
    for (int e = 0; e < 8; e++) acc[e] += h * gw[e * DM + i];
  }
#pragma unroll
  for (int e = 0; e < 8; e++)
#pragma unroll
    for (int m = 1; m < 64; m <<= 1) acc[e] += __shfl_xor(acc[e], m);
  if (lane == 0) {
    int i0 = 0;
#pragma unroll
    for (int e = 1; e < 8; e++) if (acc[e] > acc[i0]) i0 = e;
    int i1 = -1;
#pragma unroll
    for (int e = 0; e < 8; e++) if (e != i0 && (i1 < 0 || acc[e] > acc[i1])) i1 = e;
    float w0 = 1.0f;
    float w1 = expf(acc[i1] - acc[i0]);
    float rs = 1.0f / (w0 + w1);
    int p0 = atomicAdd(&cnt[i0], 1);
    int p1 = atomicAdd(&cnt[i1], 1);
    tok_e[t * 2] = i0; tok_e[t * 2 + 1] = i1;
    tok_pos[t * 2] = p0; tok_pos[t * 2 + 1] = p1;
    tok_w[t * 2] = w0 * rs; tok_w[t * 2 + 1] = w1 * rs;
  }
}

__global__ void schedule_kernel(const int* cnt, int* offs, int* mt,
                                int* row_e, int* row_bm) {
  if (threadIdx.x == 0) {
    int s = 0, m = 0;
    for (int e = 0; e < 8; e++) {
      offs[e] = s;
      int nb = (cnt[e] + 127) >> 7;
      for (int i = 0; i < nb; i++) { row_e[m] = e; row_bm[m] = i; m++; }
      s += cnt[e];
    }
    *mt = m;
  }
}

__global__ __launch_bounds__(256) void gather_kernel(
    const u16* __restrict__ hn2b, const int* __restrict__ tok_e,
    const int* __restrict__ tok_pos, const float* __restrict__ tok_w,
    const int* __restrict__ offs, u16* __restrict__ Xg,
    int* __restrict__ pair_tok, int* __restrict__ pair_slot, float* __restrict__ pair_w) {
  int t = blockIdx.x;
#pragma unroll
  for (int slot = 0; slot < 2; slot++) {
    int e = tok_e[t * 2 + slot];
    int p = offs[e] + tok_pos[t * 2 + slot];
    ((ushort4*)(Xg + (size_t)p * DM))[threadIdx.x] =
        ((const ushort4*)(hn2b + (size_t)t * DM))[threadIdx.x];
    if (threadIdx.x == 0) {
      pair_tok[p] = t; pair_slot[p] = slot; pair_w[p] = tok_w[t * 2 + slot];
    }
  }
}

// ---- grouped MoE GEMM 1&3: r8 structure (best measured) ----------------------
__global__ __launch_bounds__(256) void moe_gemm13_kernel(
    const u16* __restrict__ Xg, const float* __restrict__ w1,
    const float* __restrict__ w3, const int* __restrict__ cnt,
    const int* __restrict__ offs, const int* __restrict__ mt,
    const int* __restrict__ row_e, const int* __restrict__ row_bm,
    u16* __restrict__ inter) {
  __shared__ u16 sA[3][128][32];
  __shared__ u16 sW1[3][64][32], sW3[3][64][32];
  int MT = *mt;
  int active = MT * 56;
  int cpx = (active + 7) >> 3;
  int xg8 = blockIdx.x >> 3;
  if (xg8 >= cpx) return;
  int lid = (blockIdx.x & 7) * cpx + xg8;
  if (lid >= active) return;
  int mrow = lid % MT, bn = lid / MT;
  int e = row_e[mrow], bm = row_bm[mrow];
  int count = cnt[e], off = offs[e];
  const u16* A = Xg + (size_t)off * DM;
  const float* W1 = w1 + (size_t)e * FDIM * DM;
  const float* W3 = w3 + (size_t)e * FDIM * DM;
  int tid = threadIdx.x, lane = tid & 63, w = tid >> 6;
  int wm = w >> 1, wn = w & 1;
  int qi = lane & 15, g = lane >> 4;
  int lrA = lane >> 2, lcA = (lane & 3) * 8;
  int ga0 = bm * 128 + w * 32 + lrA;      if (ga0 >= count) ga0 = count - 1;
  int ga1 = bm * 128 + w * 32 + 16 + lrA; if (ga1 >= count) ga1 = count - 1;
  const u16* pa0 = A + (size_t)ga0 * DM + lcA;
  const u16* pa1 = A + (size_t)ga1 * DM + lcA;
  int r16 = lane >> 2;
  int rW = w * 16 + r16;
  int cW = (lane & 3) * 8;
  const float* q1 = W1 + (size_t)(bn * 64 + rW) * DM + cW;
  const float* q3 = W3 + (size_t)(bn * 64 + rW) * DM + cW;
  int uW = ((lane & 3) ^ (r16 & 3)) * 8;
  f32x4 acc1[4][2] = {}, acc3[4][2] = {};
  float4 p1a = *(const float4*)q1, p1b = *(const float4*)(q1 + 4);
  float4 p3a = *(const float4*)q3, p3b = *(const float4*)(q3 + 4);
  float4 v1a = *(const float4*)(q1 + 32), v1b = *(const float4*)(q1 + 36);
  float4 v3a = *(const float4*)(q3 + 32), v3b = *(const float4*)(q3 + 36);
  __builtin_amdgcn_sched_barrier(0);
  gload16(pa0, &sA[0][w * 32][0]);
  gload16(pa1, &sA[0][w * 32 + 16][0]);
  gload16(pa0 + 32, &sA[1][w * 32][0]);
  gload16(pa1 + 32, &sA[1][w * 32 + 16][0]);
  asm volatile("s_waitcnt vmcnt(8)" ::: "memory");
  cvtwr8(p1a, p1b, &sW1[0][rW][uW]);
  cvtwr8(p3a, p3b, &sW3[0][rW][uW]);
  for (int ks = 0; ks < 32; ks++) {
    int cur = ks % 3;
    if (ks == 0)       asm volatile("s_waitcnt vmcnt(2) lgkmcnt(0)" ::: "memory");
    else if (ks == 31) asm volatile("s_waitcnt vmcnt(0) lgkmcnt(0)" ::: "memory");
    else               asm volatile("s_waitcnt vmcnt(6) lgkmcnt(0)" ::: "memory");
    __builtin_amdgcn_s_barrier();
    short8 af[4], b1[2], b3[2];
#pragma unroll
    for (int i = 0; i < 4; i++)
      af[i] = *(short8*)&sA[cur][wm * 64 + i * 16 + qi][g * 8];
#pragma unroll
    for (int ni = 0; ni < 2; ni++) {
      int rt = wn * 32 + ni * 16 + qi;
      int ui = (g ^ (rt & 3)) * 8;
      b1[ni] = *(short8*)&sW1[cur][rt][ui];
      b3[ni] = *(short8*)&sW3[cur][rt][ui];
    }
    __builtin_amdgcn_s_setprio(1);
#pragma unroll
    for (int mi = 0; mi < 4; mi++)
#pragma unroll
      for (int ni = 0; ni < 2; ni++) {
        acc1[mi][ni] = __builtin_amdgcn_mfma_f32_16x16x32_bf16(af[mi], b1[ni], acc1[mi][ni], 0, 0, 0);
        acc3[mi][ni] = __builtin_amdgcn_mfma_f32_16x16x32_bf16(af[mi], b3[ni], acc3[mi][ni], 0, 0, 0);
      }
    __builtin_amdgcn_s_setprio(0);
    if (ks < 31) {
      int nb = (ks + 1) % 3;
      cvtwr8(v1a, v1b, &sW1[nb][rW][uW]);
      cvtwr8(v3a, v3b, &sW3[nb][rW][uW]);
      if (ks < 30) {
        int k2 = (ks + 2) * 32;
        v1a = *(const float4*)(q1 + k2); v1b = *(const float4*)(q1 + k2 + 4);
        v3a = *(const float4*)(q3 + k2); v3b = *(const float4*)(q3 + k2 + 4);
        __builtin_amdgcn_sched_barrier(0);
        int ab = (ks + 2) % 3;
        gload16(pa0 + k2, &sA[ab][w * 32][0]);
        gload16(pa1 + k2, &sA[ab][w * 32 + 16][0]);
      }
    }
  }
#pragma unroll
  for (int mi = 0; mi < 4; mi++)
#pragma unroll
    for (int r = 0; r < 4; r++) {
      int row = bm * 128 + wm * 64 + mi * 16 + g * 4 + r;
      if (row < count) {
        size_t obase = (size_t)(off + row) * FDIM + bn * 64 + wn * 32;
#pragma unroll
        for (int ni = 0; ni < 2; ni++) {
          float c1 = acc1[mi][ni][r], c3 = acc3[mi][ni][r];
          float sv = c1 / (1.0f + expf(-c1)) * c3;
          inter[obase + ni * 16 + qi] = f2bf(sv);
        }
      }
    }
}

// ---- grouped MoE GEMM 2: r8 structure, BN=64 (4 blocks/CU, 2x grid) ---------
__global__ __launch_bounds__(256) void moe_gemm2_kernel(
    const u16* __restrict__ inter, const float* __restrict__ w2,
    const int* __restrict__ cnt, const int* __restrict__ offs,
    const int* __restrict__ mt, const int* __restrict__ row_e,
    const int* __restrict__ row_bm,
    const int* __restrict__ pair_tok, const int* __restrict__ pair_slot,
    const float* __restrict__ pair_w, float* __restrict__ pout) {
  __shared__ u16 sA[3][128][32];
  __shared__ u16 sW[3][64][32];
  int MT = *mt;
  int active = MT * 16;
  int cpx = (active + 7) >> 3;
  int xg8 = blockIdx.x >> 3;
  if (xg8 >= cpx) return;
  int lid = (blockIdx.x & 7) * cpx + xg8;
  if (lid >= active) return;
  int mrow = lid % MT, bn = lid / MT;
  int e = row_e[mrow], bm = row_bm[mrow];
  int count = cnt[e], off = offs[e];
  const u16* A = inter + (size_t)off * FDIM;
  const float* W = w2 + (size_t)e * DM * FDIM;
  int tid = threadIdx.x, lane = tid & 63, w = tid >> 6;
  int wm = w >> 1, wn = w & 1;
  int qi = lane & 15, g = lane >> 4;
  int lrA = lane >> 2, lcA = (lane & 3) * 8;
  int ga0 = bm * 128 + w * 32 + lrA;      if (ga0 >= count) ga0 = count - 1;
  int ga1 = bm * 128 + w * 32 + 16 + lrA; if (ga1 >= count) ga1 = count - 1;
  const u16* pa0 = A + (size_t)ga0 * FDIM + lcA;
  const u16* pa1 = A + (size_t)ga1 * FDIM + lcA;
  int r16 = lane >> 2;
  int rW = w * 16 + r16;
  int cW = (lane & 3) * 8;
  const float* qw = W + (size_t)(bn * 64 + rW) * FDIM + cW;
  int uW = ((lane & 3) ^ (r16 & 3)) * 8;
  f32x4 acc[4][2] = {};
  const int NK = FDIM / 32;   // 112
  float4 ta = *(const float4*)qw, tb = *(const float4*)(qw + 4);
  float4 va = *(const float4*)(qw + 32), vb = *(const float4*)(qw + 36);
  __builtin_amdgcn_sched_barrier(0);
  gload16(pa0, &sA[0][w * 32][0]);
  gload16(pa1, &sA[0][w * 32 + 16][0]);
  gload16(pa0 + 32, &sA[1][w * 32][0]);
  gload16(pa1 + 32, &sA[1][w * 32 + 16][0]);
  asm volatile("s_waitcnt vmcnt(6)" ::: "memory");   // ta/tb ready
  cvtwr8(ta, tb, &sW[0][rW][uW]);
  for (int ks = 0; ks < NK; ks++) {
    int cur = ks % 3;
    if (ks == 0)           asm volatile("s_waitcnt vmcnt(2) lgkmcnt(0)" ::: "memory");
    else if (ks == NK - 1) asm volatile("s_waitcnt vmcnt(0) lgkmcnt(0)" ::: "memory");
    else                   asm volatile("s_waitcnt vmcnt(4) lgkmcnt(0)" ::: "memory");
    __builtin_amdgcn_s_barrier();
    short8 af[4], bfr[2];
#pragma unroll
    for (int i = 0; i < 4; i++)
      af[i] = *(short8*)&sA[cur][wm * 64 + i * 16 + qi][g * 8];
#pragma unroll
    for (int ni = 0; ni < 2; ni++) {
      int rt = wn * 32 + ni * 16 + qi;
      bfr[ni] = *(short8*)&sW[cur][rt][(g ^ (rt & 3)) * 8];
    }
    __builtin_amdgcn_s_setprio(1);
#pragma unroll
    for (int mi = 0; mi < 4; mi++)
#pragma unroll
      for (int ni = 0; ni < 2; ni++)
        acc[mi][ni] = __builtin_amdgcn_mfma_f32_16x16x32_bf16(af[mi], bfr[ni], acc[mi][ni], 0, 0, 0);
    __builtin_amdgcn_s_setprio(0);
    if (ks < NK - 1) {
      int nb = (ks + 1) % 3;
      cvtwr8(va, vb, &sW[nb][rW][uW]);
      if (ks < NK - 2) {
        int k2 = (ks + 2) * 32;
        va = *(const float4*)(qw + k2); vb = *(const float4*)(qw + k2 + 4);
        __builtin_amdgcn_sched_barrier(0);
        int ab = (ks + 2) % 3;
        gload16(pa0 + k2, &sA[ab][w * 32][0]);
        gload16(pa1 + k2, &sA[ab][w * 32 + 16][0]);
      }
    }
  }
#pragma unroll
  for (int mi = 0; mi < 4; mi++)
#pragma unroll
    for (int r = 0; r < 4; r++) {
      int row = bm * 128 + wm * 64 + mi * 16 + g * 4 + r;
      if (row < count) {
        int p = off + row;
        int t = pair_tok[p];
        float wgt = pair_w[p];
        size_t obase = ((size_t)pair_slot[p] * TQ + t) * DM + bn * 64 + wn * 32;
#pragma unroll
        for (int ni = 0; ni < 2; ni++)
          pout[obase + ni * 16 + qi] = acc[mi][ni][r] * wgt;
      }
    }
}

// ---------------- final combine -----------------------------------------------
__global__ __launch_bounds__(256) void combine_kernel(
    const float* __restrict__ h, const float* __restrict__ pout, float* __restrict__ out) {
  size_t i = (size_t)blockIdx.x * 256 + threadIdx.x;
  float4 a = ((const float4*)h)[i];
  float4 b0 = ((const float4*)pout)[i];
  float4 b1 = ((const float4*)pout)[i + (size_t)TQ * DM / 4];
  float4 r;
  r.x = a.x + b0.x + b1.x; r.y = a.y + b0.y + b1.y;
  r.z = a.z + b0.z + b1.z; r.w = a.w + b0.w + b1.w;
  ((float4*)out)[i] = r;
}

// ================================================================================
extern "C" void kernel_launch(void* const* d_in, const int* in_sizes, int n_in,
                              void* d_out, int out_size, void* d_ws, size_t ws_size,
                              hipStream_t stream) {
  (void)in_sizes; (void)n_in; (void)out_size; (void)ws_size;
  const float* x    = (const float*)d_in[0];
  const float* ln1  = (const float*)d_in[1];
  const float* ln2  = (const float*)d_in[2];
  const float* wq   = (const float*)d_in[3];
  const float* wk   = (const float*)d_in[4];
  const float* wv   = (const float*)d_in[5];
  const float* wo   = (const float*)d_in[6];
  const float* gw   = (const float*)d_in[7];
  const float* w1   = (const float*)d_in[8];
  const float* w2   = (const float*)d_in[9];
  const float* w3   = (const float*)d_in[10];
  const float* cosT = (const float*)d_in[11];
  const float* sinT = (const float*)d_in[12];

  char* mb = (char*)d_ws;
  const size_t MB = 1024 * 1024;
  u16*   qhb  = (u16*)(mb + 0 * MB);        // rope->attn
  u16*   qlb  = (u16*)(mb + 4 * MB);
  u16*   khb  = (u16*)(mb + 8 * MB);
  u16*   klb  = (u16*)(mb + 9 * MB);
  u16*   vhb  = (u16*)(mb + 10 * MB);
  u16*   vlb  = (u16*)(mb + 11 * MB);
  u16*   hn2b = (u16*)(mb + 0 * MB);        // rmsnorm2->gather (after attn)
  float* hn2f = (float*)(mb + 4 * MB);      // rmsnorm2->gate
  u16*   ahb  = (u16*)(mb + 12 * MB);       // attn->gemm_o
  u16*   alb  = (u16*)(mb + 16 * MB);
  u16*   Xg   = (u16*)(mb + 12 * MB);       // gather->gemm13 (after gemm_o)
  u16*   hn1h = (u16*)(mb + 20 * MB);       // rmsnorm1->qkv
  u16*   hn1l = (u16*)(mb + 24 * MB);
  u16*   inter= (u16*)(mb + 20 * MB);       // gemm13->gemm2 (28 MiB)
  float* qkvf = (float*)(mb + 28 * MB);     // qkv->rope (12 MiB)
  float* h_res= (float*)(mb + 48 * MB);     // gemm_o->end (8 MiB)
  u16*   woh  = (u16*)(mb + 56 * MB);       // wconv->gemm_o (2 MiB)
  u16*   wol  = (u16*)(mb + 58 * MB);
  float* pout = (float*)(mb + 56 * MB);     // gemm2->combine (16 MiB)
  u16*   wqkvh= (u16*)(mb + 60 * MB);       // wconv->qkv (3 MiB)
  u16*   wqkvl= (u16*)(mb + 63 * MB);
  int*   cnt  = (int*)(mb + 72 * MB);
  int*   offs = cnt + 8;
  int*   mtp  = cnt + 16;
  int*   row_e  = cnt + 17;                 // 40
  int*   row_bm = cnt + 57;                 // 40
  int*   tok_e  = cnt + 128;
  int*   tok_pos = tok_e + 4096;
  float* tok_w   = (float*)(tok_pos + 4096);
  int*   pair_tok  = (int*)(tok_w + 4096);
  int*   pair_slot = pair_tok + 4096;
  float* pair_w    = (float*)(pair_slot + 4096);

  wconv_split_kernel<<<640, 256, 0, stream>>>(wq, wk, wv, wo, wqkvh, wqkvl, woh, wol);
  rmsnorm_kernel<<<TQ, 256, 0, stream>>>(x, ln1, hn1h, hn1l, nullptr);
  gemm_split2_kernel<false><<<384, 256, 0, stream>>>(hn1h, hn1l, wqkvh, wqkvl, qkvf, nullptr, 1536, 48);
  rope_split_kernel<<<TQ, 256, 0, stream>>>(qkvf, cosT, sinT, qhb, qlb, khb, klb, vhb, vlb);
  attn_kernel<<<512, 256, 0, stream>>>(qhb, qlb, khb, klb, vhb, vlb, ahb, alb);
  gemm_split2_kernel<true><<<256, 256, 0, stream>>>(ahb, alb, woh, wol, h_res, x, 1024, 32);
  rmsnorm_kernel<<<TQ, 256, 0, stream>>>(h_res, ln2, hn2b, nullptr, hn2f);
  zero8_kernel<<<1, 64, 0, stream>>>(cnt);
  gate_kernel<<<TQ, 64, 0, stream>>>(hn2f, gw, cnt, tok_e, tok_pos, tok_w);
  schedule_kernel<<<1, 64, 0, stream>>>(cnt, offs, mtp, row_e, row_bm);
  gather_kernel<<<TQ, 256, 0, stream>>>(hn2b, tok_e, tok_pos, tok_w, offs, Xg,
                                        pair_tok, pair_slot, pair_w);
  moe_gemm13_kernel<<<2240, 256, 0, stream>>>(Xg, w1, w3, cnt, offs, mtp,
                                              row_e, row_bm, inter);
  moe_gemm2_kernel<<<640, 256, 0, stream>>>(inter, w2, cnt, offs, mtp,
                                            row_e, row_bm,
                                            pair_tok, pair_slot, pair_w, pout);
  combine_kernel<<<TQ, 256, 0, stream>>>(h_res, pout, (float*)d_out);
}

// Round 13
// 436.789 us; speedup vs baseline: 1.5793x; 1.0810x over previous
//
#include <hip/hip_runtime.h>

typedef unsigned short u16;
using short8 = __attribute__((ext_vector_type(8))) short;
using f32x4  = __attribute__((ext_vector_type(4))) float;

#define TQ   2048
#define DM   1024
#define SLEN 1024
#define FDIM 3584
#define NEXP 8

static __device__ __forceinline__ u16 f2bf(float f) {
  union { float f; unsigned u; } a; a.f = f;
  unsigned r = a.u + 0x7fffu + ((a.u >> 16) & 1u);
  return (u16)(r >> 16);
}
static __device__ __forceinline__ float bf2f(u16 u) {
  union { unsigned u; float f; } a; a.u = ((unsigned)u) << 16;
  return a.f;
}
static __device__ __forceinline__ unsigned cvtpk(float lo, float hi) {
  unsigned r;
  asm volatile("v_cvt_pk_bf16_f32 %0, %1, %2" : "=v"(r) : "v"(lo), "v"(hi));
  return r;
}

static __device__ __forceinline__ void gload16(const void* g, void* l) {
  __builtin_amdgcn_global_load_lds((const __attribute__((address_space(1))) void*)g,
                                   (__attribute__((address_space(3))) void*)l, 16, 0, 0);
}

// T1 chunked XCD swizzle
static __device__ __forceinline__ int xcd_lid(int bid, int cpx) {
  return (bid & 7) * cpx + (bid >> 3);
}

// convert 8 f32 (2 float4) -> 8 bf16 (16B) and ds_write_b128
static __device__ __forceinline__ void cvtwr8(float4 a, float4 b, u16* dst) {
  uint4 u;
  u.x = cvtpk(a.x, a.y); u.y = cvtpk(a.z, a.w);
  u.z = cvtpk(b.x, b.y); u.w = cvtpk(b.z, b.w);
  *(uint4*)dst = u;
}

// ------- fused: rmsnorm1 (blocks 0..2047) + qkv/o weight split-conv (rest) ---
__global__ __launch_bounds__(256) void fused_pre_kernel(
    const float* __restrict__ x, const float* __restrict__ ln1,
    u16* __restrict__ oh, u16* __restrict__ ol,
    const float* __restrict__ wq, const float* __restrict__ wk,
    const float* __restrict__ wv, const float* __restrict__ wo,
    u16* __restrict__ qkvh, u16* __restrict__ qkvl,
    u16* __restrict__ woh, u16* __restrict__ wol) {
  int tid = threadIdx.x;
  if (blockIdx.x < 2048) {
    int t = blockIdx.x;
    const float4* xr = (const float4*)(x + (size_t)t * DM);
    float4 v = xr[tid];
    float ss = v.x * v.x + v.y * v.y + v.z * v.z + v.w * v.w;
#pragma unroll
    for (int m = 1; m < 64; m <<= 1) ss += __shfl_xor(ss, m);
    __shared__ float red[4];
    if ((tid & 63) == 0) red[tid >> 6] = ss;
    __syncthreads();
    float tot = red[0] + red[1] + red[2] + red[3];
    float sc = rsqrtf(tot * (1.0f / DM) + 1e-5f);
    float4 wv_ = ((const float4*)ln1)[tid];
    float o0 = v.x * sc * wv_.x, o1 = v.y * sc * wv_.y;
    float o2 = v.z * sc * wv_.z, o3 = v.w * sc * wv_.w;
    ushort4 hh;
    hh.x = f2bf(o0); hh.y = f2bf(o1); hh.z = f2bf(o2); hh.w = f2bf(o3);
    *(ushort4*)(oh + (size_t)t * DM + tid * 4) = hh;
    ushort4 ll;
    ll.x = f2bf(o0 - bf2f(hh.x)); ll.y = f2bf(o1 - bf2f(hh.y));
    ll.z = f2bf(o2 - bf2f(hh.z)); ll.w = f2bf(o3 - bf2f(hh.w));
    *(ushort4*)(ol + (size_t)t * DM + tid * 4) = ll;
    return;
  }
  int wb = blockIdx.x - 2048;   // 0..639
  for (int i = wb * 256 + tid; i < 655360; i += 640 * 256) {
    int el = i * 4;
    const float* src; u16 *dh, *dl;
    if (el < 1572864) {
      int r = el >> 10, c = el & 1023;
      if (r < 1024) src = wq + el;
      else if (r < 1280) src = wk + (r - 1024) * 1024 + c;
      else src = wv + (r - 1280) * 1024 + c;
      dh = qkvh + el; dl = qkvl + el;
    } else {
      int e2 = el - 1572864;
      src = wo + e2; dh = woh + e2; dl = wol + e2;
    }
    float4 v = *(const float4*)src;
    ushort4 h, l;
    h.x = f2bf(v.x); h.y = f2bf(v.y); h.z = f2bf(v.z); h.w = f2bf(v.w);
    l.x = f2bf(v.x - bf2f(h.x)); l.y = f2bf(v.y - bf2f(h.y));
    l.z = f2bf(v.z - bf2f(h.z)); l.w = f2bf(v.w - bf2f(h.w));
    *(ushort4*)dh = h; *(ushort4*)dl = l;
  }
}

// ------- fused rmsnorm2 + gate: bf16 out + top-2 routing ----------------------
__global__ __launch_bounds__(256) void rmsnorm_gate_kernel(
    const float* __restrict__ x, const float* __restrict__ w,
    const float* __restrict__ gw, u16* __restrict__ oh,
    int* cnt, int* tok_e, int* tok_pos, float* tok_w) {
  int t = blockIdx.x, tid = threadIdx.x;
  float4 v = ((const float4*)(x + (size_t)t * DM))[tid];
  float ss = v.x * v.x + v.y * v.y + v.z * v.z + v.w * v.w;
#pragma unroll
  for (int m = 1; m < 64; m <<= 1) ss += __shfl_xor(ss, m);
  __shared__ float red[4];
  __shared__ float gred[4][8];
  if ((tid & 63) == 0) red[tid >> 6] = ss;
  __syncthreads();
  float tot = red[0] + red[1] + red[2] + red[3];
  float sc = rsqrtf(tot * (1.0f / DM) + 1e-5f);
  float4 wv_ = ((const float4*)w)[tid];
  float o0 = v.x * sc * wv_.x, o1 = v.y * sc * wv_.y;
  float o2 = v.z * sc * wv_.z, o3 = v.w * sc * wv_.w;
  ushort4 hh;
  hh.x = f2bf(o0); hh.y = f2bf(o1); hh.z = f2bf(o2); hh.w = f2bf(o3);
  *(ushort4*)(oh + (size_t)t * DM + tid * 4) = hh;
  float acc[8];
#pragma unroll
  for (int e = 0; e < 8; e++) {
    float4 ge = ((const float4*)(gw + e * DM))[tid];
    acc[e] = o0 * ge.x + o1 * ge.y + o2 * ge.z + o3 * ge.w;
  }
#pragma unroll
  for (int e = 0; e < 8; e++)
#pragma unroll
    for (int m = 1; m < 64; m <<= 1) acc[e] += __shfl_xor(acc[e], m);
  int lane = tid & 63, wvi = tid >> 6;
  if (lane == 0)
#pragma unroll
    for (int e = 0; e < 8; e++) gred[wvi][e] = acc[e];
  __syncthreads();
  if (tid == 0) {
    float l[8];
#pragma unroll
    for (int e = 0; e < 8; e++)
      l[e] = gred[0][e] + gred[1][e] + gred[2][e] + gred[3][e];
    int i0 = 0;
#pragma unroll
    for (int e = 1; e < 8; e++) if (l[e] > l[i0]) i0 = e;
    int i1 = -1;
#pragma unroll
    for (int e = 0; e < 8; e++) if (e != i0 && (i1 < 0 || l[e] > l[i1])) i1 = e;
    float w0 = 1.0f;
    float w1 = expf(l[i1] - l[i0]);
    float rs = 1.0f / (w0 + w1);
    int p0 = atomicAdd(&cnt[i0], 1);
    int p1 = atomicAdd(&cnt[i1], 1);
    tok_e[t * 2] = i0; tok_e[t * 2 + 1] = i1;
    tok_pos[t * 2] = p0; tok_pos[t * 2 + 1] = p1;
    tok_w[t * 2] = w0 * rs; tok_w[t * 2 + 1] = w1 * rs;
  }
}

// ------- split-bf16 dense GEMM, counted depth-3 pipeline (r8 pattern) --------
// C(2048 x N) = [Ah+Al](2048 x 1024) @ [Wh+Wl](N x 1024)^T (+resid). BM=128 BN=64.
template <bool RESID>
__global__ __launch_bounds__(256) void gemm_split3_kernel(
    const u16* __restrict__ Ah, const u16* __restrict__ Al,
    const u16* __restrict__ Wh, const u16* __restrict__ Wl,
    float* __restrict__ C, const float* __restrict__ resid, int N, int cpx) {
  __shared__ u16 sAh[3][128][32], sAl[3][128][32], sWh[3][64][32], sWl[3][64][32];
  int lid = xcd_lid(blockIdx.x, cpx);
  int bm = lid & 15, bn = lid >> 4;
  int tid = threadIdx.x, lane = tid & 63, w = tid >> 6;
  int wm = w >> 1, wn = w & 1;
  int qi = lane & 15, g = lane >> 4;
  int lr = lane >> 2, lc = (lane & 3) * 8;
  const u16* pa0 = Ah + (size_t)(bm * 128 + w * 16 + lr) * DM + lc;
  const u16* pa1 = pa0 + 64 * DM;
  const u16* pl0 = Al + (size_t)(bm * 128 + w * 16 + lr) * DM + lc;
  const u16* pl1 = pl0 + 64 * DM;
  const u16* pw  = Wh + (size_t)(bn * 64 + w * 16 + lr) * DM + lc;
  const u16* pwl = Wl + (size_t)(bn * 64 + w * 16 + lr) * DM + lc;
  f32x4 acc[4][2] = {};
#define STG3(buf, kk) do { \
    gload16(pa0 + (kk), &sAh[buf][w * 16][0]); \
    gload16(pa1 + (kk), &sAh[buf][64 + w * 16][0]); \
    gload16(pl0 + (kk), &sAl[buf][w * 16][0]); \
    gload16(pl1 + (kk), &sAl[buf][64 + w * 16][0]); \
    gload16(pw  + (kk), &sWh[buf][w * 16][0]); \
    gload16(pwl + (kk), &sWl[buf][w * 16][0]); } while (0)
  STG3(0, 0);
  STG3(1, 32);
  for (int ks = 0; ks < 32; ks++) {
    int cur = ks % 3;
    if (ks == 31) asm volatile("s_waitcnt vmcnt(0) lgkmcnt(0)" ::: "memory");
    else          asm volatile("s_waitcnt vmcnt(6) lgkmcnt(0)" ::: "memory");
    __builtin_amdgcn_s_barrier();
    short8 afh[4], afl[4], bfh[2], bfl[2];
#pragma unroll
    for (int i = 0; i < 4; i++) {
      afh[i] = *(short8*)&sAh[cur][wm * 64 + i * 16 + qi][g * 8];
      afl[i] = *(short8*)&sAl[cur][wm * 64 + i * 16 + qi][g * 8];
    }
#pragma unroll
    for (int i = 0; i < 2; i++) {
      bfh[i] = *(short8*)&sWh[cur][wn * 32 + i * 16 + qi][g * 8];
      bfl[i] = *(short8*)&sWl[cur][wn * 32 + i * 16 + qi][g * 8];
    }
    __builtin_amdgcn_s_setprio(1);
#pragma unroll
    for (int mi = 0; mi < 4; mi++)
#pragma unroll
      for (int ni = 0; ni < 2; ni++) {
        f32x4 a = acc[mi][ni];
        a = __builtin_amdgcn_mfma_f32_16x16x32_bf16(afh[mi], bfh[ni], a, 0, 0, 0);
        a = __builtin_amdgcn_mfma_f32_16x16x32_bf16(afl[mi], bfh[ni], a, 0, 0, 0);
        a = __builtin_amdgcn_mfma_f32_16x16x32_bf16(afh[mi], bfl[ni], a, 0, 0, 0);
        acc[mi][ni] = a;
      }
    __builtin_amdgcn_s_setprio(0);
    if (ks < 30) STG3((ks + 2) % 3, (ks + 2) * 32);
  }
#undef STG3
#pragma unroll
  for (int mi = 0; mi < 4; mi++)
#pragma unroll
    for (int ni = 0; ni < 2; ni++) {
      int col = bn * 64 + wn * 32 + ni * 16 + qi;
#pragma unroll
      for (int r = 0; r < 4; r++) {
        int row = bm * 128 + wm * 64 + mi * 16 + g * 4 + r;
        float val = acc[mi][ni][r];
        if (RESID) val += resid[(size_t)row * N + col];
        C[(size_t)row * N + col] = val;
      }
    }
}

// ---------------- RoPE on fused qkv f32 [2048][1536] -------------------------
__global__ __launch_bounds__(256) void rope_split_kernel(
    const float* __restrict__ qkvf,
    const float* __restrict__ cosT, const float* __restrict__ sinT,
    u16* __restrict__ qh, u16* __restrict__ ql, u16* __restrict__ kh, u16* __restrict__ kl,
    u16* __restrict__ vh, u16* __restrict__ vl) {
  int t = blockIdx.x, tid = threadIdx.x;
  int s = t & (SLEN - 1);
  const float* rowp = qkvf + (size_t)t * 1536;
#pragma unroll
  for (int it = 0; it < 2; it++) {
    int i = it * 256 + tid;
    int hh = i >> 5, d = i & 31;
    float c = cosT[s * 64 + d], sn = sinT[s * 64 + d];
    size_t dst = (size_t)t * DM + hh * 64 + d;
    float x1 = rowp[hh * 64 + d], x2 = rowp[hh * 64 + d + 32];
    float o1 = x1 * c - x2 * sn;
    float o2 = x2 * c + x1 * sn;
    u16 h1 = f2bf(o1), h2 = f2bf(o2);
    qh[dst] = h1; qh[dst + 32] = h2;
    ql[dst] = f2bf(o1 - bf2f(h1)); ql[dst + 32] = f2bf(o2 - bf2f(h2));
  }
  if (tid < 128) {
    int hh = tid >> 5, d = tid & 31;
    float c = cosT[s * 64 + d], sn = sinT[s * 64 + d];
    size_t dst = (size_t)t * 256 + hh * 64 + d;
    float x1 = rowp[1024 + hh * 64 + d], x2 = rowp[1024 + hh * 64 + d + 32];
    float o1 = x1 * c - x2 * sn;
    float o2 = x2 * c + x1 * sn;
    u16 h1 = f2bf(o1), h2 = f2bf(o2);
    kh[dst] = h1; kh[dst + 32] = h2;
    kl[dst] = f2bf(o1 - bf2f(h1)); kl[dst + 32] = f2bf(o2 - bf2f(h2));
  }
  {
    size_t dst = (size_t)t * 256 + tid;
    float v = rowp[1280 + tid];
    u16 h = f2bf(v);
    vh[dst] = h; vl[dst] = f2bf(v - bf2f(h));
  }
}

// ---------------- flash attention, split-bf16, GQA 4:1, causal ---------------
// 512 blocks, complement-balanced: bid<256 -> qt=p, bid>=256 -> qt=15-p.
__global__ __launch_bounds__(256) void attn_kernel(
    const u16* __restrict__ qh, const u16* __restrict__ ql,
    const u16* __restrict__ kh, const u16* __restrict__ kl,
    const u16* __restrict__ vh, const u16* __restrict__ vl,
    u16* __restrict__ oh, u16* __restrict__ ol) {
  __shared__ u16 sKh[64][72], sKl[64][72];
  __shared__ u16 sVh[64][72], sVl[64][72];
  __shared__ u16 sPh[4][16][72], sPl[4][16][72];
  int idx = blockIdx.x & 255;
  int p = idx & 7;
  int bh = idx >> 3;
  int b = bh >> 4, h = bh & 15, kvh = h >> 2;
  int qt = (blockIdx.x < 256) ? p : (15 - p);
  int tid = threadIdx.x, lane = tid & 63, w = tid >> 6;
  int qi = lane & 15, g = lane >> 4;
  int qrow = qt * 64 + w * 16 + qi;
  size_t qbase = ((size_t)(b * SLEN + qrow)) * DM + h * 64;
  short8 qfh[2], qfl[2];
#pragma unroll
  for (int ds = 0; ds < 2; ds++) {
    qfh[ds] = *(const short8*)(qh + qbase + ds * 32 + g * 8);
    qfl[ds] = *(const short8*)(ql + qbase + ds * 32 + g * 8);
  }
  f32x4 oacc[4] = {};
  float mrun = -1e30f, lrun = 0.f;
  int ktiles = qt + 1;
  for (int kt = 0; kt < ktiles; kt++) {
    __syncthreads();
    {
      int r = tid >> 3, cs = (tid & 7) * 8;
#pragma unroll
      for (int rr = 0; rr < 64; rr += 32) {
        int key = kt * 64 + rr + r;
        size_t src = ((size_t)(b * SLEN + key)) * 256 + kvh * 64 + cs;
        *(short8*)&sKh[rr + r][cs] = *(const short8*)(kh + src);
        *(short8*)&sKl[rr + r][cs] = *(const short8*)(kl + src);
        short8 vv = *(const short8*)(vh + src);
        short8 vv2 = *(const short8*)(vl + src);
#pragma unroll
        for (int j = 0; j < 8; j++) {
          sVh[cs + j][rr + r] = (u16)vv[j];
          sVl[cs + j][rr + r] = (u16)vv2[j];
        }
      }
    }
    __syncthreads();
    f32x4 sa[4];
#pragma unroll
    for (int kf = 0; kf < 4; kf++) {
      f32x4 a = {};
#pragma unroll
      for (int ds = 0; ds < 2; ds++) {
        short8 kfh = *(short8*)&sKh[kf * 16 + qi][ds * 32 + g * 8];
        short8 kfl = *(short8*)&sKl[kf * 16 + qi][ds * 32 + g * 8];
        a = __builtin_amdgcn_mfma_f32_16x16x32_bf16(kfh, qfh[ds], a, 0, 0, 0);
        a = __builtin_amdgcn_mfma_f32_16x16x32_bf16(kfl, qfh[ds], a, 0, 0, 0);
        a = __builtin_amdgcn_mfma_f32_16x16x32_bf16(kfh, qfl[ds], a, 0, 0, 0);
      }
      sa[kf] = a;
    }
    int qg = qt * 64 + w * 16 + qi;
    float sv[4][4];
    float tmax = -1e30f;
#pragma unroll
    for (int kf = 0; kf < 4; kf++)
#pragma unroll
      for (int r = 0; r < 4; r++) {
        int key = kt * 64 + kf * 16 + g * 4 + r;
        float s = sa[kf][r] * 0.125f;
        s = (key <= qg) ? s : -1e30f;
        sv[kf][r] = s;
        tmax = fmaxf(tmax, s);
      }
    tmax = fmaxf(tmax, __shfl_xor(tmax, 16));
    tmax = fmaxf(tmax, __shfl_xor(tmax, 32));
    float mn = fmaxf(mrun, tmax);
    float alpha = expf(mrun - mn);
    float psum = 0.f;
#pragma unroll
    for (int kf = 0; kf < 4; kf++) {
      float p0 = expf(sv[kf][0] - mn), p1 = expf(sv[kf][1] - mn);
      float p2 = expf(sv[kf][2] - mn), p3 = expf(sv[kf][3] - mn);
      psum += p0 + p1 + p2 + p3;
      ushort4 ph, pl;
      ph.x = f2bf(p0); ph.y = f2bf(p1); ph.z = f2bf(p2); ph.w = f2bf(p3);
      pl.x = f2bf(p0 - bf2f(ph.x)); pl.y = f2bf(p1 - bf2f(ph.y));
      pl.z = f2bf(p2 - bf2f(ph.z)); pl.w = f2bf(p3 - bf2f(ph.w));
      *(ushort4*)&sPh[w][qi][kf * 16 + g * 4] = ph;
      *(ushort4*)&sPl[w][qi][kf * 16 + g * 4] = pl;
    }
    psum += __shfl_xor(psum, 16);
    psum += __shfl_xor(psum, 32);
    lrun = lrun * alpha + psum;
    mrun = mn;
#pragma unroll
    for (int df = 0; df < 4; df++) {
      oacc[df][0] *= alpha; oacc[df][1] *= alpha;
      oacc[df][2] *= alpha; oacc[df][3] *= alpha;
    }
#pragma unroll
    for (int ks = 0; ks < 2; ks++) {
      short8 pfh = *(short8*)&sPh[w][qi][ks * 32 + g * 8];
      short8 pfl = *(short8*)&sPl[w][qi][ks * 32 + g * 8];
#pragma unroll
      for (int df = 0; df < 4; df++) {
        short8 vfh = *(short8*)&sVh[df * 16 + qi][ks * 32 + g * 8];
        short8 vfl = *(short8*)&sVl[df * 16 + qi][ks * 32 + g * 8];
        f32x4 a = oacc[df];
        a = __builtin_amdgcn_mfma_f32_16x16x32_bf16(vfh, pfh, a, 0, 0, 0);
        a = __builtin_amdgcn_mfma_f32_16x16x32_bf16(vfl, pfh, a, 0, 0, 0);
        a = __builtin_amdgcn_mfma_f32_16x16x32_bf16(vfh, pfl, a, 0, 0, 0);
        oacc[df] = a;
      }
    }
  }
  float inv = 1.0f / lrun;
  size_t obase = ((size_t)(b * SLEN + qt * 64 + w * 16 + qi)) * DM + h * 64;
#pragma unroll
  for (int df = 0; df < 4; df++) {
    float o0 = oacc[df][0] * inv, o1 = oacc[df][1] * inv;
    float o2 = oacc[df][2] * inv, o3 = oacc[df][3] * inv;
    ushort4 hh, ll;
    hh.x = f2bf(o0); hh.y = f2bf(o1); hh.z = f2bf(o2); hh.w = f2bf(o3);
    ll.x = f2bf(o0 - bf2f(hh.x)); ll.y = f2bf(o1 - bf2f(hh.y));
    ll.z = f2bf(o2 - bf2f(hh.z)); ll.w = f2bf(o3 - bf2f(hh.w));
    *(ushort4*)(oh + obase + df * 16 + g * 4) = hh;
    *(ushort4*)(ol + obase + df * 16 + g * 4) = ll;
  }
}

// ---------------- routing helpers --------------------------------------------
__global__ void zero8_kernel(int* p) { if (threadIdx.x < 8) p[threadIdx.x] = 0; }

__global__ void schedule_kernel(const int* cnt, int* offs, int* mt,
                                int* row_e, int* row_bm) {
  if (threadIdx.x == 0) {
    int s = 0, m = 0;
    for (int e = 0; e < 8; e++) {
      offs[e] = s;
      int nb = (cnt[e] + 127) >> 7;
      for (int i = 0; i < nb; i++) { row_e[m] = e; row_bm[m] = i; m++; }
      s += cnt[e];
    }
    *mt = m;
  }
}

__global__ __launch_bounds__(256) void gather_kernel(
    const u16* __restrict__ hn2b, const int* __restrict__ tok_e,
    const int* __restrict__ tok_pos, const float* __restrict__ tok_w,
    const int* __restrict__ offs, u16* __restrict__ Xg,
    int* __restrict__ pair_tok, int* __restrict__ pair_slot, float* __restrict__ pair_w) {
  int t = blockIdx.x;
#pragma unroll
  for (int slot = 0; slot < 2; slot++) {
    int e = tok_e[t * 2 + slot];
    int p = offs[e] + tok_pos[t * 2 + slot];
    ((ushort4*)(Xg + (size_t)p * DM))[threadIdx.x] =
        ((const ushort4*)(hn2b + (size_t)t * DM))[threadIdx.x];
    if (threadIdx.x == 0) {
      pair_tok[p] = t; pair_slot[p] = slot; pair_w[p] = tok_w[t * 2 + slot];
    }
  }
}

// ---- grouped MoE GEMM 1&3: r8 structure (frozen best) ------------------------
__global__ __launch_bounds__(256) void moe_gemm13_kernel(
    const u16* __restrict__ Xg, const float* __restrict__ w1,
    const float* __restrict__ w3, const int* __restrict__ cnt,
    const int* __restrict__ offs, const int* __restrict__ mt,
    const int* __restrict__ row_e, const int* __restrict__ row_bm,
    u16* __restrict__ inter) {
  __shared__ u16 sA[3][128][32];
  __shared__ u16 sW1[3][64][32], sW3[3][64][32];
  int MT = *mt;
  int active = MT * 56;
  int cpx = (active + 7) >> 3;
  int xg8 = blockIdx.x >> 3;
  if (xg8 >= cpx) return;
  int lid = (blockIdx.x & 7) * cpx + xg8;
  if (lid >= active) return;
  int mrow = lid % MT, bn = lid / MT;
  int e = row_e[mrow], bm = row_bm[mrow];
  int count = cnt[e], off = offs[e];
  const u16* A = Xg + (size_t)off * DM;
  const float* W1 = w1 + (size_t)e * FDIM * DM;
  const float* W3 = w3 + (size_t)e * FDIM * DM;
  int tid = threadIdx.x, lane = tid & 63, w = tid >> 6;
  int wm = w >> 1, wn = w & 1;
  int qi = lane & 15, g = lane >> 4;
  int lrA = lane >> 2, lcA = (lane & 3) * 8;
  int ga0 = bm * 128 + w * 32 + lrA;      if (ga0 >= count) ga0 = count - 1;
  int ga1 = bm * 128 + w * 32 + 16 + lrA; if (ga1 >= count) ga1 = count - 1;
  const u16* pa0 = A + (size_t)ga0 * DM + lcA;
  const u16* pa1 = A + (size_t)ga1 * DM + lcA;
  int r16 = lane >> 2;
  int rW = w * 16 + r16;
  int cW = (lane & 3) * 8;
  const float* q1 = W1 + (size_t)(bn * 64 + rW) * DM + cW;
  const float* q3 = W3 + (size_t)(bn * 64 + rW) * DM + cW;
  int uW = ((lane & 3) ^ (r16 & 3)) * 8;
  f32x4 acc1[4][2] = {}, acc3[4][2] = {};
  float4 p1a = *(const float4*)q1, p1b = *(const float4*)(q1 + 4);
  float4 p3a = *(const float4*)q3, p3b = *(const float4*)(q3 + 4);
  float4 v1a = *(const float4*)(q1 + 32), v1b = *(const float4*)(q1 + 36);
  float4 v3a = *(const float4*)(q3 + 32), v3b = *(const float4*)(q3 + 36);
  __builtin_amdgcn_sched_barrier(0);
  gload16(pa0, &sA[0][w * 32][0]);
  gload16(pa1, &sA[0][w * 32 + 16][0]);
  gload16(pa0 + 32, &sA[1][w * 32][0]);
  gload16(pa1 + 32, &sA[1][w * 32 + 16][0]);
  asm volatile("s_waitcnt vmcnt(8)" ::: "memory");
  cvtwr8(p1a, p1b, &sW1[0][rW][uW]);
  cvtwr8(p3a, p3b, &sW3[0][rW][uW]);
  for (int ks = 0; ks < 32; ks++) {
    int cur = ks % 3;
    if (ks == 0)       asm volatile("s_waitcnt vmcnt(2) lgkmcnt(0)" ::: "memory");
    else if (ks == 31) asm volatile("s_waitcnt vmcnt(0) lgkmcnt(0)" ::: "memory");
    else               asm volatile("s_waitcnt vmcnt(6) lgkmcnt(0)" ::: "memory");
    __builtin_amdgcn_s_barrier();
    short8 af[4], b1[2], b3[2];
#pragma unroll
    for (int i = 0; i < 4; i++)
      af[i] = *(short8*)&sA[cur][wm * 64 + i * 16 + qi][g * 8];
#pragma unroll
    for (int ni = 0; ni < 2; ni++) {
      int rt = wn * 32 + ni * 16 + qi;
      int ui = (g ^ (rt & 3)) * 8;
      b1[ni] = *(short8*)&sW1[cur][rt][ui];
      b3[ni] = *(short8*)&sW3[cur][rt][ui];
    }
    __builtin_amdgcn_s_setprio(1);
#pragma unroll
    for (int mi = 0; mi < 4; mi++)
#pragma unroll
      for (int ni = 0; ni < 2; ni++) {
        acc1[mi][ni] = __builtin_amdgcn_mfma_f32_16x16x32_bf16(af[mi], b1[ni], acc1[mi][ni], 0, 0, 0);
        acc3[mi][ni] = __builtin_amdgcn_mfma_f32_16x16x32_bf16(af[mi], b3[ni], acc3[mi][ni], 0, 0, 0);
      }
    __builtin_amdgcn_s_setprio(0);
    if (ks < 31) {
      int nb = (ks + 1) % 3;
      cvtwr8(v1a, v1b, &sW1[nb][rW][uW]);
      cvtwr8(v3a, v3b, &sW3[nb][rW][uW]);
      if (ks < 30) {
        int k2 = (ks + 2) * 32;
        v1a = *(const float4*)(q1 + k2); v1b = *(const float4*)(q1 + k2 + 4);
        v3a = *(const float4*)(q3 + k2); v3b = *(const float4*)(q3 + k2 + 4);
        __builtin_amdgcn_sched_barrier(0);
        int ab = (ks + 2) % 3;
        gload16(pa0 + k2, &sA[ab][w * 32][0]);
        gload16(pa1 + k2, &sA[ab][w * 32 + 16][0]);
      }
    }
  }
#pragma unroll
  for (int mi = 0; mi < 4; mi++)
#pragma unroll
    for (int r = 0; r < 4; r++) {
      int row = bm * 128 + wm * 64 + mi * 16 + g * 4 + r;
      if (row < count) {
        size_t obase = (size_t)(off + row) * FDIM + bn * 64 + wn * 32;
#pragma unroll
        for (int ni = 0; ni < 2; ni++) {
          float c1 = acc1[mi][ni][r], c3 = acc3[mi][ni][r];
          float sv = c1 / (1.0f + expf(-c1)) * c3;
          inter[obase + ni * 16 + qi] = f2bf(sv);
        }
      }
    }
}

// ---- grouped MoE GEMM 2: r10 structure, BN=64 (frozen best) ------------------
__global__ __launch_bounds__(256) void moe_gemm2_kernel(
    const u16* __restrict__ inter, const float* __restrict__ w2,
    const int* __restrict__ cnt, const int* __restrict__ offs,
    const int* __restrict__ mt, const int* __restrict__ row_e,
    const int* __restrict__ row_bm,
    const int* __restrict__ pair_tok, const int* __restrict__ pair_slot,
    const float* __restrict__ pair_w, float* __restrict__ pout) {
  __shared__ u16 sA[3][128][32];
  __shared__ u16 sW[3][64][32];
  int MT = *mt;
  int active = MT * 16;
  int cpx = (active + 7) >> 3;
  int xg8 = blockIdx.x >> 3;
  if (xg8 >= cpx) return;
  int lid = (blockIdx.x & 7) * cpx + xg8;
  if (lid >= active) return;
  int mrow = lid % MT, bn = lid / MT;
  int e = row_e[mrow], bm = row_bm[mrow];
  int count = cnt[e], off = offs[e];
  const u16* A = inter + (size_t)off * FDIM;
  const float* W = w2 + (size_t)e * DM * FDIM;
  int tid = threadIdx.x, lane = tid & 63, w = tid >> 6;
  int wm = w >> 1, wn = w & 1;
  int qi = lane & 15, g = lane >> 4;
  int lrA = lane >> 2, lcA = (lane & 3) * 8;
  int ga0 = bm * 128 + w * 32 + lrA;      if (ga0 >= count) ga0 = count - 1;
  int ga1 = bm * 128 + w * 32 + 16 + lrA; if (ga1 >= count) ga1 = count - 1;
  const u16* pa0 = A + (size_t)ga0 * FDIM + lcA;
  const u16* pa1 = A + (size_t)ga1 * FDIM + lcA;
  int r16 = lane >> 2;
  int rW = w * 16 + r16;
  int cW = (lane & 3) * 8;
  const float* qw = W + (size_t)(bn * 64 + rW) * FDIM + cW;
  int uW = ((lane & 3) ^ (r16 & 3)) * 8;
  f32x4 acc[4][2] = {};
  const int NK = FDIM / 32;   // 112
  float4 ta = *(const float4*)qw, tb = *(const float4*)(qw + 4);
  float4 va = *(const float4*)(qw + 32), vb = *(const float4*)(qw + 36);
  __builtin_amdgcn_sched_barrier(0);
  gload16(pa0, &sA[0][w * 32][0]);
  gload16(pa1, &sA[0][w * 32 + 16][0]);
  gload16(pa0 + 32, &sA[1][w * 32][0]);
  gload16(pa1 + 32, &sA[1][w * 32 + 16][0]);
  asm volatile("s_waitcnt vmcnt(6)" ::: "memory");   // ta/tb ready
  cvtwr8(ta, tb, &sW[0][rW][uW]);
  for (int ks = 0; ks < NK; ks++) {
    int cur = ks % 3;
    if (ks == 0)           asm volatile("s_waitcnt vmcnt(2) lgkmcnt(0)" ::: "memory");
    else if (ks == NK - 1) asm volatile("s_waitcnt vmcnt(0) lgkmcnt(0)" ::: "memory");
    else                   asm volatile("s_waitcnt vmcnt(4) lgkmcnt(0)" ::: "memory");
    __builtin_amdgcn_s_barrier();
    short8 af[4], bfr[2];
#pragma unroll
    for (int i = 0; i < 4; i++)
      af[i] = *(short8*)&sA[cur][wm * 64 + i * 16 + qi][g * 8];
#pragma unroll
    for (int ni = 0; ni < 2; ni++) {
      int rt = wn * 32 + ni * 16 + qi;
      bfr[ni] = *(short8*)&sW[cur][rt][(g ^ (rt & 3)) * 8];
    }
    __builtin_amdgcn_s_setprio(1);
#pragma unroll
    for (int mi = 0; mi < 4; mi++)
#pragma unroll
      for (int ni = 0; ni < 2; ni++)
        acc[mi][ni] = __builtin_amdgcn_mfma_f32_16x16x32_bf16(af[mi], bfr[ni], acc[mi][ni], 0, 0, 0);
    __builtin_amdgcn_s_setprio(0);
    if (ks < NK - 1) {
      int nb = (ks + 1) % 3;
      cvtwr8(va, vb, &sW[nb][rW][uW]);
      if (ks < NK - 2) {
        int k2 = (ks + 2) * 32;
        va = *(const float4*)(qw + k2); vb = *(const float4*)(qw + k2 + 4);
        __builtin_amdgcn_sched_barrier(0);
        int ab = (ks + 2) % 3;
        gload16(pa0 + k2, &sA[ab][w * 32][0]);
        gload16(pa1 + k2, &sA[ab][w * 32 + 16][0]);
      }
    }
  }
#pragma unroll
  for (int mi = 0; mi < 4; mi++)
#pragma unroll
    for (int r = 0; r < 4; r++) {
      int row = bm * 128 + wm * 64 + mi * 16 + g * 4 + r;
      if (row < count) {
        int p = off + row;
        int t = pair_tok[p];
        float wgt = pair_w[p];
        size_t obase = ((size_t)pair_slot[p] * TQ + t) * DM + bn * 64 + wn * 32;
#pragma unroll
        for (int ni = 0; ni < 2; ni++)
          pout[obase + ni * 16 + qi] = acc[mi][ni][r] * wgt;
      }
    }
}

// ---------------- final combine -----------------------------------------------
__global__ __launch_bounds__(256) void combine_kernel(
    const float* __restrict__ h, const float* __restrict__ pout, float* __restrict__ out) {
  size_t i = (size_t)blockIdx.x * 256 + threadIdx.x;
  float4 a = ((const float4*)h)[i];
  float4 b0 = ((const float4*)pout)[i];
  float4 b1 = ((const float4*)pout)[i + (size_t)TQ * DM / 4];
  float4 r;
  r.x = a.x + b0.x + b1.x; r.y = a.y + b0.y + b1.y;
  r.z = a.z + b0.z + b1.z; r.w = a.w + b0.w + b1.w;
  ((float4*)out)[i] = r;
}

// ================================================================================
extern "C" void kernel_launch(void* const* d_in, const int* in_sizes, int n_in,
                              void* d_out, int out_size, void* d_ws, size_t ws_size,
                              hipStream_t stream) {
  (void)in_sizes; (void)n_in; (void)out_size; (void)ws_size;
  const float* x    = (const float*)d_in[0];
  const float* ln1  = (const float*)d_in[1];
  const float* ln2  = (const float*)d_in[2];
  const float* wq   = (const float*)d_in[3];
  const float* wk   = (const float*)d_in[4];
  const float* wv   = (const float*)d_in[5];
  const float* wo   = (const float*)d_in[6];
  const float* gw   = (const float*)d_in[7];
  const float* w1   = (const float*)d_in[8];
  const float* w2   = (const float*)d_in[9];
  const float* w3   = (const float*)d_in[10];
  const float* cosT = (const float*)d_in[11];
  const float* sinT = (const float*)d_in[12];

  char* mb = (char*)d_ws;
  const size_t MB = 1024 * 1024;
  u16*   qhb  = (u16*)(mb + 0 * MB);        // rope->attn
  u16*   qlb  = (u16*)(mb + 4 * MB);
  u16*   khb  = (u16*)(mb + 8 * MB);
  u16*   klb  = (u16*)(mb + 9 * MB);
  u16*   vhb  = (u16*)(mb + 10 * MB);
  u16*   vlb  = (u16*)(mb + 11 * MB);
  u16*   hn2b = (u16*)(mb + 0 * MB);        // rmsnorm2->gather (after attn)
  u16*   ahb  = (u16*)(mb + 12 * MB);       // attn->gemm_o
  u16*   alb  = (u16*)(mb + 16 * MB);
  u16*   Xg   = (u16*)(mb + 12 * MB);       // gather->gemm13 (after gemm_o)
  u16*   hn1h = (u16*)(mb + 20 * MB);       // rmsnorm1->qkv
  u16*   hn1l = (u16*)(mb + 24 * MB);
  u16*   inter= (u16*)(mb + 20 * MB);       // gemm13->gemm2 (28 MiB)
  float* qkvf = (float*)(mb + 28 * MB);     // qkv->rope (12 MiB)
  float* h_res= (float*)(mb + 48 * MB);     // gemm_o->end (8 MiB)
  u16*   woh  = (u16*)(mb + 56 * MB);       // wconv->gemm_o (2 MiB)
  u16*   wol  = (u16*)(mb + 58 * MB);
  float* pout = (float*)(mb + 56 * MB);     // gemm2->combine (16 MiB)
  u16*   wqkvh= (u16*)(mb + 60 * MB);       // wconv->qkv (3 MiB)
  u16*   wqkvl= (u16*)(mb + 63 * MB);
  int*   cnt  = (int*)(mb + 72 * MB);
  int*   offs = cnt + 8;
  int*   mtp  = cnt + 16;
  int*   row_e  = cnt + 17;                 // 40
  int*   row_bm = cnt + 57;                 // 40
  int*   tok_e  = cnt + 128;
  int*   tok_pos = tok_e + 4096;
  float* tok_w   = (float*)(tok_pos + 4096);
  int*   pair_tok  = (int*)(tok_w + 4096);
  int*   pair_slot = pair_tok + 4096;
  float* pair_w    = (float*)(pair_slot + 4096);

  fused_pre_kernel<<<2688, 256, 0, stream>>>(x, ln1, hn1h, hn1l,
                                             wq, wk, wv, wo,
                                             wqkvh, wqkvl, woh, wol);
  gemm_split3_kernel<false><<<384, 256, 0, stream>>>(hn1h, hn1l, wqkvh, wqkvl, qkvf, nullptr, 1536, 48);
  rope_split_kernel<<<TQ, 256, 0, stream>>>(qkvf, cosT, sinT, qhb, qlb, khb, klb, vhb, vlb);
  attn_kernel<<<512, 256, 0, stream>>>(qhb, qlb, khb, klb, vhb, vlb, ahb, alb);
  gemm_split3_kernel<true><<<256, 256, 0, stream>>>(ahb, alb, woh, wol, h_res, x, 1024, 32);
  zero8_kernel<<<1, 64, 0, stream>>>(cnt);
  rmsnorm_gate_kernel<<<TQ, 256, 0, stream>>>(h_res, ln2, gw, hn2b,
                                              cnt, tok_e, tok_pos, tok_w);
  schedule_kernel<<<1, 64, 0, stream>>>(cnt, offs, mtp, row_e, row_bm);
  gather_kernel<<<TQ, 256, 0, stream>>>(hn2b, tok_e, tok_pos, tok_w, offs, Xg,
                                        pair_tok, pair_slot, pair_w);
  moe_gemm13_kernel<<<2240, 256, 0, stream>>>(Xg, w1, w3, cnt, offs, mtp,
                                              row_e, row_bm, inter);
  moe_gemm2_kernel<<<640, 256, 0, stream>>>(inter, w2, cnt, offs, mtp,
                                            row_e, row_bm,
                                            pair_tok, pair_slot, pair_w, pout);
  combine_kernel<<<TQ, 256, 0, stream>>>(h_res, pout, (float*)d_out);
}

// Round 14
// 431.087 us; speedup vs baseline: 1.6002x; 1.0132x over previous
//
#include <hip/hip_runtime.h>

typedef unsigned short u16;
using short8 = __attribute__((ext_vector_type(8))) short;
using f32x4  = __attribute__((ext_vector_type(4))) float;

#define TQ   2048
#define DM   1024
#define SLEN 1024
#define FDIM 3584
#define NEXP 8

static __device__ __forceinline__ u16 f2bf(float f) {
  union { float f; unsigned u; } a; a.f = f;
  unsigned r = a.u + 0x7fffu + ((a.u >> 16) & 1u);
  return (u16)(r >> 16);
}
static __device__ __forceinline__ float bf2f(u16 u) {
  union { unsigned u; float f; } a; a.u = ((unsigned)u) << 16;
  return a.f;
}
static __device__ __forceinline__ unsigned cvtpk(float lo, float hi) {
  unsigned r;
  asm volatile("v_cvt_pk_bf16_f32 %0, %1, %2" : "=v"(r) : "v"(lo), "v"(hi));
  return r;
}

static __device__ __forceinline__ void gload16(const void* g, void* l) {
  __builtin_amdgcn_global_load_lds((const __attribute__((address_space(1))) void*)g,
                                   (__attribute__((address_space(3))) void*)l, 16, 0, 0);
}

// T1 chunked XCD swizzle
static __device__ __forceinline__ int xcd_lid(int bid, int cpx) {
  return (bid & 7) * cpx + (bid >> 3);
}

// convert 8 f32 (2 float4) -> 8 bf16 (16B) and ds_write_b128
static __device__ __forceinline__ void cvtwr8(float4 a, float4 b, u16* dst) {
  uint4 u;
  u.x = cvtpk(a.x, a.y); u.y = cvtpk(a.z, a.w);
  u.z = cvtpk(b.x, b.y); u.w = cvtpk(b.z, b.w);
  *(uint4*)dst = u;
}

// ------- fused: rmsnorm1 (blocks 0..2047) + qkv/o weight split-conv (rest) ---
__global__ __launch_bounds__(256) void fused_pre_kernel(
    const float* __restrict__ x, const float* __restrict__ ln1,
    u16* __restrict__ oh, u16* __restrict__ ol,
    const float* __restrict__ wq, const float* __restrict__ wk,
    const float* __restrict__ wv, const float* __restrict__ wo,
    u16* __restrict__ qkvh, u16* __restrict__ qkvl,
    u16* __restrict__ woh, u16* __restrict__ wol) {
  int tid = threadIdx.x;
  if (blockIdx.x < 2048) {
    int t = blockIdx.x;
    const float4* xr = (const float4*)(x + (size_t)t * DM);
    float4 v = xr[tid];
    float ss = v.x * v.x + v.y * v.y + v.z * v.z + v.w * v.w;
#pragma unroll
    for (int m = 1; m < 64; m <<= 1) ss += __shfl_xor(ss, m);
    __shared__ float red[4];
    if ((tid & 63) == 0) red[tid >> 6] = ss;
    __syncthreads();
    float tot = red[0] + red[1] + red[2] + red[3];
    float sc = rsqrtf(tot * (1.0f / DM) + 1e-5f);
    float4 wv_ = ((const float4*)ln1)[tid];
    float o0 = v.x * sc * wv_.x, o1 = v.y * sc * wv_.y;
    float o2 = v.z * sc * wv_.z, o3 = v.w * sc * wv_.w;
    ushort4 hh;
    hh.x = f2bf(o0); hh.y = f2bf(o1); hh.z = f2bf(o2); hh.w = f2bf(o3);
    *(ushort4*)(oh + (size_t)t * DM + tid * 4) = hh;
    ushort4 ll;
    ll.x = f2bf(o0 - bf2f(hh.x)); ll.y = f2bf(o1 - bf2f(hh.y));
    ll.z = f2bf(o2 - bf2f(hh.z)); ll.w = f2bf(o3 - bf2f(hh.w));
    *(ushort4*)(ol + (size_t)t * DM + tid * 4) = ll;
    return;
  }
  int wb = blockIdx.x - 2048;   // 0..639
  for (int i = wb * 256 + tid; i < 655360; i += 640 * 256) {
    int el = i * 4;
    const float* src; u16 *dh, *dl;
    if (el < 1572864) {
      int r = el >> 10, c = el & 1023;
      if (r < 1024) src = wq + el;
      else if (r < 1280) src = wk + (r - 1024) * 1024 + c;
      else src = wv + (r - 1280) * 1024 + c;
      dh = qkvh + el; dl = qkvl + el;
    } else {
      int e2 = el - 1572864;
      src = wo + e2; dh = woh + e2; dl = wol + e2;
    }
    float4 v = *(const float4*)src;
    ushort4 h, l;
    h.x = f2bf(v.x); h.y = f2bf(v.y); h.z = f2bf(v.z); h.w = f2bf(v.w);
    l.x = f2bf(v.x - bf2f(h.x)); l.y = f2bf(v.y - bf2f(h.y));
    l.z = f2bf(v.z - bf2f(h.z)); l.w = f2bf(v.w - bf2f(h.w));
    *(ushort4*)dh = h; *(ushort4*)dl = l;
  }
}

// ------- fused rmsnorm2 + gate: bf16 out + top-2 routing ----------------------
__global__ __launch_bounds__(256) void rmsnorm_gate_kernel(
    const float* __restrict__ x, const float* __restrict__ w,
    const float* __restrict__ gw, u16* __restrict__ oh,
    int* cnt, int* tok_e, int* tok_pos, float* tok_w) {
  int t = blockIdx.x, tid = threadIdx.x;
  float4 v = ((const float4*)(x + (size_t)t * DM))[tid];
  float ss = v.x * v.x + v.y * v.y + v.z * v.z + v.w * v.w;
#pragma unroll
  for (int m = 1; m < 64; m <<= 1) ss += __shfl_xor(ss, m);
  __shared__ float red[4];
  __shared__ float gred[4][8];
  if ((tid & 63) == 0) red[tid >> 6] = ss;
  __syncthreads();
  float tot = red[0] + red[1] + red[2] + red[3];
  float sc = rsqrtf(tot * (1.0f / DM) + 1e-5f);
  float4 wv_ = ((const float4*)w)[tid];
  float o0 = v.x * sc * wv_.x, o1 = v.y * sc * wv_.y;
  float o2 = v.z * sc * wv_.z, o3 = v.w * sc * wv_.w;
  ushort4 hh;
  hh.x = f2bf(o0); hh.y = f2bf(o1); hh.z = f2bf(o2); hh.w = f2bf(o3);
  *(ushort4*)(oh + (size_t)t * DM + tid * 4) = hh;
  float acc[8];
#pragma unroll
  for (int e = 0; e < 8; e++) {
    float4 ge = ((const float4*)(gw + e * DM))[tid];
    acc[e] = o0 * ge.x + o1 * ge.y + o2 * ge.z + o3 * ge.w;
  }
#pragma unroll
  for (int e = 0; e < 8; e++)
#pragma unroll
    for (int m = 1; m < 64; m <<= 1) acc[e] += __shfl_xor(acc[e], m);
  int lane = tid & 63, wvi = tid >> 6;
  if (lane == 0)
#pragma unroll
    for (int e = 0; e < 8; e++) gred[wvi][e] = acc[e];
  __syncthreads();
  if (tid == 0) {
    float l[8];
#pragma unroll
    for (int e = 0; e < 8; e++)
      l[e] = gred[0][e] + gred[1][e] + gred[2][e] + gred[3][e];
    int i0 = 0;
#pragma unroll
    for (int e = 1; e < 8; e++) if (l[e] > l[i0]) i0 = e;
    int i1 = -1;
#pragma unroll
    for (int e = 0; e < 8; e++) if (e != i0 && (i1 < 0 || l[e] > l[i1])) i1 = e;
    float w0 = 1.0f;
    float w1 = expf(l[i1] - l[i0]);
    float rs = 1.0f / (w0 + w1);
    int p0 = atomicAdd(&cnt[i0], 1);
    int p1 = atomicAdd(&cnt[i1], 1);
    tok_e[t * 2] = i0; tok_e[t * 2 + 1] = i1;
    tok_pos[t * 2] = p0; tok_pos[t * 2 + 1] = p1;
    tok_w[t * 2] = w0 * rs; tok_w[t * 2 + 1] = w1 * rs;
  }
}

// ------- fused QKV GEMM + RoPE + split-bf16 epilogue --------------------------
// C-tile(128 x 64) spans exactly one head (q: bn<16, k: bn in 16..19,
// v: bn in 20..23). After the counted depth-3 K-loop, acc is staged to LDS
// (aliased over dead staging buffers), rope applied per (d, d+32) pair, and
// split-bf16 q/k/v written in final layout. Numerically identical to the old
// gemm->qkvf->rope path.
__global__ __launch_bounds__(256) void qkv_rope_kernel(
    const u16* __restrict__ Ah, const u16* __restrict__ Al,
    const u16* __restrict__ Wh, const u16* __restrict__ Wl,
    const float* __restrict__ cosT, const float* __restrict__ sinT,
    u16* __restrict__ qh, u16* __restrict__ ql,
    u16* __restrict__ kh, u16* __restrict__ kl,
    u16* __restrict__ vh, u16* __restrict__ vl, int cpx) {
  __shared__ __align__(16) char pool[73728];
  u16 (*sAh)[128][32] = (u16(*)[128][32])pool;
  u16 (*sAl)[128][32] = (u16(*)[128][32])(pool + 24576);
  u16 (*sWh)[64][32]  = (u16(*)[64][32])(pool + 49152);
  u16 (*sWl)[64][32]  = (u16(*)[64][32])(pool + 61440);
  float (*sEpi)[65]   = (float(*)[65])pool;          // 128*65*4 = 33280 B
  int lid = xcd_lid(blockIdx.x, cpx);
  int bm = lid & 15, bn = lid >> 4;                  // bn 0..23
  int tid = threadIdx.x, lane = tid & 63, w = tid >> 6;
  int wm = w >> 1, wn = w & 1;
  int qi = lane & 15, g = lane >> 4;
  int lr = lane >> 2, lc = (lane & 3) * 8;
  const u16* pa0 = Ah + (size_t)(bm * 128 + w * 16 + lr) * DM + lc;
  const u16* pa1 = pa0 + 64 * DM;
  const u16* pl0 = Al + (size_t)(bm * 128 + w * 16 + lr) * DM + lc;
  const u16* pl1 = pl0 + 64 * DM;
  const u16* pw  = Wh + (size_t)(bn * 64 + w * 16 + lr) * DM + lc;
  const u16* pwl = Wl + (size_t)(bn * 64 + w * 16 + lr) * DM + lc;
  f32x4 acc[4][2] = {};
#define STGQ(buf, kk) do { \
    gload16(pa0 + (kk), &sAh[buf][w * 16][0]); \
    gload16(pa1 + (kk), &sAh[buf][64 + w * 16][0]); \
    gload16(pl0 + (kk), &sAl[buf][w * 16][0]); \
    gload16(pl1 + (kk), &sAl[buf][64 + w * 16][0]); \
    gload16(pw  + (kk), &sWh[buf][w * 16][0]); \
    gload16(pwl + (kk), &sWl[buf][w * 16][0]); } while (0)
  STGQ(0, 0);
  STGQ(1, 32);
  for (int ks = 0; ks < 32; ks++) {
    int cur = ks % 3;
    if (ks == 31) asm volatile("s_waitcnt vmcnt(0) lgkmcnt(0)" ::: "memory");
    else          asm volatile("s_waitcnt vmcnt(6) lgkmcnt(0)" ::: "memory");
    __builtin_amdgcn_s_barrier();
    short8 afh[4], afl[4], bfh[2], bfl[2];
#pragma unroll
    for (int i = 0; i < 4; i++) {
      afh[i] = *(short8*)&sAh[cur][wm * 64 + i * 16 + qi][g * 8];
      afl[i] = *(short8*)&sAl[cur][wm * 64 + i * 16 + qi][g * 8];
    }
#pragma unroll
    for (int i = 0; i < 2; i++) {
      bfh[i] = *(short8*)&sWh[cur][wn * 32 + i * 16 + qi][g * 8];
      bfl[i] = *(short8*)&sWl[cur][wn * 32 + i * 16 + qi][g * 8];
    }
    __builtin_amdgcn_s_setprio(1);
#pragma unroll
    for (int mi = 0; mi < 4; mi++)
#pragma unroll
      for (int ni = 0; ni < 2; ni++) {
        f32x4 a = acc[mi][ni];
        a = __builtin_amdgcn_mfma_f32_16x16x32_bf16(afh[mi], bfh[ni], a, 0, 0, 0);
        a = __builtin_amdgcn_mfma_f32_16x16x32_bf16(afl[mi], bfh[ni], a, 0, 0, 0);
        a = __builtin_amdgcn_mfma_f32_16x16x32_bf16(afh[mi], bfl[ni], a, 0, 0, 0);
        acc[mi][ni] = a;
      }
    __builtin_amdgcn_s_setprio(0);
    if (ks < 30) STGQ((ks + 2) % 3, (ks + 2) * 32);
  }
#undef STGQ
  // ---- epilogue: stage acc to LDS (aliased), rope, split-bf16 store ----
  __syncthreads();
#pragma unroll
  for (int mi = 0; mi < 4; mi++)
#pragma unroll
    for (int ni = 0; ni < 2; ni++)
#pragma unroll
      for (int r = 0; r < 4; r++)
        sEpi[wm * 64 + mi * 16 + g * 4 + r][wn * 32 + ni * 16 + qi] = acc[mi][ni][r];
  __syncthreads();
  int r0 = tid >> 1, hc = (tid & 1) * 16;
  int t = bm * 128 + r0;
  int s = t & (SLEN - 1);
  union { ushort u[16]; uint4 v[2]; } h1, l1, h2, l2;
  if (bn < 20) {
    // rope path (q or k)
#pragma unroll
    for (int j = 0; j < 16; j++) {
      int d = hc + j;
      float c = cosT[s * 64 + d], sn = sinT[s * 64 + d];
      float x1 = sEpi[r0][d], x2 = sEpi[r0][d + 32];
      float o1 = x1 * c - x2 * sn;
      float o2 = x2 * c + x1 * sn;
      h1.u[j] = f2bf(o1); l1.u[j] = f2bf(o1 - bf2f(h1.u[j]));
      h2.u[j] = f2bf(o2); l2.u[j] = f2bf(o2 - bf2f(h2.u[j]));
    }
    u16 *dh, *dl; size_t base;
    if (bn < 16) { dh = qh; dl = ql; base = (size_t)t * DM + bn * 64; }
    else         { dh = kh; dl = kl; base = (size_t)t * 256 + (bn - 16) * 64; }
    *(uint4*)(dh + base + hc)      = h1.v[0];
    *(uint4*)(dh + base + hc + 8)  = h1.v[1];
    *(uint4*)(dh + base + 32 + hc)     = h2.v[0];
    *(uint4*)(dh + base + 32 + hc + 8) = h2.v[1];
    *(uint4*)(dl + base + hc)      = l1.v[0];
    *(uint4*)(dl + base + hc + 8)  = l1.v[1];
    *(uint4*)(dl + base + 32 + hc)     = l2.v[0];
    *(uint4*)(dl + base + 32 + hc + 8) = l2.v[1];
  } else {
    // v path: plain split convert
#pragma unroll
    for (int j = 0; j < 16; j++) {
      float x1 = sEpi[r0][hc + j], x2 = sEpi[r0][hc + 32 + j];
      h1.u[j] = f2bf(x1); l1.u[j] = f2bf(x1 - bf2f(h1.u[j]));
      h2.u[j] = f2bf(x2); l2.u[j] = f2bf(x2 - bf2f(h2.u[j]));
    }
    size_t base = (size_t)t * 256 + (bn - 20) * 64;
    *(uint4*)(vh + base + hc)      = h1.v[0];
    *(uint4*)(vh + base + hc + 8)  = h1.v[1];
    *(uint4*)(vh + base + 32 + hc)     = h2.v[0];
    *(uint4*)(vh + base + 32 + hc + 8) = h2.v[1];
    *(uint4*)(vl + base + hc)      = l1.v[0];
    *(uint4*)(vl + base + hc + 8)  = l1.v[1];
    *(uint4*)(vl + base + 32 + hc)     = l2.v[0];
    *(uint4*)(vl + base + 32 + hc + 8) = l2.v[1];
  }
}

// ------- split-bf16 dense GEMM, counted depth-3 pipeline (O-proj) ------------
template <bool RESID>
__global__ __launch_bounds__(256) void gemm_split3_kernel(
    const u16* __restrict__ Ah, const u16* __restrict__ Al,
    const u16* __restrict__ Wh, const u16* __restrict__ Wl,
    float* __restrict__ C, const float* __restrict__ resid, int N, int cpx) {
  __shared__ u16 sAh[3][128][32], sAl[3][128][32], sWh[3][64][32], sWl[3][64][32];
  int lid = xcd_lid(blockIdx.x, cpx);
  int bm = lid & 15, bn = lid >> 4;
  int tid = threadIdx.x, lane = tid & 63, w = tid >> 6;
  int wm = w >> 1, wn = w & 1;
  int qi = lane & 15, g = lane >> 4;
  int lr = lane >> 2, lc = (lane & 3) * 8;
  const u16* pa0 = Ah + (size_t)(bm * 128 + w * 16 + lr) * DM + lc;
  const u16* pa1 = pa0 + 64 * DM;
  const u16* pl0 = Al + (size_t)(bm * 128 + w * 16 + lr) * DM + lc;
  const u16* pl1 = pl0 + 64 * DM;
  const u16* pw  = Wh + (size_t)(bn * 64 + w * 16 + lr) * DM + lc;
  const u16* pwl = Wl + (size_t)(bn * 64 + w * 16 + lr) * DM + lc;
  f32x4 acc[4][2] = {};
#define STG3(buf, kk) do { \
    gload16(pa0 + (kk), &sAh[buf][w * 16][0]); \
    gload16(pa1 + (kk), &sAh[buf][64 + w * 16][0]); \
    gload16(pl0 + (kk), &sAl[buf][w * 16][0]); \
    gload16(pl1 + (kk), &sAl[buf][64 + w * 16][0]); \
    gload16(pw  + (kk), &sWh[buf][w * 16][0]); \
    gload16(pwl + (kk), &sWl[buf][w * 16][0]); } while (0)
  STG3(0, 0);
  STG3(1, 32);
  for (int ks = 0; ks < 32; ks++) {
    int cur = ks % 3;
    if (ks == 31) asm volatile("s_waitcnt vmcnt(0) lgkmcnt(0)" ::: "memory");
    else          asm volatile("s_waitcnt vmcnt(6) lgkmcnt(0)" ::: "memory");
    __builtin_amdgcn_s_barrier();
    short8 afh[4], afl[4], bfh[2], bfl[2];
#pragma unroll
    for (int i = 0; i < 4; i++) {
      afh[i] = *(short8*)&sAh[cur][wm * 64 + i * 16 + qi][g * 8];
      afl[i] = *(short8*)&sAl[cur][wm * 64 + i * 16 + qi][g * 8];
    }
#pragma unroll
    for (int i = 0; i < 2; i++) {
      bfh[i] = *(short8*)&sWh[cur][wn * 32 + i * 16 + qi][g * 8];
      bfl[i] = *(short8*)&sWl[cur][wn * 32 + i * 16 + qi][g * 8];
    }
    __builtin_amdgcn_s_setprio(1);
#pragma unroll
    for (int mi = 0; mi < 4; mi++)
#pragma unroll
      for (int ni = 0; ni < 2; ni++) {
        f32x4 a = acc[mi][ni];
        a = __builtin_amdgcn_mfma_f32_16x16x32_bf16(afh[mi], bfh[ni], a, 0, 0, 0);
        a = __builtin_amdgcn_mfma_f32_16x16x32_bf16(afl[mi], bfh[ni], a, 0, 0, 0);
        a = __builtin_amdgcn_mfma_f32_16x16x32_bf16(afh[mi], bfl[ni], a, 0, 0, 0);
        acc[mi][ni] = a;
      }
    __builtin_amdgcn_s_setprio(0);
    if (ks < 30) STG3((ks + 2) % 3, (ks + 2) * 32);
  }
#undef STG3
#pragma unroll
  for (int mi = 0; mi < 4; mi++)
#pragma unroll
    for (int ni = 0; ni < 2; ni++) {
      int col = bn * 64 + wn * 32 + ni * 16 + qi;
#pragma unroll
      for (int r = 0; r < 4; r++) {
        int row = bm * 128 + wm * 64 + mi * 16 + g * 4 + r;
        float val = acc[mi][ni][r];
        if (RESID) val += resid[(size_t)row * N + col];
        C[(size_t)row * N + col] = val;
      }
    }
}

// ---------------- flash attention, split-bf16, GQA 4:1, causal ---------------
// 512 blocks, complement-balanced: bid<256 -> qt=p, bid>=256 -> qt=15-p.
__global__ __launch_bounds__(256) void attn_kernel(
    const u16* __restrict__ qh, const u16* __restrict__ ql,
    const u16* __restrict__ kh, const u16* __restrict__ kl,
    const u16* __restrict__ vh, const u16* __restrict__ vl,
    u16* __restrict__ oh, u16* __restrict__ ol) {
  __shared__ u16 sKh[64][72], sKl[64][72];
  __shared__ u16 sVh[64][72], sVl[64][72];
  __shared__ u16 sPh[4][16][72], sPl[4][16][72];
  int idx = blockIdx.x & 255;
  int p = idx & 7;
  int bh = idx >> 3;
  int b = bh >> 4, h = bh & 15, kvh = h >> 2;
  int qt = (blockIdx.x < 256) ? p : (15 - p);
  int tid = threadIdx.x, lane = tid & 63, w = tid >> 6;
  int qi = lane & 15, g = lane >> 4;
  int qrow = qt * 64 + w * 16 + qi;
  size_t qbase = ((size_t)(b * SLEN + qrow)) * DM + h * 64;
  short8 qfh[2], qfl[2];
#pragma unroll
  for (int ds = 0; ds < 2; ds++) {
    qfh[ds] = *(const short8*)(qh + qbase + ds * 32 + g * 8);
    qfl[ds] = *(const short8*)(ql + qbase + ds * 32 + g * 8);
  }
  f32x4 oacc[4] = {};
  float mrun = -1e30f, lrun = 0.f;
  int ktiles = qt + 1;
  for (int kt = 0; kt < ktiles; kt++) {
    __syncthreads();
    {
      int r = tid >> 3, cs = (tid & 7) * 8;
#pragma unroll
      for (int rr = 0; rr < 64; rr += 32) {
        int key = kt * 64 + rr + r;
        size_t src = ((size_t)(b * SLEN + key)) * 256 + kvh * 64 + cs;
        *(short8*)&sKh[rr + r][cs] = *(const short8*)(kh + src);
        *(short8*)&sKl[rr + r][cs] = *(const short8*)(kl + src);
        short8 vv = *(const short8*)(vh + src);
        short8 vv2 = *(const short8*)(vl + src);
#pragma unroll
        for (int j = 0; j < 8; j++) {
          sVh[cs + j][rr + r] = (u16)vv[j];
          sVl[cs + j][rr + r] = (u16)vv2[j];
        }
      }
    }
    __syncthreads();
    f32x4 sa[4];
#pragma unroll
    for (int kf = 0; kf < 4; kf++) {
      f32x4 a = {};
#pragma unroll
      for (int ds = 0; ds < 2; ds++) {
        short8 kfh = *(short8*)&sKh[kf * 16 + qi][ds * 32 + g * 8];
        short8 kfl = *(short8*)&sKl[kf * 16 + qi][ds * 32 + g * 8];
        a = __builtin_amdgcn_mfma_f32_16x16x32_bf16(kfh, qfh[ds], a, 0, 0, 0);
        a = __builtin_amdgcn_mfma_f32_16x16x32_bf16(kfl, qfh[ds], a, 0, 0, 0);
        a = __builtin_amdgcn_mfma_f32_16x16x32_bf16(kfh, qfl[ds], a, 0, 0, 0);
      }
      sa[kf] = a;
    }
    int qg = qt * 64 + w * 16 + qi;
    float sv[4][4];
    float tmax = -1e30f;
#pragma unroll
    for (int kf = 0; kf < 4; kf++)
#pragma unroll
      for (int r = 0; r < 4; r++) {
        int key = kt * 64 + kf * 16 + g * 4 + r;
        float s = sa[kf][r] * 0.125f;
        s = (key <= qg) ? s : -1e30f;
        sv[kf][r] = s;
        tmax = fmaxf(tmax, s);
      }
    tmax = fmaxf(tmax, __shfl_xor(tmax, 16));
    tmax = fmaxf(tmax, __shfl_xor(tmax, 32));
    float mn = fmaxf(mrun, tmax);
    float alpha = expf(mrun - mn);
    float psum = 0.f;
#pragma unroll
    for (int kf = 0; kf < 4; kf++) {
      float p0 = expf(sv[kf][0] - mn), p1 = expf(sv[kf][1] - mn);
      float p2 = expf(sv[kf][2] - mn), p3 = expf(sv[kf][3] - mn);
      psum += p0 + p1 + p2 + p3;
      ushort4 ph, pl;
      ph.x = f2bf(p0); ph.y = f2bf(p1); ph.z = f2bf(p2); ph.w = f2bf(p3);
      pl.x = f2bf(p0 - bf2f(ph.x)); pl.y = f2bf(p1 - bf2f(ph.y));
      pl.z = f2bf(p2 - bf2f(ph.z)); pl.w = f2bf(p3 - bf2f(ph.w));
      *(ushort4*)&sPh[w][qi][kf * 16 + g * 4] = ph;
      *(ushort4*)&sPl[w][qi][kf * 16 + g * 4] = pl;
    }
    psum += __shfl_xor(psum, 16);
    psum += __shfl_xor(psum, 32);
    lrun = lrun * alpha + psum;
    mrun = mn;
#pragma unroll
    for (int df = 0; df < 4; df++) {
      oacc[df][0] *= alpha; oacc[df][1] *= alpha;
      oacc[df][2] *= alpha; oacc[df][3] *= alpha;
    }
#pragma unroll
    for (int ks = 0; ks < 2; ks++) {
      short8 pfh = *(short8*)&sPh[w][qi][ks * 32 + g * 8];
      short8 pfl = *(short8*)&sPl[w][qi][ks * 32 + g * 8];
#pragma unroll
      for (int df = 0; df < 4; df++) {
        short8 vfh = *(short8*)&sVh[df * 16 + qi][ks * 32 + g * 8];
        short8 vfl = *(short8*)&sVl[df * 16 + qi][ks * 32 + g * 8];
        f32x4 a = oacc[df];
        a = __builtin_amdgcn_mfma_f32_16x16x32_bf16(vfh, pfh, a, 0, 0, 0);
        a = __builtin_amdgcn_mfma_f32_16x16x32_bf16(vfl, pfh, a, 0, 0, 0);
        a = __builtin_amdgcn_mfma_f32_16x16x32_bf16(vfh, pfl, a, 0, 0, 0);
        oacc[df] = a;
      }
    }
  }
  float inv = 1.0f / lrun;
  size_t obase = ((size_t)(b * SLEN + qt * 64 + w * 16 + qi)) * DM + h * 64;
#pragma unroll
  for (int df = 0; df < 4; df++) {
    float o0 = oacc[df][0] * inv, o1 = oacc[df][1] * inv;
    float o2 = oacc[df][2] * inv, o3 = oacc[df][3] * inv;
    ushort4 hh, ll;
    hh.x = f2bf(o0); hh.y = f2bf(o1); hh.z = f2bf(o2); hh.w = f2bf(o3);
    ll.x = f2bf(o0 - bf2f(hh.x)); ll.y = f2bf(o1 - bf2f(hh.y));
    ll.z = f2bf(o2 - bf2f(hh.z)); ll.w = f2bf(o3 - bf2f(hh.w));
    *(ushort4*)(oh + obase + df * 16 + g * 4) = hh;
    *(ushort4*)(ol + obase + df * 16 + g * 4) = ll;
  }
}

// ---------------- routing helpers --------------------------------------------
__global__ void zero8_kernel(int* p) { if (threadIdx.x < 8) p[threadIdx.x] = 0; }

__global__ void schedule_kernel(const int* cnt, int* offs, int* mt,
                                int* row_e, int* row_bm) {
  if (threadIdx.x == 0) {
    int s = 0, m = 0;
    for (int e = 0; e < 8; e++) {
      offs[e] = s;
      int nb = (cnt[e] + 127) >> 7;
      for (int i = 0; i < nb; i++) { row_e[m] = e; row_bm[m] = i; m++; }
      s += cnt[e];
    }
    *mt = m;
  }
}

__global__ __launch_bounds__(256) void gather_kernel(
    const u16* __restrict__ hn2b, const int* __restrict__ tok_e,
    const int* __restrict__ tok_pos, const float* __restrict__ tok_w,
    const int* __restrict__ offs, u16* __restrict__ Xg,
    int* __restrict__ pair_tok, int* __restrict__ pair_slot, float* __restrict__ pair_w) {
  int t = blockIdx.x;
#pragma unroll
  for (int slot = 0; slot < 2; slot++) {
    int e = tok_e[t * 2 + slot];
    int p = offs[e] + tok_pos[t * 2 + slot];
    ((ushort4*)(Xg + (size_t)p * DM))[threadIdx.x] =
        ((const ushort4*)(hn2b + (size_t)t * DM))[threadIdx.x];
    if (threadIdx.x == 0) {
      pair_tok[p] = t; pair_slot[p] = slot; pair_w[p] = tok_w[t * 2 + slot];
    }
  }
}

// ---- grouped MoE GEMM 1&3: r8 structure (frozen best) ------------------------
__global__ __launch_bounds__(256) void moe_gemm13_kernel(
    const u16* __restrict__ Xg, const float* __restrict__ w1,
    const float* __restrict__ w3, const int* __restrict__ cnt,
    const int* __restrict__ offs, const int* __restrict__ mt,
    const int* __restrict__ row_e, const int* __restrict__ row_bm,
    u16* __restrict__ inter) {
  __shared__ u16 sA[3][128][32];
  __shared__ u16 sW1[3][64][32], sW3[3][64][32];
  int MT = *mt;
  int active = MT * 56;
  int cpx = (active + 7) >> 3;
  int xg8 = blockIdx.x >> 3;
  if (xg8 >= cpx) return;
  int lid = (blockIdx.x & 7) * cpx + xg8;
  if (lid >= active) return;
  int mrow = lid % MT, bn = lid / MT;
  int e = row_e[mrow], bm = row_bm[mrow];
  int count = cnt[e], off = offs[e];
  const u16* A = Xg + (size_t)off * DM;
  const float* W1 = w1 + (size_t)e * FDIM * DM;
  const float* W3 = w3 + (size_t)e * FDIM * DM;
  int tid = threadIdx.x, lane = tid & 63, w = tid >> 6;
  int wm = w >> 1, wn = w & 1;
  int qi = lane & 15, g = lane >> 4;
  int lrA = lane >> 2, lcA = (lane & 3) * 8;
  int ga0 = bm * 128 + w * 32 + lrA;      if (ga0 >= count) ga0 = count - 1;
  int ga1 = bm * 128 + w * 32 + 16 + lrA; if (ga1 >= count) ga1 = count - 1;
  const u16* pa0 = A + (size_t)ga0 * DM + lcA;
  const u16* pa1 = A + (size_t)ga1 * DM + lcA;
  int r16 = lane >> 2;
  int rW = w * 16 + r16;
  int cW = (lane & 3) * 8;
  const float* q1 = W1 + (size_t)(bn * 64 + rW) * DM + cW;
  const float* q3 = W3 + (size_t)(bn * 64 + rW) * DM + cW;
  int uW = ((lane & 3) ^ (r16 & 3)) * 8;
  f32x4 acc1[4][2] = {}, acc3[4][2] = {};
  float4 p1a = *(const float4*)q1, p1b = *(const float4*)(q1 + 4);
  float4 p3a = *(const float4*)q3, p3b = *(const float4*)(q3 + 4);
  float4 v1a = *(const float4*)(q1 + 32), v1b = *(const float4*)(q1 + 36);
  float4 v3a = *(const float4*)(q3 + 32), v3b = *(const float4*)(q3 + 36);
  __builtin_amdgcn_sched_barrier(0);
  gload16(pa0, &sA[0][w * 32][0]);
  gload16(pa1, &sA[0][w * 32 + 16][0]);
  gload16(pa0 + 32, &sA[1][w * 32][0]);
  gload16(pa1 + 32, &sA[1][w * 32 + 16][0]);
  asm volatile("s_waitcnt vmcnt(8)" ::: "memory");
  cvtwr8(p1a, p1b, &sW1[0][rW][uW]);
  cvtwr8(p3a, p3b, &sW3[0][rW][uW]);
  for (int ks = 0; ks < 32; ks++) {
    int cur = ks % 3;
    if (ks == 0)       asm volatile("s_waitcnt vmcnt(2) lgkmcnt(0)" ::: "memory");
    else if (ks == 31) asm volatile("s_waitcnt vmcnt(0) lgkmcnt(0)" ::: "memory");
    else               asm volatile("s_waitcnt vmcnt(6) lgkmcnt(0)" ::: "memory");
    __builtin_amdgcn_s_barrier();
    short8 af[4], b1[2], b3[2];
#pragma unroll
    for (int i = 0; i < 4; i++)
      af[i] = *(short8*)&sA[cur][wm * 64 + i * 16 + qi][g * 8];
#pragma unroll
    for (int ni = 0; ni < 2; ni++) {
      int rt = wn * 32 + ni * 16 + qi;
      int ui = (g ^ (rt & 3)) * 8;
      b1[ni] = *(short8*)&sW1[cur][rt][ui];
      b3[ni] = *(short8*)&sW3[cur][rt][ui];
    }
    __builtin_amdgcn_s_setprio(1);
#pragma unroll
    for (int mi = 0; mi < 4; mi++)
#pragma unroll
      for (int ni = 0; ni < 2; ni++) {
        acc1[mi][ni] = __builtin_amdgcn_mfma_f32_16x16x32_bf16(af[mi], b1[ni], acc1[mi][ni], 0, 0, 0);
        acc3[mi][ni] = __builtin_amdgcn_mfma_f32_16x16x32_bf16(af[mi], b3[ni], acc3[mi][ni], 0, 0, 0);
      }
    __builtin_amdgcn_s_setprio(0);
    if (ks < 31) {
      int nb = (ks + 1) % 3;
      cvtwr8(v1a, v1b, &sW1[nb][rW][uW]);
      cvtwr8(v3a, v3b, &sW3[nb][rW][uW]);
      if (ks < 30) {
        int k2 = (ks + 2) * 32;
        v1a = *(const float4*)(q1 + k2); v1b = *(const float4*)(q1 + k2 + 4);
        v3a = *(const float4*)(q3 + k2); v3b = *(const float4*)(q3 + k2 + 4);
        __builtin_amdgcn_sched_barrier(0);
        int ab = (ks + 2) % 3;
        gload16(pa0 + k2, &sA[ab][w * 32][0]);
        gload16(pa1 + k2, &sA[ab][w * 32 + 16][0]);
      }
    }
  }
#pragma unroll
  for (int mi = 0; mi < 4; mi++)
#pragma unroll
    for (int r = 0; r < 4; r++) {
      int row = bm * 128 + wm * 64 + mi * 16 + g * 4 + r;
      if (row < count) {
        size_t obase = (size_t)(off + row) * FDIM + bn * 64 + wn * 32;
#pragma unroll
        for (int ni = 0; ni < 2; ni++) {
          float c1 = acc1[mi][ni][r], c3 = acc3[mi][ni][r];
          float sv = c1 / (1.0f + expf(-c1)) * c3;
          inter[obase + ni * 16 + qi] = f2bf(sv);
        }
      }
    }
}

// ---- grouped MoE GEMM 2: r10 structure, BN=64 (frozen best) ------------------
__global__ __launch_bounds__(256) void moe_gemm2_kernel(
    const u16* __restrict__ inter, const float* __restrict__ w2,
    const int* __restrict__ cnt, const int* __restrict__ offs,
    const int* __restrict__ mt, const int* __restrict__ row_e,
    const int* __restrict__ row_bm,
    const int* __restrict__ pair_tok, const int* __restrict__ pair_slot,
    const float* __restrict__ pair_w, float* __restrict__ pout) {
  __shared__ u16 sA[3][128][32];
  __shared__ u16 sW[3][64][32];
  int MT = *mt;
  int active = MT * 16;
  int cpx = (active + 7) >> 3;
  int xg8 = blockIdx.x >> 3;
  if (xg8 >= cpx) return;
  int lid = (blockIdx.x & 7) * cpx + xg8;
  if (lid >= active) return;
  int mrow = lid % MT, bn = lid / MT;
  int e = row_e[mrow], bm = row_bm[mrow];
  int count = cnt[e], off = offs[e];
  const u16* A = inter + (size_t)off * FDIM;
  const float* W = w2 + (size_t)e * DM * FDIM;
  int tid = threadIdx.x, lane = tid & 63, w = tid >> 6;
  int wm = w >> 1, wn = w & 1;
  int qi = lane & 15, g = lane >> 4;
  int lrA = lane >> 2, lcA = (lane & 3) * 8;
  int ga0 = bm * 128 + w * 32 + lrA;      if (ga0 >= count) ga0 = count - 1;
  int ga1 = bm * 128 + w * 32 + 16 + lrA; if (ga1 >= count) ga1 = count - 1;
  const u16* pa0 = A + (size_t)ga0 * FDIM + lcA;
  const u16* pa1 = A + (size_t)ga1 * FDIM + lcA;
  int r16 = lane >> 2;
  int rW = w * 16 + r16;
  int cW = (lane & 3) * 8;
  const float* qw = W + (size_t)(bn * 64 + rW) * FDIM + cW;
  int uW = ((lane & 3) ^ (r16 & 3)) * 8;
  f32x4 acc[4][2] = {};
  const int NK = FDIM / 32;   // 112
  float4 ta = *(const float4*)qw, tb = *(const float4*)(qw + 4);
  float4 va = *(const float4*)(qw + 32), vb = *(const float4*)(qw + 36);
  __builtin_amdgcn_sched_barrier(0);
  gload16(pa0, &sA[0][w * 32][0]);
  gload16(pa1, &sA[0][w * 32 + 16][0]);
  gload16(pa0 + 32, &sA[1][w * 32][0]);
  gload16(pa1 + 32, &sA[1][w * 32 + 16][0]);
  asm volatile("s_waitcnt vmcnt(6)" ::: "memory");   // ta/tb ready
  cvtwr8(ta, tb, &sW[0][rW][uW]);
  for (int ks = 0; ks < NK; ks++) {
    int cur = ks % 3;
    if (ks == 0)           asm volatile("s_waitcnt vmcnt(2) lgkmcnt(0)" ::: "memory");
    else if (ks == NK - 1) asm volatile("s_waitcnt vmcnt(0) lgkmcnt(0)" ::: "memory");
    else                   asm volatile("s_waitcnt vmcnt(4) lgkmcnt(0)" ::: "memory");
    __builtin_amdgcn_s_barrier();
    short8 af[4], bfr[2];
#pragma unroll
    for (int i = 0; i < 4; i++)
      af[i] = *(short8*)&sA[cur][wm * 64 + i * 16 + qi][g * 8];
#pragma unroll
    for (int ni = 0; ni < 2; ni++) {
      int rt = wn * 32 + ni * 16 + qi;
      bfr[ni] = *(short8*)&sW[cur][rt][(g ^ (rt & 3)) * 8];
    }
    __builtin_amdgcn_s_setprio(1);
#pragma unroll
    for (int mi = 0; mi < 4; mi++)
#pragma unroll
      for (int ni = 0; ni < 2; ni++)
        acc[mi][ni] = __builtin_amdgcn_mfma_f32_16x16x32_bf16(af[mi], bfr[ni], acc[mi][ni], 0, 0, 0);
    __builtin_amdgcn_s_setprio(0);
    if (ks < NK - 1) {
      int nb = (ks + 1) % 3;
      cvtwr8(va, vb, &sW[nb][rW][uW]);
      if (ks < NK - 2) {
        int k2 = (ks + 2) * 32;
        va = *(const float4*)(qw + k2); vb = *(const float4*)(qw + k2 + 4);
        __builtin_amdgcn_sched_barrier(0);
        int ab = (ks + 2) % 3;
        gload16(pa0 + k2, &sA[ab][w * 32][0]);
        gload16(pa1 + k2, &sA[ab][w * 32 + 16][0]);
      }
    }
  }
#pragma unroll
  for (int mi = 0; mi < 4; mi++)
#pragma unroll
    for (int r = 0; r < 4; r++) {
      int row = bm * 128 + wm * 64 + mi * 16 + g * 4 + r;
      if (row < count) {
        int p = off + row;
        int t = pair_tok[p];
        float wgt = pair_w[p];
        size_t obase = ((size_t)pair_slot[p] * TQ + t) * DM + bn * 64 + wn * 32;
#pragma unroll
        for (int ni = 0; ni < 2; ni++)
          pout[obase + ni * 16 + qi] = acc[mi][ni][r] * wgt;
      }
    }
}

// ---------------- final combine -----------------------------------------------
__global__ __launch_bounds__(256) void combine_kernel(
    const float* __restrict__ h, const float* __restrict__ pout, float* __restrict__ out) {
  size_t i = (size_t)blockIdx.x * 256 + threadIdx.x;
  float4 a = ((const float4*)h)[i];
  float4 b0 = ((const float4*)pout)[i];
  float4 b1 = ((const float4*)pout)[i + (size_t)TQ * DM / 4];
  float4 r;
  r.x = a.x + b0.x + b1.x; r.y = a.y + b0.y + b1.y;
  r.z = a.z + b0.z + b1.z; r.w = a.w + b0.w + b1.w;
  ((float4*)out)[i] = r;
}

// ================================================================================
extern "C" void kernel_launch(void* const* d_in, const int* in_sizes, int n_in,
                              void* d_out, int out_size, void* d_ws, size_t ws_size,
                              hipStream_t stream) {
  (void)in_sizes; (void)n_in; (void)out_size; (void)ws_size;
  const float* x    = (const float*)d_in[0];
  const float* ln1  = (const float*)d_in[1];
  const float* ln2  = (const float*)d_in[2];
  const float* wq   = (const float*)d_in[3];
  const float* wk   = (const float*)d_in[4];
  const float* wv   = (const float*)d_in[5];
  const float* wo   = (const float*)d_in[6];
  const float* gw   = (const float*)d_in[7];
  const float* w1   = (const float*)d_in[8];
  const float* w2   = (const float*)d_in[9];
  const float* w3   = (const float*)d_in[10];
  const float* cosT = (const float*)d_in[11];
  const float* sinT = (const float*)d_in[12];

  char* mb = (char*)d_ws;
  const size_t MB = 1024 * 1024;
  u16*   qhb  = (u16*)(mb + 0 * MB);        // qkv->attn
  u16*   qlb  = (u16*)(mb + 4 * MB);
  u16*   khb  = (u16*)(mb + 8 * MB);
  u16*   klb  = (u16*)(mb + 9 * MB);
  u16*   vhb  = (u16*)(mb + 10 * MB);
  u16*   vlb  = (u16*)(mb + 11 * MB);
  u16*   hn2b = (u16*)(mb + 0 * MB);        // rmsnorm2->gather (after attn)
  u16*   ahb  = (u16*)(mb + 12 * MB);       // attn->gemm_o
  u16*   alb  = (u16*)(mb + 16 * MB);
  u16*   Xg   = (u16*)(mb + 12 * MB);       // gather->gemm13 (after gemm_o)
  u16*   hn1h = (u16*)(mb + 20 * MB);       // rmsnorm1->qkv
  u16*   hn1l = (u16*)(mb + 24 * MB);
  u16*   inter= (u16*)(mb + 20 * MB);       // gemm13->gemm2 (28 MiB)
  float* h_res= (float*)(mb + 48 * MB);     // gemm_o->end (8 MiB)
  u16*   woh  = (u16*)(mb + 56 * MB);       // wconv->gemm_o (2 MiB)
  u16*   wol  = (u16*)(mb + 58 * MB);
  float* pout = (float*)(mb + 56 * MB);     // gemm2->combine (16 MiB)
  u16*   wqkvh= (u16*)(mb + 60 * MB);       // wconv->qkv (3 MiB)
  u16*   wqkvl= (u16*)(mb + 63 * MB);
  int*   cnt  = (int*)(mb + 72 * MB);
  int*   offs = cnt + 8;
  int*   mtp  = cnt + 16;
  int*   row_e  = cnt + 17;                 // 40
  int*   row_bm = cnt + 57;                 // 40
  int*   tok_e  = cnt + 128;
  int*   tok_pos = tok_e + 4096;
  float* tok_w   = (float*)(tok_pos + 4096);
  int*   pair_tok  = (int*)(tok_w + 4096);
  int*   pair_slot = pair_tok + 4096;
  float* pair_w    = (float*)(pair_slot + 4096);

  fused_pre_kernel<<<2688, 256, 0, stream>>>(x, ln1, hn1h, hn1l,
                                             wq, wk, wv, wo,
                                             wqkvh, wqkvl, woh, wol);
  qkv_rope_kernel<<<384, 256, 0, stream>>>(hn1h, hn1l, wqkvh, wqkvl,
                                           cosT, sinT,
                                           qhb, qlb, khb, klb, vhb, vlb, 48);
  attn_kernel<<<512, 256, 0, stream>>>(qhb, qlb, khb, klb, vhb, vlb, ahb, alb);
  gemm_split3_kernel<true><<<256, 256, 0, stream>>>(ahb, alb, woh, wol, h_res, x, 1024, 32);
  zero8_kernel<<<1, 64, 0, stream>>>(cnt);
  rmsnorm_gate_kernel<<<TQ, 256, 0, stream>>>(h_res, ln2, gw, hn2b,
                                              cnt, tok_e, tok_pos, tok_w);
  schedule_kernel<<<1, 64, 0, stream>>>(cnt, offs, mtp, row_e, row_bm);
  gather_kernel<<<TQ, 256, 0, stream>>>(hn2b, tok_e, tok_pos, tok_w, offs, Xg,
                                        pair_tok, pair_slot, pair_w);
  moe_gemm13_kernel<<<2240, 256, 0, stream>>>(Xg, w1, w3, cnt, offs, mtp,
                                              row_e, row_bm, inter);
  moe_gemm2_kernel<<<640, 256, 0, stream>>>(inter, w2, cnt, offs, mtp,
                                            row_e, row_bm,
                                            pair_tok, pair_slot, pair_w, pout);
  combine_kernel<<<TQ, 256, 0, stream>>>(h_res, pout, (float*)d_out);
}

// Round 15
// 427.011 us; speedup vs baseline: 1.6155x; 1.0095x over previous
//
#include <hip/hip_runtime.h>

typedef unsigned short u16;
using short8 = __attribute__((ext_vector_type(8))) short;
using f32x4  = __attribute__((ext_vector_type(4))) float;

#define TQ   2048
#define DM   1024
#define SLEN 1024
#define FDIM 3584
#define NEXP 8

static __device__ __forceinline__ u16 f2bf(float f) {
  union { float f; unsigned u; } a; a.f = f;
  unsigned r = a.u + 0x7fffu + ((a.u >> 16) & 1u);
  return (u16)(r >> 16);
}
static __device__ __forceinline__ float bf2f(u16 u) {
  union { unsigned u; float f; } a; a.u = ((unsigned)u) << 16;
  return a.f;
}
static __device__ __forceinline__ unsigned cvtpk(float lo, float hi) {
  unsigned r;
  asm volatile("v_cvt_pk_bf16_f32 %0, %1, %2" : "=v"(r) : "v"(lo), "v"(hi));
  return r;
}

static __device__ __forceinline__ void gload16(const void* g, void* l) {
  __builtin_amdgcn_global_load_lds((const __attribute__((address_space(1))) void*)g,
                                   (__attribute__((address_space(3))) void*)l, 16, 0, 0);
}

// T1 chunked XCD swizzle
static __device__ __forceinline__ int xcd_lid(int bid, int cpx) {
  return (bid & 7) * cpx + (bid >> 3);
}

// convert 8 f32 (2 float4) -> 8 bf16 (16B) and ds_write_b128
static __device__ __forceinline__ void cvtwr8(float4 a, float4 b, u16* dst) {
  uint4 u;
  u.x = cvtpk(a.x, a.y); u.y = cvtpk(a.z, a.w);
  u.z = cvtpk(b.x, b.y); u.w = cvtpk(b.z, b.w);
  *(uint4*)dst = u;
}

// ------- fused: rmsnorm1 (blocks 0..2047) + weight split-conv + cnt zero -----
__global__ __launch_bounds__(256) void fused_pre_kernel(
    const float* __restrict__ x, const float* __restrict__ ln1,
    u16* __restrict__ oh, u16* __restrict__ ol,
    const float* __restrict__ wq, const float* __restrict__ wk,
    const float* __restrict__ wv, const float* __restrict__ wo,
    u16* __restrict__ qkvh, u16* __restrict__ qkvl,
    u16* __restrict__ woh, u16* __restrict__ wol, int* __restrict__ cnt) {
  int tid = threadIdx.x;
  if (blockIdx.x < 2048) {
    int t = blockIdx.x;
    const float4* xr = (const float4*)(x + (size_t)t * DM);
    float4 v = xr[tid];
    float ss = v.x * v.x + v.y * v.y + v.z * v.z + v.w * v.w;
#pragma unroll
    for (int m = 1; m < 64; m <<= 1) ss += __shfl_xor(ss, m);
    __shared__ float red[4];
    if ((tid & 63) == 0) red[tid >> 6] = ss;
    __syncthreads();
    float tot = red[0] + red[1] + red[2] + red[3];
    float sc = rsqrtf(tot * (1.0f / DM) + 1e-5f);
    float4 wv_ = ((const float4*)ln1)[tid];
    float o0 = v.x * sc * wv_.x, o1 = v.y * sc * wv_.y;
    float o2 = v.z * sc * wv_.z, o3 = v.w * sc * wv_.w;
    ushort4 hh;
    hh.x = f2bf(o0); hh.y = f2bf(o1); hh.z = f2bf(o2); hh.w = f2bf(o3);
    *(ushort4*)(oh + (size_t)t * DM + tid * 4) = hh;
    ushort4 ll;
    ll.x = f2bf(o0 - bf2f(hh.x)); ll.y = f2bf(o1 - bf2f(hh.y));
    ll.z = f2bf(o2 - bf2f(hh.z)); ll.w = f2bf(o3 - bf2f(hh.w));
    *(ushort4*)(ol + (size_t)t * DM + tid * 4) = ll;
    return;
  }
  int wb = blockIdx.x - 2048;   // 0..639
  if (wb == 0 && tid < 8) cnt[tid] = 0;
  for (int i = wb * 256 + tid; i < 655360; i += 640 * 256) {
    int el = i * 4;
    const float* src; u16 *dh, *dl;
    if (el < 1572864) {
      int r = el >> 10, c = el & 1023;
      if (r < 1024) src = wq + el;
      else if (r < 1280) src = wk + (r - 1024) * 1024 + c;
      else src = wv + (r - 1280) * 1024 + c;
      dh = qkvh + el; dl = qkvl + el;
    } else {
      int e2 = el - 1572864;
      src = wo + e2; dh = woh + e2; dl = wol + e2;
    }
    float4 v = *(const float4*)src;
    ushort4 h, l;
    h.x = f2bf(v.x); h.y = f2bf(v.y); h.z = f2bf(v.z); h.w = f2bf(v.w);
    l.x = f2bf(v.x - bf2f(h.x)); l.y = f2bf(v.y - bf2f(h.y));
    l.z = f2bf(v.z - bf2f(h.z)); l.w = f2bf(v.w - bf2f(h.w));
    *(ushort4*)dh = h; *(ushort4*)dl = l;
  }
}

// ------- fused rmsnorm2 + gate: bf16 out + top-2 routing ----------------------
__global__ __launch_bounds__(256) void rmsnorm_gate_kernel(
    const float* __restrict__ x, const float* __restrict__ w,
    const float* __restrict__ gw, u16* __restrict__ oh,
    int* cnt, int* tok_e, int* tok_pos, float* tok_w) {
  int t = blockIdx.x, tid = threadIdx.x;
  float4 v = ((const float4*)(x + (size_t)t * DM))[tid];
  float ss = v.x * v.x + v.y * v.y + v.z * v.z + v.w * v.w;
#pragma unroll
  for (int m = 1; m < 64; m <<= 1) ss += __shfl_xor(ss, m);
  __shared__ float red[4];
  __shared__ float gred[4][8];
  if ((tid & 63) == 0) red[tid >> 6] = ss;
  __syncthreads();
  float tot = red[0] + red[1] + red[2] + red[3];
  float sc = rsqrtf(tot * (1.0f / DM) + 1e-5f);
  float4 wv_ = ((const float4*)w)[tid];
  float o0 = v.x * sc * wv_.x, o1 = v.y * sc * wv_.y;
  float o2 = v.z * sc * wv_.z, o3 = v.w * sc * wv_.w;
  ushort4 hh;
  hh.x = f2bf(o0); hh.y = f2bf(o1); hh.z = f2bf(o2); hh.w = f2bf(o3);
  *(ushort4*)(oh + (size_t)t * DM + tid * 4) = hh;
  float acc[8];
#pragma unroll
  for (int e = 0; e < 8; e++) {
    float4 ge = ((const float4*)(gw + e * DM))[tid];
    acc[e] = o0 * ge.x + o1 * ge.y + o2 * ge.z + o3 * ge.w;
  }
#pragma unroll
  for (int e = 0; e < 8; e++)
#pragma unroll
    for (int m = 1; m < 64; m <<= 1) acc[e] += __shfl_xor(acc[e], m);
  int lane = tid & 63, wvi = tid >> 6;
  if (lane == 0)
#pragma unroll
    for (int e = 0; e < 8; e++) gred[wvi][e] = acc[e];
  __syncthreads();
  if (tid == 0) {
    float l[8];
#pragma unroll
    for (int e = 0; e < 8; e++)
      l[e] = gred[0][e] + gred[1][e] + gred[2][e] + gred[3][e];
    int i0 = 0;
#pragma unroll
    for (int e = 1; e < 8; e++) if (l[e] > l[i0]) i0 = e;
    int i1 = -1;
#pragma unroll
    for (int e = 0; e < 8; e++) if (e != i0 && (i1 < 0 || l[e] > l[i1])) i1 = e;
    float w0 = 1.0f;
    float w1 = expf(l[i1] - l[i0]);
    float rs = 1.0f / (w0 + w1);
    int p0 = atomicAdd(&cnt[i0], 1);
    int p1 = atomicAdd(&cnt[i1], 1);
    tok_e[t * 2] = i0; tok_e[t * 2 + 1] = i1;
    tok_pos[t * 2] = p0; tok_pos[t * 2 + 1] = p1;
    tok_w[t * 2] = w0 * rs; tok_w[t * 2 + 1] = w1 * rs;
  }
}

// ------- fused QKV GEMM + RoPE + split-bf16 epilogue --------------------------
__global__ __launch_bounds__(256) void qkv_rope_kernel(
    const u16* __restrict__ Ah, const u16* __restrict__ Al,
    const u16* __restrict__ Wh, const u16* __restrict__ Wl,
    const float* __restrict__ cosT, const float* __restrict__ sinT,
    u16* __restrict__ qh, u16* __restrict__ ql,
    u16* __restrict__ kh, u16* __restrict__ kl,
    u16* __restrict__ vh, u16* __restrict__ vl, int cpx) {
  __shared__ __align__(16) char pool[73728];
  u16 (*sAh)[128][32] = (u16(*)[128][32])pool;
  u16 (*sAl)[128][32] = (u16(*)[128][32])(pool + 24576);
  u16 (*sWh)[64][32]  = (u16(*)[64][32])(pool + 49152);
  u16 (*sWl)[64][32]  = (u16(*)[64][32])(pool + 61440);
  float (*sEpi)[65]   = (float(*)[65])pool;          // 128*65*4 = 33280 B
  int lid = xcd_lid(blockIdx.x, cpx);
  int bm = lid & 15, bn = lid >> 4;                  // bn 0..23
  int tid = threadIdx.x, lane = tid & 63, w = tid >> 6;
  int wm = w >> 1, wn = w & 1;
  int qi = lane & 15, g = lane >> 4;
  int lr = lane >> 2, lc = (lane & 3) * 8;
  const u16* pa0 = Ah + (size_t)(bm * 128 + w * 16 + lr) * DM + lc;
  const u16* pa1 = pa0 + 64 * DM;
  const u16* pl0 = Al + (size_t)(bm * 128 + w * 16 + lr) * DM + lc;
  const u16* pl1 = pl0 + 64 * DM;
  const u16* pw  = Wh + (size_t)(bn * 64 + w * 16 + lr) * DM + lc;
  const u16* pwl = Wl + (size_t)(bn * 64 + w * 16 + lr) * DM + lc;
  f32x4 acc[4][2] = {};
#define STGQ(buf, kk) do { \
    gload16(pa0 + (kk), &sAh[buf][w * 16][0]); \
    gload16(pa1 + (kk), &sAh[buf][64 + w * 16][0]); \
    gload16(pl0 + (kk), &sAl[buf][w * 16][0]); \
    gload16(pl1 + (kk), &sAl[buf][64 + w * 16][0]); \
    gload16(pw  + (kk), &sWh[buf][w * 16][0]); \
    gload16(pwl + (kk), &sWl[buf][w * 16][0]); } while (0)
  STGQ(0, 0);
  STGQ(1, 32);
  for (int ks = 0; ks < 32; ks++) {
    int cur = ks % 3;
    if (ks == 31) asm volatile("s_waitcnt vmcnt(0) lgkmcnt(0)" ::: "memory");
    else          asm volatile("s_waitcnt vmcnt(6) lgkmcnt(0)" ::: "memory");
    __builtin_amdgcn_s_barrier();
    short8 afh[4], afl[4], bfh[2], bfl[2];
#pragma unroll
    for (int i = 0; i < 4; i++) {
      afh[i] = *(short8*)&sAh[cur][wm * 64 + i * 16 + qi][g * 8];
      afl[i] = *(short8*)&sAl[cur][wm * 64 + i * 16 + qi][g * 8];
    }
#pragma unroll
    for (int i = 0; i < 2; i++) {
      bfh[i] = *(short8*)&sWh[cur][wn * 32 + i * 16 + qi][g * 8];
      bfl[i] = *(short8*)&sWl[cur][wn * 32 + i * 16 + qi][g * 8];
    }
    __builtin_amdgcn_s_setprio(1);
#pragma unroll
    for (int mi = 0; mi < 4; mi++)
#pragma unroll
      for (int ni = 0; ni < 2; ni++) {
        f32x4 a = acc[mi][ni];
        a = __builtin_amdgcn_mfma_f32_16x16x32_bf16(afh[mi], bfh[ni], a, 0, 0, 0);
        a = __builtin_amdgcn_mfma_f32_16x16x32_bf16(afl[mi], bfh[ni], a, 0, 0, 0);
        a = __builtin_amdgcn_mfma_f32_16x16x32_bf16(afh[mi], bfl[ni], a, 0, 0, 0);
        acc[mi][ni] = a;
      }
    __builtin_amdgcn_s_setprio(0);
    if (ks < 30) STGQ((ks + 2) % 3, (ks + 2) * 32);
  }
#undef STGQ
  __syncthreads();
#pragma unroll
  for (int mi = 0; mi < 4; mi++)
#pragma unroll
    for (int ni = 0; ni < 2; ni++)
#pragma unroll
      for (int r = 0; r < 4; r++)
        sEpi[wm * 64 + mi * 16 + g * 4 + r][wn * 32 + ni * 16 + qi] = acc[mi][ni][r];
  __syncthreads();
  int r0 = tid >> 1, hc = (tid & 1) * 16;
  int t = bm * 128 + r0;
  int s = t & (SLEN - 1);
  union { ushort u[16]; uint4 v[2]; } h1, l1, h2, l2;
  if (bn < 20) {
#pragma unroll
    for (int j = 0; j < 16; j++) {
      int d = hc + j;
      float c = cosT[s * 64 + d], sn = sinT[s * 64 + d];
      float x1 = sEpi[r0][d], x2 = sEpi[r0][d + 32];
      float o1 = x1 * c - x2 * sn;
      float o2 = x2 * c + x1 * sn;
      h1.u[j] = f2bf(o1); l1.u[j] = f2bf(o1 - bf2f(h1.u[j]));
      h2.u[j] = f2bf(o2); l2.u[j] = f2bf(o2 - bf2f(h2.u[j]));
    }
    u16 *dh, *dl; size_t base;
    if (bn < 16) { dh = qh; dl = ql; base = (size_t)t * DM + bn * 64; }
    else         { dh = kh; dl = kl; base = (size_t)t * 256 + (bn - 16) * 64; }
    *(uint4*)(dh + base + hc)      = h1.v[0];
    *(uint4*)(dh + base + hc + 8)  = h1.v[1];
    *(uint4*)(dh + base + 32 + hc)     = h2.v[0];
    *(uint4*)(dh + base + 32 + hc + 8) = h2.v[1];
    *(uint4*)(dl + base + hc)      = l1.v[0];
    *(uint4*)(dl + base + hc + 8)  = l1.v[1];
    *(uint4*)(dl + base + 32 + hc)     = l2.v[0];
    *(uint4*)(dl + base + 32 + hc + 8) = l2.v[1];
  } else {
#pragma unroll
    for (int j = 0; j < 16; j++) {
      float x1 = sEpi[r0][hc + j], x2 = sEpi[r0][hc + 32 + j];
      h1.u[j] = f2bf(x1); l1.u[j] = f2bf(x1 - bf2f(h1.u[j]));
      h2.u[j] = f2bf(x2); l2.u[j] = f2bf(x2 - bf2f(h2.u[j]));
    }
    size_t base = (size_t)t * 256 + (bn - 20) * 64;
    *(uint4*)(vh + base + hc)      = h1.v[0];
    *(uint4*)(vh + base + hc + 8)  = h1.v[1];
    *(uint4*)(vh + base + 32 + hc)     = h2.v[0];
    *(uint4*)(vh + base + 32 + hc + 8) = h2.v[1];
    *(uint4*)(vl + base + hc)      = l1.v[0];
    *(uint4*)(vl + base + hc + 8)  = l1.v[1];
    *(uint4*)(vl + base + 32 + hc)     = l2.v[0];
    *(uint4*)(vl + base + 32 + hc + 8) = l2.v[1];
  }
}

// ------- split-bf16 dense GEMM, counted depth-3 pipeline (O-proj) ------------
template <bool RESID>
__global__ __launch_bounds__(256) void gemm_split3_kernel(
    const u16* __restrict__ Ah, const u16* __restrict__ Al,
    const u16* __restrict__ Wh, const u16* __restrict__ Wl,
    float* __restrict__ C, const float* __restrict__ resid, int N, int cpx) {
  __shared__ u16 sAh[3][128][32], sAl[3][128][32], sWh[3][64][32], sWl[3][64][32];
  int lid = xcd_lid(blockIdx.x, cpx);
  int bm = lid & 15, bn = lid >> 4;
  int tid = threadIdx.x, lane = tid & 63, w = tid >> 6;
  int wm = w >> 1, wn = w & 1;
  int qi = lane & 15, g = lane >> 4;
  int lr = lane >> 2, lc = (lane & 3) * 8;
  const u16* pa0 = Ah + (size_t)(bm * 128 + w * 16 + lr) * DM + lc;
  const u16* pa1 = pa0 + 64 * DM;
  const u16* pl0 = Al + (size_t)(bm * 128 + w * 16 + lr) * DM + lc;
  const u16* pl1 = pl0 + 64 * DM;
  const u16* pw  = Wh + (size_t)(bn * 64 + w * 16 + lr) * DM + lc;
  const u16* pwl = Wl + (size_t)(bn * 64 + w * 16 + lr) * DM + lc;
  f32x4 acc[4][2] = {};
#define STG3(buf, kk) do { \
    gload16(pa0 + (kk), &sAh[buf][w * 16][0]); \
    gload16(pa1 + (kk), &sAh[buf][64 + w * 16][0]); \
    gload16(pl0 + (kk), &sAl[buf][w * 16][0]); \
    gload16(pl1 + (kk), &sAl[buf][64 + w * 16][0]); \
    gload16(pw  + (kk), &sWh[buf][w * 16][0]); \
    gload16(pwl + (kk), &sWl[buf][w * 16][0]); } while (0)
  STG3(0, 0);
  STG3(1, 32);
  for (int ks = 0; ks < 32; ks++) {
    int cur = ks % 3;
    if (ks == 31) asm volatile("s_waitcnt vmcnt(0) lgkmcnt(0)" ::: "memory");
    else          asm volatile("s_waitcnt vmcnt(6) lgkmcnt(0)" ::: "memory");
    __builtin_amdgcn_s_barrier();
    short8 afh[4], afl[4], bfh[2], bfl[2];
#pragma unroll
    for (int i = 0; i < 4; i++) {
      afh[i] = *(short8*)&sAh[cur][wm * 64 + i * 16 + qi][g * 8];
      afl[i] = *(short8*)&sAl[cur][wm * 64 + i * 16 + qi][g * 8];
    }
#pragma unroll
    for (int i = 0; i < 2; i++) {
      bfh[i] = *(short8*)&sWh[cur][wn * 32 + i * 16 + qi][g * 8];
      bfl[i] = *(short8*)&sWl[cur][wn * 32 + i * 16 + qi][g * 8];
    }
    __builtin_amdgcn_s_setprio(1);
#pragma unroll
    for (int mi = 0; mi < 4; mi++)
#pragma unroll
      for (int ni = 0; ni < 2; ni++) {
        f32x4 a = acc[mi][ni];
        a = __builtin_amdgcn_mfma_f32_16x16x32_bf16(afh[mi], bfh[ni], a, 0, 0, 0);
        a = __builtin_amdgcn_mfma_f32_16x16x32_bf16(afl[mi], bfh[ni], a, 0, 0, 0);
        a = __builtin_amdgcn_mfma_f32_16x16x32_bf16(afh[mi], bfl[ni], a, 0, 0, 0);
        acc[mi][ni] = a;
      }
    __builtin_amdgcn_s_setprio(0);
    if (ks < 30) STG3((ks + 2) % 3, (ks + 2) * 32);
  }
#undef STG3
#pragma unroll
  for (int mi = 0; mi < 4; mi++)
#pragma unroll
    for (int ni = 0; ni < 2; ni++) {
      int col = bn * 64 + wn * 32 + ni * 16 + qi;
#pragma unroll
      for (int r = 0; r < 4; r++) {
        int row = bm * 128 + wm * 64 + mi * 16 + g * 4 + r;
        float val = acc[mi][ni][r];
        if (RESID) val += resid[(size_t)row * N + col];
        C[(size_t)row * N + col] = val;
      }
    }
}

// ---------------- flash attention, split-bf16, GQA 4:1, causal ---------------
__global__ __launch_bounds__(256) void attn_kernel(
    const u16* __restrict__ qh, const u16* __restrict__ ql,
    const u16* __restrict__ kh, const u16* __restrict__ kl,
    const u16* __restrict__ vh, const u16* __restrict__ vl,
    u16* __restrict__ oh, u16* __restrict__ ol) {
  __shared__ u16 sKh[64][72], sKl[64][72];
  __shared__ u16 sVh[64][72], sVl[64][72];
  __shared__ u16 sPh[4][16][72], sPl[4][16][72];
  int idx = blockIdx.x & 255;
  int p = idx & 7;
  int bh = idx >> 3;
  int b = bh >> 4, h = bh & 15, kvh = h >> 2;
  int qt = (blockIdx.x < 256) ? p : (15 - p);
  int tid = threadIdx.x, lane = tid & 63, w = tid >> 6;
  int qi = lane & 15, g = lane >> 4;
  int qrow = qt * 64 + w * 16 + qi;
  size_t qbase = ((size_t)(b * SLEN + qrow)) * DM + h * 64;
  short8 qfh[2], qfl[2];
#pragma unroll
  for (int ds = 0; ds < 2; ds++) {
    qfh[ds] = *(const short8*)(qh + qbase + ds * 32 + g * 8);
    qfl[ds] = *(const short8*)(ql + qbase + ds * 32 + g * 8);
  }
  f32x4 oacc[4] = {};
  float mrun = -1e30f, lrun = 0.f;
  int ktiles = qt + 1;
  for (int kt = 0; kt < ktiles; kt++) {
    __syncthreads();
    {
      int r = tid >> 3, cs = (tid & 7) * 8;
#pragma unroll
      for (int rr = 0; rr < 64; rr += 32) {
        int key = kt * 64 + rr + r;
        size_t src = ((size_t)(b * SLEN + key)) * 256 + kvh * 64 + cs;
        *(short8*)&sKh[rr + r][cs] = *(const short8*)(kh + src);
        *(short8*)&sKl[rr + r][cs] = *(const short8*)(kl + src);
        short8 vv = *(const short8*)(vh + src);
        short8 vv2 = *(const short8*)(vl + src);
#pragma unroll
        for (int j = 0; j < 8; j++) {
          sVh[cs + j][rr + r] = (u16)vv[j];
          sVl[cs + j][rr + r] = (u16)vv2[j];
        }
      }
    }
    __syncthreads();
    f32x4 sa[4];
#pragma unroll
    for (int kf = 0; kf < 4; kf++) {
      f32x4 a = {};
#pragma unroll
      for (int ds = 0; ds < 2; ds++) {
        short8 kfh = *(short8*)&sKh[kf * 16 + qi][ds * 32 + g * 8];
        short8 kfl = *(short8*)&sKl[kf * 16 + qi][ds * 32 + g * 8];
        a = __builtin_amdgcn_mfma_f32_16x16x32_bf16(kfh, qfh[ds], a, 0, 0, 0);
        a = __builtin_amdgcn_mfma_f32_16x16x32_bf16(kfl, qfh[ds], a, 0, 0, 0);
        a = __builtin_amdgcn_mfma_f32_16x16x32_bf16(kfh, qfl[ds], a, 0, 0, 0);
      }
      sa[kf] = a;
    }
    int qg = qt * 64 + w * 16 + qi;
    float sv[4][4];
    float tmax = -1e30f;
#pragma unroll
    for (int kf = 0; kf < 4; kf++)
#pragma unroll
      for (int r = 0; r < 4; r++) {
        int key = kt * 64 + kf * 16 + g * 4 + r;
        float s = sa[kf][r] * 0.125f;
        s = (key <= qg) ? s : -1e30f;
        sv[kf][r] = s;
        tmax = fmaxf(tmax, s);
      }
    tmax = fmaxf(tmax, __shfl_xor(tmax, 16));
    tmax = fmaxf(tmax, __shfl_xor(tmax, 32));
    float mn = fmaxf(mrun, tmax);
    float alpha = expf(mrun - mn);
    float psum = 0.f;
#pragma unroll
    for (int kf = 0; kf < 4; kf++) {
      float p0 = expf(sv[kf][0] - mn), p1 = expf(sv[kf][1] - mn);
      float p2 = expf(sv[kf][2] - mn), p3 = expf(sv[kf][3] - mn);
      psum += p0 + p1 + p2 + p3;
      ushort4 ph, pl;
      ph.x = f2bf(p0); ph.y = f2bf(p1); ph.z = f2bf(p2); ph.w = f2bf(p3);
      pl.x = f2bf(p0 - bf2f(ph.x)); pl.y = f2bf(p1 - bf2f(ph.y));
      pl.z = f2bf(p2 - bf2f(ph.z)); pl.w = f2bf(p3 - bf2f(ph.w));
      *(ushort4*)&sPh[w][qi][kf * 16 + g * 4] = ph;
      *(ushort4*)&sPl[w][qi][kf * 16 + g * 4] = pl;
    }
    psum += __shfl_xor(psum, 16);
    psum += __shfl_xor(psum, 32);
    lrun = lrun * alpha + psum;
    mrun = mn;
#pragma unroll
    for (int df = 0; df < 4; df++) {
      oacc[df][0] *= alpha; oacc[df][1] *= alpha;
      oacc[df][2] *= alpha; oacc[df][3] *= alpha;
    }
#pragma unroll
    for (int ks = 0; ks < 2; ks++) {
      short8 pfh = *(short8*)&sPh[w][qi][ks * 32 + g * 8];
      short8 pfl = *(short8*)&sPl[w][qi][ks * 32 + g * 8];
#pragma unroll
      for (int df = 0; df < 4; df++) {
        short8 vfh = *(short8*)&sVh[df * 16 + qi][ks * 32 + g * 8];
        short8 vfl = *(short8*)&sVl[df * 16 + qi][ks * 32 + g * 8];
        f32x4 a = oacc[df];
        a = __builtin_amdgcn_mfma_f32_16x16x32_bf16(vfh, pfh, a, 0, 0, 0);
        a = __builtin_amdgcn_mfma_f32_16x16x32_bf16(vfl, pfh, a, 0, 0, 0);
        a = __builtin_amdgcn_mfma_f32_16x16x32_bf16(vfh, pfl, a, 0, 0, 0);
        oacc[df] = a;
      }
    }
  }
  float inv = 1.0f / lrun;
  size_t obase = ((size_t)(b * SLEN + qt * 64 + w * 16 + qi)) * DM + h * 64;
#pragma unroll
  for (int df = 0; df < 4; df++) {
    float o0 = oacc[df][0] * inv, o1 = oacc[df][1] * inv;
    float o2 = oacc[df][2] * inv, o3 = oacc[df][3] * inv;
    ushort4 hh, ll;
    hh.x = f2bf(o0); hh.y = f2bf(o1); hh.z = f2bf(o2); hh.w = f2bf(o3);
    ll.x = f2bf(o0 - bf2f(hh.x)); ll.y = f2bf(o1 - bf2f(hh.y));
    ll.z = f2bf(o2 - bf2f(hh.z)); ll.w = f2bf(o3 - bf2f(hh.w));
    *(ushort4*)(oh + obase + df * 16 + g * 4) = hh;
    *(ushort4*)(ol + obase + df * 16 + g * 4) = ll;
  }
}

// ---------------- routing helpers --------------------------------------------
__global__ void schedule_kernel(const int* cnt, int* offs, int* mt,
                                int* row_e, int* row_bm) {
  if (threadIdx.x == 0) {
    int s = 0, m = 0;
    for (int e = 0; e < 8; e++) {
      offs[e] = s;
      int nb = (cnt[e] + 127) >> 7;
      for (int i = 0; i < nb; i++) { row_e[m] = e; row_bm[m] = i; m++; }
      s += cnt[e];
    }
    *mt = m;
  }
}

// metadata-only: pair_tok/slot/w (no data copy; gemm13 reads hn2b indirectly)
__global__ __launch_bounds__(64) void pair_kernel(
    const int* __restrict__ tok_e, const int* __restrict__ tok_pos,
    const float* __restrict__ tok_w, const int* __restrict__ offs,
    int* __restrict__ pair_tok, int* __restrict__ pair_slot,
    float* __restrict__ pair_w) {
  int t = blockIdx.x * 64 + threadIdx.x;
#pragma unroll
  for (int slot = 0; slot < 2; slot++) {
    int e = tok_e[t * 2 + slot];
    int p = offs[e] + tok_pos[t * 2 + slot];
    pair_tok[p] = t; pair_slot[p] = slot; pair_w[p] = tok_w[t * 2 + slot];
  }
}

// ---- grouped MoE GEMM 1&3: r8 structure, A read indirectly from hn2b --------
__global__ __launch_bounds__(256) void moe_gemm13_kernel(
    const u16* __restrict__ hn2b, const int* __restrict__ pair_tok,
    const float* __restrict__ w1,
    const float* __restrict__ w3, const int* __restrict__ cnt,
    const int* __restrict__ offs, const int* __restrict__ mt,
    const int* __restrict__ row_e, const int* __restrict__ row_bm,
    u16* __restrict__ inter) {
  __shared__ u16 sA[3][128][32];
  __shared__ u16 sW1[3][64][32], sW3[3][64][32];
  int MT = *mt;
  int active = MT * 56;
  int cpx = (active + 7) >> 3;
  int xg8 = blockIdx.x >> 3;
  if (xg8 >= cpx) return;
  int lid = (blockIdx.x & 7) * cpx + xg8;
  if (lid >= active) return;
  int mrow = lid % MT, bn = lid / MT;
  int e = row_e[mrow], bm = row_bm[mrow];
  int count = cnt[e], off = offs[e];
  const float* W1 = w1 + (size_t)e * FDIM * DM;
  const float* W3 = w3 + (size_t)e * FDIM * DM;
  int tid = threadIdx.x, lane = tid & 63, w = tid >> 6;
  int wm = w >> 1, wn = w & 1;
  int qi = lane & 15, g = lane >> 4;
  int lrA = lane >> 2, lcA = (lane & 3) * 8;
  int ga0 = bm * 128 + w * 32 + lrA;      if (ga0 >= count) ga0 = count - 1;
  int ga1 = bm * 128 + w * 32 + 16 + lrA; if (ga1 >= count) ga1 = count - 1;
  int t0 = pair_tok[off + ga0];
  int t1 = pair_tok[off + ga1];
  const u16* pa0 = hn2b + (size_t)t0 * DM + lcA;
  const u16* pa1 = hn2b + (size_t)t1 * DM + lcA;
  int r16 = lane >> 2;
  int rW = w * 16 + r16;
  int cW = (lane & 3) * 8;
  const float* q1 = W1 + (size_t)(bn * 64 + rW) * DM + cW;
  const float* q3 = W3 + (size_t)(bn * 64 + rW) * DM + cW;
  int uW = ((lane & 3) ^ (r16 & 3)) * 8;
  f32x4 acc1[4][2] = {}, acc3[4][2] = {};
  float4 p1a = *(const float4*)q1, p1b = *(const float4*)(q1 + 4);
  float4 p3a = *(const float4*)q3, p3b = *(const float4*)(q3 + 4);
  float4 v1a = *(const float4*)(q1 + 32), v1b = *(const float4*)(q1 + 36);
  float4 v3a = *(const float4*)(q3 + 32), v3b = *(const float4*)(q3 + 36);
  __builtin_amdgcn_sched_barrier(0);
  gload16(pa0, &sA[0][w * 32][0]);
  gload16(pa1, &sA[0][w * 32 + 16][0]);
  gload16(pa0 + 32, &sA[1][w * 32][0]);
  gload16(pa1 + 32, &sA[1][w * 32 + 16][0]);
  asm volatile("s_waitcnt vmcnt(8)" ::: "memory");
  cvtwr8(p1a, p1b, &sW1[0][rW][uW]);
  cvtwr8(p3a, p3b, &sW3[0][rW][uW]);
  for (int ks = 0; ks < 32; ks++) {
    int cur = ks % 3;
    if (ks == 0)       asm volatile("s_waitcnt vmcnt(2) lgkmcnt(0)" ::: "memory");
    else if (ks == 31) asm volatile("s_waitcnt vmcnt(0) lgkmcnt(0)" ::: "memory");
    else               asm volatile("s_waitcnt vmcnt(6) lgkmcnt(0)" ::: "memory");
    __builtin_amdgcn_s_barrier();
    short8 af[4], b1[2], b3[2];
#pragma unroll
    for (int i = 0; i < 4; i++)
      af[i] = *(short8*)&sA[cur][wm * 64 + i * 16 + qi][g * 8];
#pragma unroll
    for (int ni = 0; ni < 2; ni++) {
      int rt = wn * 32 + ni * 16 + qi;
      int ui = (g ^ (rt & 3)) * 8;
      b1[ni] = *(short8*)&sW1[cur][rt][ui];
      b3[ni] = *(short8*)&sW3[cur][rt][ui];
    }
    __builtin_amdgcn_s_setprio(1);
#pragma unroll
    for (int mi = 0; mi < 4; mi++)
#pragma unroll
      for (int ni = 0; ni < 2; ni++) {
        acc1[mi][ni] = __builtin_amdgcn_mfma_f32_16x16x32_bf16(af[mi], b1[ni], acc1[mi][ni], 0, 0, 0);
        acc3[mi][ni] = __builtin_amdgcn_mfma_f32_16x16x32_bf16(af[mi], b3[ni], acc3[mi][ni], 0, 0, 0);
      }
    __builtin_amdgcn_s_setprio(0);
    if (ks < 31) {
      int nb = (ks + 1) % 3;
      cvtwr8(v1a, v1b, &sW1[nb][rW][uW]);
      cvtwr8(v3a, v3b, &sW3[nb][rW][uW]);
      if (ks < 30) {
        int k2 = (ks + 2) * 32;
        v1a = *(const float4*)(q1 + k2); v1b = *(const float4*)(q1 + k2 + 4);
        v3a = *(const float4*)(q3 + k2); v3b = *(const float4*)(q3 + k2 + 4);
        __builtin_amdgcn_sched_barrier(0);
        int ab = (ks + 2) % 3;
        gload16(pa0 + k2, &sA[ab][w * 32][0]);
        gload16(pa1 + k2, &sA[ab][w * 32 + 16][0]);
      }
    }
  }
#pragma unroll
  for (int mi = 0; mi < 4; mi++)
#pragma unroll
    for (int r = 0; r < 4; r++) {
      int row = bm * 128 + wm * 64 + mi * 16 + g * 4 + r;
      if (row < count) {
        size_t obase = (size_t)(off + row) * FDIM + bn * 64 + wn * 32;
#pragma unroll
        for (int ni = 0; ni < 2; ni++) {
          float c1 = acc1[mi][ni][r], c3 = acc3[mi][ni][r];
          float sv = c1 / (1.0f + expf(-c1)) * c3;
          inter[obase + ni * 16 + qi] = f2bf(sv);
        }
      }
    }
}

// ---- grouped MoE GEMM 2: r10 structure, BN=64 (frozen best) ------------------
__global__ __launch_bounds__(256) void moe_gemm2_kernel(
    const u16* __restrict__ inter, const float* __restrict__ w2,
    const int* __restrict__ cnt, const int* __restrict__ offs,
    const int* __restrict__ mt, const int* __restrict__ row_e,
    const int* __restrict__ row_bm,
    const int* __restrict__ pair_tok, const int* __restrict__ pair_slot,
    const float* __restrict__ pair_w, float* __restrict__ pout) {
  __shared__ u16 sA[3][128][32];
  __shared__ u16 sW[3][64][32];
  int MT = *mt;
  int active = MT * 16;
  int cpx = (active + 7) >> 3;
  int xg8 = blockIdx.x >> 3;
  if (xg8 >= cpx) return;
  int lid = (blockIdx.x & 7) * cpx + xg8;
  if (lid >= active) return;
  int mrow = lid % MT, bn = lid / MT;
  int e = row_e[mrow], bm = row_bm[mrow];
  int count = cnt[e], off = offs[e];
  const u16* A = inter + (size_t)off * FDIM;
  const float* W = w2 + (size_t)e * DM * FDIM;
  int tid = threadIdx.x, lane = tid & 63, w = tid >> 6;
  int wm = w >> 1, wn = w & 1;
  int qi = lane & 15, g = lane >> 4;
  int lrA = lane >> 2, lcA = (lane & 3) * 8;
  int ga0 = bm * 128 + w * 32 + lrA;      if (ga0 >= count) ga0 = count - 1;
  int ga1 = bm * 128 + w * 32 + 16 + lrA; if (ga1 >= count) ga1 = count - 1;
  const u16* pa0 = A + (size_t)ga0 * FDIM + lcA;
  const u16* pa1 = A + (size_t)ga1 * FDIM + lcA;
  int r16 = lane >> 2;
  int rW = w * 16 + r16;
  int cW = (lane & 3) * 8;
  const float* qw = W + (size_t)(bn * 64 + rW) * FDIM + cW;
  int uW = ((lane & 3) ^ (r16 & 3)) * 8;
  f32x4 acc[4][2] = {};
  const int NK = FDIM / 32;   // 112
  float4 ta = *(const float4*)qw, tb = *(const float4*)(qw + 4);
  float4 va = *(const float4*)(qw + 32), vb = *(const float4*)(qw + 36);
  __builtin_amdgcn_sched_barrier(0);
  gload16(pa0, &sA[0][w * 32][0]);
  gload16(pa1, &sA[0][w * 32 + 16][0]);
  gload16(pa0 + 32, &sA[1][w * 32][0]);
  gload16(pa1 + 32, &sA[1][w * 32 + 16][0]);
  asm volatile("s_waitcnt vmcnt(6)" ::: "memory");   // ta/tb ready
  cvtwr8(ta, tb, &sW[0][rW][uW]);
  for (int ks = 0; ks < NK; ks++) {
    int cur = ks % 3;
    if (ks == 0)           asm volatile("s_waitcnt vmcnt(2) lgkmcnt(0)" ::: "memory");
    else if (ks == NK - 1) asm volatile("s_waitcnt vmcnt(0) lgkmcnt(0)" ::: "memory");
    else                   asm volatile("s_waitcnt vmcnt(4) lgkmcnt(0)" ::: "memory");
    __builtin_amdgcn_s_barrier();
    short8 af[4], bfr[2];
#pragma unroll
    for (int i = 0; i < 4; i++)
      af[i] = *(short8*)&sA[cur][wm * 64 + i * 16 + qi][g * 8];
#pragma unroll
    for (int ni = 0; ni < 2; ni++) {
      int rt = wn * 32 + ni * 16 + qi;
      bfr[ni] = *(short8*)&sW[cur][rt][(g ^ (rt & 3)) * 8];
    }
    __builtin_amdgcn_s_setprio(1);
#pragma unroll
    for (int mi = 0; mi < 4; mi++)
#pragma unroll
      for (int ni = 0; ni < 2; ni++)
        acc[mi][ni] = __builtin_amdgcn_mfma_f32_16x16x32_bf16(af[mi], bfr[ni], acc[mi][ni], 0, 0, 0);
    __builtin_amdgcn_s_setprio(0);
    if (ks < NK - 1) {
      int nb = (ks + 1) % 3;
      cvtwr8(va, vb, &sW[nb][rW][uW]);
      if (ks < NK - 2) {
        int k2 = (ks + 2) * 32;
        va = *(const float4*)(qw + k2); vb = *(const float4*)(qw + k2 + 4);
        __builtin_amdgcn_sched_barrier(0);
        int ab = (ks + 2) % 3;
        gload16(pa0 + k2, &sA[ab][w * 32][0]);
        gload16(pa1 + k2, &sA[ab][w * 32 + 16][0]);
      }
    }
  }
#pragma unroll
  for (int mi = 0; mi < 4; mi++)
#pragma unroll
    for (int r = 0; r < 4; r++) {
      int row = bm * 128 + wm * 64 + mi * 16 + g * 4 + r;
      if (row < count) {
        int p = off + row;
        int t = pair_tok[p];
        float wgt = pair_w[p];
        size_t obase = ((size_t)pair_slot[p] * TQ + t) * DM + bn * 64 + wn * 32;
#pragma unroll
        for (int ni = 0; ni < 2; ni++)
          pout[obase + ni * 16 + qi] = acc[mi][ni][r] * wgt;
      }
    }
}

// ---------------- final combine -----------------------------------------------
__global__ __launch_bounds__(256) void combine_kernel(
    const float* __restrict__ h, const float* __restrict__ pout, float* __restrict__ out) {
  size_t i = (size_t)blockIdx.x * 256 + threadIdx.x;
  float4 a = ((const float4*)h)[i];
  float4 b0 = ((const float4*)pout)[i];
  float4 b1 = ((const float4*)pout)[i + (size_t)TQ * DM / 4];
  float4 r;
  r.x = a.x + b0.x + b1.x; r.y = a.y + b0.y + b1.y;
  r.z = a.z + b0.z + b1.z; r.w = a.w + b0.w + b1.w;
  ((float4*)out)[i] = r;
}

// ================================================================================
extern "C" void kernel_launch(void* const* d_in, const int* in_sizes, int n_in,
                              void* d_out, int out_size, void* d_ws, size_t ws_size,
                              hipStream_t stream) {
  (void)in_sizes; (void)n_in; (void)out_size; (void)ws_size;
  const float* x    = (const float*)d_in[0];
  const float* ln1  = (const float*)d_in[1];
  const float* ln2  = (const float*)d_in[2];
  const float* wq   = (const float*)d_in[3];
  const float* wk   = (const float*)d_in[4];
  const float* wv   = (const float*)d_in[5];
  const float* wo   = (const float*)d_in[6];
  const float* gw   = (const float*)d_in[7];
  const float* w1   = (const float*)d_in[8];
  const float* w2   = (const float*)d_in[9];
  const float* w3   = (const float*)d_in[10];
  const float* cosT = (const float*)d_in[11];
  const float* sinT = (const float*)d_in[12];

  char* mb = (char*)d_ws;
  const size_t MB = 1024 * 1024;
  u16*   qhb  = (u16*)(mb + 0 * MB);        // qkv->attn
  u16*   qlb  = (u16*)(mb + 4 * MB);
  u16*   khb  = (u16*)(mb + 8 * MB);
  u16*   klb  = (u16*)(mb + 9 * MB);
  u16*   vhb  = (u16*)(mb + 10 * MB);
  u16*   vlb  = (u16*)(mb + 11 * MB);
  u16*   hn2b = (u16*)(mb + 0 * MB);        // rmsnorm2->gemm13 (after attn)
  u16*   ahb  = (u16*)(mb + 12 * MB);       // attn->gemm_o
  u16*   alb  = (u16*)(mb + 16 * MB);
  u16*   hn1h = (u16*)(mb + 20 * MB);       // rmsnorm1->qkv
  u16*   hn1l = (u16*)(mb + 24 * MB);
  u16*   inter= (u16*)(mb + 20 * MB);       // gemm13->gemm2 (28 MiB)
  float* h_res= (float*)(mb + 48 * MB);     // gemm_o->end (8 MiB)
  u16*   woh  = (u16*)(mb + 56 * MB);       // wconv->gemm_o (2 MiB)
  u16*   wol  = (u16*)(mb + 58 * MB);
  float* pout = (float*)(mb + 56 * MB);     // gemm2->combine (16 MiB)
  u16*   wqkvh= (u16*)(mb + 60 * MB);       // wconv->qkv (3 MiB)
  u16*   wqkvl= (u16*)(mb + 63 * MB);
  int*   cnt  = (int*)(mb + 72 * MB);
  int*   offs = cnt + 8;
  int*   mtp  = cnt + 16;
  int*   row_e  = cnt + 17;                 // 40
  int*   row_bm = cnt + 57;                 // 40
  int*   tok_e  = cnt + 128;
  int*   tok_pos = tok_e + 4096;
  float* tok_w   = (float*)(tok_pos + 4096);
  int*   pair_tok  = (int*)(tok_w + 4096);
  int*   pair_slot = pair_tok + 4096;
  float* pair_w    = (float*)(pair_slot + 4096);

  fused_pre_kernel<<<2688, 256, 0, stream>>>(x, ln1, hn1h, hn1l,
                                             wq, wk, wv, wo,
                                             wqkvh, wqkvl, woh, wol, cnt);
  qkv_rope_kernel<<<384, 256, 0, stream>>>(hn1h, hn1l, wqkvh, wqkvl,
                                           cosT, sinT,
                                           qhb, qlb, khb, klb, vhb, vlb, 48);
  attn_kernel<<<512, 256, 0, stream>>>(qhb, qlb, khb, klb, vhb, vlb, ahb, alb);
  gemm_split3_kernel<true><<<256, 256, 0, stream>>>(ahb, alb, woh, wol, h_res, x, 1024, 32);
  rmsnorm_gate_kernel<<<TQ, 256, 0, stream>>>(h_res, ln2, gw, hn2b,
                                              cnt, tok_e, tok_pos, tok_w);
  schedule_kernel<<<1, 64, 0, stream>>>(cnt, offs, mtp, row_e, row_bm);
  pair_kernel<<<32, 64, 0, stream>>>(tok_e, tok_pos, tok_w, offs,
                                     pair_tok, pair_slot, pair_w);
  moe_gemm13_kernel<<<2240, 256, 0, stream>>>(hn2b, pair_tok, w1, w3, cnt, offs, mtp,
                                              row_e, row_bm, inter);
  moe_gemm2_kernel<<<640, 256, 0, stream>>>(inter, w2, cnt, offs, mtp,
                                            row_e, row_bm,
                                            pair_tok, pair_slot, pair_w, pout);
  combine_kernel<<<TQ, 256, 0, stream>>>(h_res, pout, (float*)d_out);
}